// Round 11
// baseline (800.659 us; speedup 1.0000x reference)
//
#include <hip/hip_runtime.h>
#include <math.h>

#define BB   128
#define DECD 512
#define E2D  1024
#define EMBD 256
#define S1D  200
#define S2D  200
#define SJD  400
#define VV   50000
#define NEGV (-1e10f)

typedef unsigned short u16;
typedef __bf16 bf16x8 __attribute__((ext_vector_type(8)));
typedef float f32x4 __attribute__((ext_vector_type(4)));
typedef u16 u16x8 __attribute__((ext_vector_type(8)));

__device__ __forceinline__ u16 f2bf(float x) {
  unsigned u = __float_as_uint(x);
  unsigned r = (u + 0x7fffu + ((u >> 16) & 1u)) >> 16;
  return (u16)r;
}
__device__ __forceinline__ float bf2f(u16 h) {
  return __uint_as_float(((unsigned)h) << 16);
}
// hardware RTNE casts (validated r7/r9: identical absmax)
__device__ __forceinline__ bf16x8 cvt8(float4 a, float4 b) {
  bf16x8 r;
  r[0] = (__bf16)a.x; r[1] = (__bf16)a.y; r[2] = (__bf16)a.z; r[3] = (__bf16)a.w;
  r[4] = (__bf16)b.x; r[5] = (__bf16)b.y; r[6] = (__bf16)b.z; r[7] = (__bf16)b.w;
  return r;
}

typedef const __attribute__((address_space(1))) void* gas_t;
typedef __attribute__((address_space(3))) void* las_t;
__device__ __forceinline__ void async_copy16(const u16* g, u16* l) {
  __builtin_amdgcn_global_load_lds((gas_t)g, (las_t)l, 16, 0, 0);
}

// ---------------- generic fp32 -> bf16 ----------------
__global__ __launch_bounds__(256) void k_cvt(const float* __restrict__ src,
    u16* __restrict__ dst, int n8) {
  int i = blockIdx.x * 256 + threadIdx.x;
  if (i >= n8) return;
  const float4 f0 = *(const float4*)(src + (size_t)i * 8);
  const float4 f1 = *(const float4*)(src + (size_t)i * 8 + 4);
  u16x8 o;
  o[0] = f2bf(f0.x); o[1] = f2bf(f0.y); o[2] = f2bf(f0.z); o[3] = f2bf(f0.w);
  o[4] = f2bf(f1.x); o[5] = f2bf(f1.y); o[6] = f2bf(f1.z); o[7] = f2bf(f1.w);
  *(u16x8*)(dst + (size_t)i * 8) = o;
}

// Wt[n][k] = bf16( W[512+k][n] )
__global__ __launch_bounds__(256) void k_wt(const float* __restrict__ W,
    u16* __restrict__ Wt) {
  __shared__ float t[32][33];
  int bk = blockIdx.x, bn = blockIdx.y;
  int tx = threadIdx.x & 31, ty = threadIdx.x >> 5;
  #pragma unroll
  for (int r = 0; r < 4; ++r) {
    int k = bk * 32 + ty + r * 8;
    t[ty + r * 8][tx] = W[(size_t)(512 + k) * 512 + bn * 32 + tx];
  }
  __syncthreads();
  #pragma unroll
  for (int r = 0; r < 4; ++r) {
    int n = bn * 32 + ty + r * 8;
    Wt[(size_t)n * 1024 + bk * 32 + tx] = f2bf(t[tx][ty + r * 8]);
  }
}

// ---------------- hybrid energy GEMM: r6 B-LDS skeleton + A direct-to-register ----------------
// tile 64x256, grid (2, M/64), 4 waves 2Mx2N, acc[2][8].
// B: bf16 Wt via async_copy16 -> 16 KB LDS (verified r6 path, 2 barriers/step).
// A: fp32 enc fragments straight to regs (4x float4/step, 1-step-ahead), cvt in-reg
//    (verified r9 A-layout). No A LDS, no A_bf writeback.
__global__ __launch_bounds__(256) void gemm_energy_h(
    const float* __restrict__ encA, const float* __restrict__ encB,
    const u16* __restrict__ Bt,
    const float* __restrict__ hW, const float* __restrict__ v,
    float* __restrict__ part, int M) {
  __shared__ u16 Bs[256 * 32];     // 16 KB
  __shared__ float sbuf[64][2];
  int tid = threadIdx.x;
  int wid = tid >> 6, lane = tid & 63;
  int wr = wid >> 1, wc = wid & 1;
  int bn = blockIdx.x;                 // n-half: 0 or 1
  size_t m0 = (size_t)blockIdx.y * 64;
  int bhalf = (blockIdx.y & 1) * 64;   // batch-row offset within the 128-batch
  int n0 = bn * 256;
  int q = lane >> 4, cl = lane & 15;

  const float* base = (m0 < (size_t)S1D * BB) ? (encA + m0 * E2D)
                                              : (encB + (m0 - (size_t)S1D * BB) * E2D);
  // A fragment bases (r9-verified layout): rows wr*32 + {0,16} + cl, elems q*8
  const float* gA0 = base + (size_t)(wr * 32 + cl) * E2D + q * 8;
  const float* gA1 = gA0 + (size_t)16 * E2D;

  // B staging: 4 async issues; issue i dest rows [i*64 + wid*16, +16) (r6-verified)
  const u16* gB[4];
  #pragma unroll
  for (int i = 0; i < 4; ++i) {
    int rn = i * 64 + wid * 16 + (lane >> 2);
    int c = (lane & 3) ^ ((rn >> 1) & 3);
    gB[i] = Bt + (size_t)(n0 + rn) * E2D + c * 8;
  }

  // B fragment LDS byte offsets (r6-verified swizzle)
  int boff[8];
  #pragma unroll
  for (int nj = 0; nj < 8; ++nj) {
    int rn = wc * 128 + nj * 16 + cl;
    boff[nj] = rn * 64 + ((q ^ ((rn >> 1) & 3)) * 16);
  }

  f32x4 acc[2][8];
  #pragma unroll
  for (int mi = 0; mi < 2; ++mi)
    #pragma unroll
    for (int nj = 0; nj < 8; ++nj) {
      f32x4 z = {0.f, 0.f, 0.f, 0.f};
      acc[mi][nj] = z;
    }

  // prologue: A(0) into regs
  float4 A0a = *(const float4*)(gA0);
  float4 A0b = *(const float4*)(gA0 + 4);
  float4 A1a = *(const float4*)(gA1);
  float4 A1b = *(const float4*)(gA1 + 4);
  float4 N0a, N0b, N1a, N1b;

  for (int t = 0; t < 32; ++t) {
    int k0 = t * 32, k1 = k0 + 32;
    // stage B(t) into LDS
    #pragma unroll
    for (int i = 0; i < 4; ++i) async_copy16(gB[i] + k0, &Bs[2048 * i + wid * 512]);
    // issue A(t+1) register loads
    if (t < 31) {
      N0a = *(const float4*)(gA0 + k1);
      N0b = *(const float4*)(gA0 + k1 + 4);
      N1a = *(const float4*)(gA1 + k1);
      N1b = *(const float4*)(gA1 + k1 + 4);
    }
    __syncthreads();   // B(t) visible (drains all vmem)
    bf16x8 af0 = cvt8(A0a, A0b);
    bf16x8 af1 = cvt8(A1a, A1b);
    #pragma unroll
    for (int nj = 0; nj < 8; ++nj) {
      bf16x8 bg = *(const bf16x8*)((const char*)Bs + boff[nj]);
      acc[0][nj] = __builtin_amdgcn_mfma_f32_16x16x32_bf16(af0, bg, acc[0][nj], 0, 0, 0);
      acc[1][nj] = __builtin_amdgcn_mfma_f32_16x16x32_bf16(af1, bg, acc[1][nj], 0, 0, 0);
    }
    __syncthreads();   // readers done before next-step B overwrite
    A0a = N0a; A0b = N0b; A1a = N1a; A1b = N1b;
  }

  // epilogue: partial over this n-half's 256 d (r6-verified)
  #pragma unroll
  for (int mi = 0; mi < 2; ++mi) {
    #pragma unroll
    for (int j = 0; j < 4; ++j) {
      int m = wr * 32 + mi * 16 + q * 4 + j;
      float s = 0.f;
      #pragma unroll
      for (int nj = 0; nj < 8; ++nj) {
        int d = n0 + wc * 128 + nj * 16 + cl;
        s += tanhf(acc[mi][nj][j] + hW[(size_t)(bhalf + m) * DECD + d]) * v[d];
      }
      s += __shfl_xor(s, 1, 64);
      s += __shfl_xor(s, 2, 64);
      s += __shfl_xor(s, 4, 64);
      s += __shfl_xor(s, 8, 64);
      if (cl == 0) sbuf[m][wc] = s;
    }
  }
  __syncthreads();
  if (tid < 64)
    part[(size_t)bn * M + m0 + tid] = sbuf[tid][0] + sbuf[tid][1];
}

// joint softmax fused with partial-sum (r10-verified)
__global__ __launch_bounds__(256) void k_softmax_j(const float* __restrict__ part,
    int M, float* __restrict__ sc,
    const int* __restrict__ m1, const int* __restrict__ m2) {
  int b = blockIdx.x, tid = threadIdx.x;
  __shared__ float sm[4];
  int s0 = tid, s2 = tid + 256;
  float a0 = -INFINITY, a1 = -INFINITY;
  {
    int msk = (s0 < S1D) ? m1[b * S1D + s0] : m2[b * S2D + (s0 - S1D)];
    int m = s0 * 128 + b;
    a0 = msk ? (part[m] + part[M + m]) : NEGV;
  }
  if (s2 < SJD) {
    int msk = (s2 < S1D) ? m1[b * S1D + s2] : m2[b * S2D + (s2 - S1D)];
    int m = s2 * 128 + b;
    a1 = msk ? (part[m] + part[M + m]) : NEGV;
  }
  float vmax = fmaxf(a0, a1);
  #pragma unroll
  for (int off = 32; off > 0; off >>= 1) vmax = fmaxf(vmax, __shfl_down(vmax, off, 64));
  int lane = tid & 63, wid = tid >> 6;
  if (lane == 0) sm[wid] = vmax;
  __syncthreads();
  vmax = fmaxf(fmaxf(sm[0], sm[1]), fmaxf(sm[2], sm[3]));
  __syncthreads();
  float lsum = expf(a0 - vmax);
  if (s2 < SJD) lsum += expf(a1 - vmax);
  #pragma unroll
  for (int off = 32; off > 0; off >>= 1) lsum += __shfl_down(lsum, off, 64);
  if (lane == 0) sm[wid] = lsum;
  __syncthreads();
  float inv = 1.0f / (sm[0] + sm[1] + sm[2] + sm[3]);
  sc[(size_t)b * SJD + s0] = expf(a0 - vmax) * inv;
  if (s2 < SJD) sc[(size_t)b * SJD + s2] = expf(a1 - vmax) * inv;
}

// scores[b][s] = part_half0[m] + part_half1[m], m = s*128 + b
__global__ __launch_bounds__(256) void k_sum2(const float* __restrict__ part,
    float* __restrict__ sc, int M, int S) {
  int m = blockIdx.x * 256 + threadIdx.x;
  if (m >= M) return;
  int b = m & 127, s = m >> 7;
  sc[(size_t)b * S + s] = part[m] + part[M + m];
}

// copy-path masked softmax (r8-verified, mode 1 semantics)
__global__ __launch_bounds__(256) void k_softmax_s(float* __restrict__ sc, int S,
    const int* __restrict__ m1, const int* __restrict__ m2) {
  int b = blockIdx.x, tid = threadIdx.x;
  __shared__ float sm[4];
  int s0 = tid;
  float a0 = -INFINITY;
  if (s0 < S) {
    int msk = m1[b * S + s0] * m2[b * S + s0];
    a0 = msk ? sc[(size_t)b * S + s0] : NEGV;
  }
  float vmax = a0;
  #pragma unroll
  for (int off = 32; off > 0; off >>= 1) vmax = fmaxf(vmax, __shfl_down(vmax, off, 64));
  int lane = tid & 63, wid = tid >> 6;
  if (lane == 0) sm[wid] = vmax;
  __syncthreads();
  vmax = fmaxf(fmaxf(sm[0], sm[1]), fmaxf(sm[2], sm[3]));
  __syncthreads();
  float lsum = (s0 < S) ? expf(a0 - vmax) : 0.f;
  #pragma unroll
  for (int off = 32; off > 0; off >>= 1) lsum += __shfl_down(lsum, off, 64);
  if (lane == 0) sm[wid] = lsum;
  __syncthreads();
  float inv = 1.0f / (sm[0] + sm[1] + sm[2] + sm[3]);
  if (s0 < S) sc[(size_t)b * S + s0] = expf(a0 - vmax) * inv;
}

// ---------------- fc GEMM v2 (r8-verified) ----------------
__global__ __launch_bounds__(512) void gemm_fc2(
    const u16* __restrict__ A, const float* __restrict__ Bf,
    const float* __restrict__ bias, float* __restrict__ C,
    int N, int K) {
  __shared__ u16 As[2][128 * 32];
  __shared__ u16 Bs[2][128 * 32];
  int tid = threadIdx.x;
  int wid = tid >> 6, lane = tid & 63;
  int wr = wid >> 2, wc = wid & 3;
  int n0 = blockIdx.x * 128;

  int rowa = wid * 16 + (lane >> 2);
  int ca = (lane & 3) ^ ((rowa >> 1) & 3);
  const u16* gA = A + (size_t)rowa * K + ca * 8;

  int rB = tid >> 2, cB = tid & 3;
  int gnB = n0 + rB; if (gnB >= N) gnB = N - 1;
  const float* gB = Bf + (size_t)gnB * K + cB * 8;
  int lBoff = rB * 32 + ((cB ^ ((rB >> 1) & 3)) * 8);

  int q = lane >> 4, cl = lane & 15;
  int aoff[4], boff[2];
  #pragma unroll
  for (int mi = 0; mi < 4; ++mi) {
    int row = wr * 64 + mi * 16 + cl;
    aoff[mi] = row * 64 + ((q ^ ((row >> 1) & 3)) * 16);
  }
  #pragma unroll
  for (int nj = 0; nj < 2; ++nj) {
    int rn = wc * 32 + nj * 16 + cl;
    boff[nj] = rn * 64 + ((q ^ ((rn >> 1) & 3)) * 16);
  }

  f32x4 acc[4][2];
  #pragma unroll
  for (int mi = 0; mi < 4; ++mi)
    #pragma unroll
    for (int nj = 0; nj < 2; ++nj) {
      f32x4 z = {0.f, 0.f, 0.f, 0.f};
      acc[mi][nj] = z;
    }

  for (int k0 = 0; k0 < K; k0 += 64) {
    float4 b00 = *(const float4*)(gB + k0);
    float4 b01 = *(const float4*)(gB + k0 + 4);
    float4 b10 = *(const float4*)(gB + k0 + 32);
    float4 b11 = *(const float4*)(gB + k0 + 36);
    u16x8 o0, o1;
    o0[0] = f2bf(b00.x); o0[1] = f2bf(b00.y); o0[2] = f2bf(b00.z); o0[3] = f2bf(b00.w);
    o0[4] = f2bf(b01.x); o0[5] = f2bf(b01.y); o0[6] = f2bf(b01.z); o0[7] = f2bf(b01.w);
    o1[0] = f2bf(b10.x); o1[1] = f2bf(b10.y); o1[2] = f2bf(b10.z); o1[3] = f2bf(b10.w);
    o1[4] = f2bf(b11.x); o1[5] = f2bf(b11.y); o1[6] = f2bf(b11.z); o1[7] = f2bf(b11.w);
    *(u16x8*)(&Bs[0][lBoff]) = o0;
    *(u16x8*)(&Bs[1][lBoff]) = o1;
    async_copy16(gA + k0,      &As[0][wid * 512]);
    async_copy16(gA + k0 + 32, &As[1][wid * 512]);
    __syncthreads();
    #pragma unroll
    for (int h = 0; h < 2; ++h) {
      bf16x8 af[4], bg[2];
      #pragma unroll
      for (int mi = 0; mi < 4; ++mi) af[mi] = *(const bf16x8*)((const char*)As[h] + aoff[mi]);
      #pragma unroll
      for (int nj = 0; nj < 2; ++nj) bg[nj] = *(const bf16x8*)((const char*)Bs[h] + boff[nj]);
      #pragma unroll
      for (int mi = 0; mi < 4; ++mi)
        #pragma unroll
        for (int nj = 0; nj < 2; ++nj)
          acc[mi][nj] = __builtin_amdgcn_mfma_f32_16x16x32_bf16(af[mi], bg[nj], acc[mi][nj], 0, 0, 0);
    }
    __syncthreads();
  }

  #pragma unroll
  for (int mi = 0; mi < 4; ++mi) {
    #pragma unroll
    for (int nj = 0; nj < 2; ++nj) {
      int n = n0 + wc * 32 + nj * 16 + cl;
      if (n < N) {
        float bv = bias[n];
        #pragma unroll
        for (int j = 0; j < 4; ++j) {
          int m = wr * 64 + mi * 16 + q * 4 + j;
          C[(size_t)m * N + n] = acc[mi][nj][j] + bv;
        }
      }
    }
  }
}

// ---------------- small kernels (r8-verified) ----------------
__global__ __launch_bounds__(256) void k_partial(const float* __restrict__ h,
    const float* __restrict__ W, const float* __restrict__ bias,
    float* __restrict__ out) {
  int b = blockIdx.y;
  int d = blockIdx.x * 256 + threadIdx.x;
  const float* hr = h + (size_t)b * DECD;
  float acc = bias[d];
  #pragma unroll 8
  for (int k = 0; k < DECD; ++k) acc += hr[k] * W[(size_t)k * DECD + d];
  out[(size_t)b * DECD + d] = acc;
}

// weighted partials over s-chunks of 100, fp32 enc reads (r9-verified)
__global__ __launch_bounds__(256) void k_wpart(const float* __restrict__ enc1,
    const float* __restrict__ enc2, const float* __restrict__ a,
    float* __restrict__ wp) {
  int b = blockIdx.x;
  int e2 = blockIdx.y * 256 + threadIdx.x;
  int scn = blockIdx.z;
  const float* arow = a + (size_t)b * SJD;
  float acc0 = 0.f, acc1 = 0.f;
  #pragma unroll 4
  for (int s = scn * 100; s < scn * 100 + 100; ++s) {
    const float* ep = (s < S1D) ? (enc1 + ((size_t)s * BB + b) * E2D)
                                : (enc2 + ((size_t)(s - S1D) * BB + b) * E2D);
    float2 u = *(const float2*)(ep + e2 * 2);
    float w = arow[s];
    acc0 += w * u.x;
    acc1 += w * u.y;
  }
  float* dst = wp + ((size_t)scn * BB + b) * E2D + e2 * 2;
  dst[0] = acc0;
  dst[1] = acc1;
}

__global__ __launch_bounds__(256) void k_wsum_x(const float* __restrict__ wp,
    float* __restrict__ wgt, u16* __restrict__ x) {
  int i = blockIdx.x * 256 + threadIdx.x;
  const int NN = BB * E2D;
  float s = wp[i] + wp[NN + i] + wp[2 * NN + i] + wp[3 * NN + i];
  wgt[i] = s;
  int b = i >> 10, e = i & 1023;
  x[(size_t)b * 1280 + EMBD + e] = f2bf(s);
}

__global__ __launch_bounds__(256) void k_embx(const int* __restrict__ inp,
    const float* __restrict__ table, u16* __restrict__ x) {
  int b = blockIdx.x, t = threadIdx.x;
  x[(size_t)b * 1280 + t] = f2bf(table[(size_t)inp[b] * EMBD + t]);
}

__global__ __launch_bounds__(256) void k_concat_state_bf(const float* __restrict__ hnew,
    const float* __restrict__ wgt, u16* __restrict__ st) {
  int b = blockIdx.x;
  for (int i = threadIdx.x; i < DECD + E2D; i += 256) {
    float vv = (i < DECD) ? hnew[(size_t)b * DECD + i] : wgt[(size_t)b * E2D + i - DECD];
    st[(size_t)b * (DECD + E2D) + i] = f2bf(vv);
  }
}

__global__ __launch_bounds__(256) void k_gru(const float* __restrict__ gx,
    const float* __restrict__ gh, const float* __restrict__ hidden,
    float* __restrict__ hnew) {
  int b = blockIdx.x, tid = threadIdx.x;
  #pragma unroll
  for (int qq = 0; qq < 2; ++qq) {
    int d = tid + qq * 256;
    size_t o = (size_t)b * 1536;
    float xr = gx[o + d],        hr = gh[o + d];
    float xz = gx[o + 512 + d],  hz = gh[o + 512 + d];
    float xn = gx[o + 1024 + d], hn = gh[o + 1024 + d];
    float r = 1.f / (1.f + expf(-(xr + hr)));
    float z = 1.f / (1.f + expf(-(xz + hz)));
    float n = tanhf(xn + r * hn);
    hnew[(size_t)b * DECD + d] = (1.f - z) * n + z * hidden[(size_t)b * DECD + d];
  }
}

__global__ __launch_bounds__(256) void k_pgen(const float* __restrict__ wgt,
    const int* __restrict__ inp, const float* __restrict__ table,
    const float* __restrict__ gW, const float* __restrict__ gb,
    float* __restrict__ pg) {
  int b = blockIdx.x, tid = threadIdx.x;
  __shared__ float sm[4];
  float s = 0.f;
  for (int k = tid; k < E2D + EMBD; k += 256)
    s += gW[k] * ((k < E2D) ? wgt[(size_t)b * E2D + k]
                            : table[(size_t)inp[b] * EMBD + k - E2D]);
  #pragma unroll
  for (int off = 32; off > 0; off >>= 1) s += __shfl_down(s, off, 64);
  int lane = tid & 63, wid = tid >> 6;
  if (lane == 0) sm[wid] = s;
  __syncthreads();
  if (tid == 0) {
    float t = sm[0] + sm[1] + sm[2] + sm[3] + gb[0];
    pg[b] = 1.f / (1.f + expf(-t));
  }
}

__global__ __launch_bounds__(256) void k_vocab(float* __restrict__ dist,
    const float* __restrict__ pg) {
  int b = blockIdx.x, tid = threadIdx.x;
  float* row = dist + (size_t)b * VV;
  __shared__ float sm[4];
  float m = -INFINITY;
  for (int i = tid; i < VV; i += 256) m = fmaxf(m, row[i]);
  #pragma unroll
  for (int off = 32; off > 0; off >>= 1) m = fmaxf(m, __shfl_down(m, off, 64));
  int lane = tid & 63, wid = tid >> 6;
  if (lane == 0) sm[wid] = m;
  __syncthreads();
  m = fmaxf(fmaxf(sm[0], sm[1]), fmaxf(sm[2], sm[3]));
  __syncthreads();
  float s = 0.f;
  for (int i = tid; i < VV; i += 256) s += expf(row[i] - m);
  #pragma unroll
  for (int off = 32; off > 0; off >>= 1) s += __shfl_down(s, off, 64);
  if (lane == 0) sm[wid] = s;
  __syncthreads();
  s = sm[0] + sm[1] + sm[2] + sm[3];
  float scale = pg[b] / s;
  for (int i = tid; i < VV; i += 256) row[i] = expf(row[i] - m) * scale;
}

__global__ __launch_bounds__(256) void k_scatter(float* __restrict__ dist,
    const float* __restrict__ ad, const float* __restrict__ pg,
    const int* __restrict__ src1) {
  int b = blockIdx.x, tid = threadIdx.x;
  if (tid < S1D) {
    float val = (1.f - pg[b]) * ad[(size_t)b * S1D + tid];
    int tok = src1[(size_t)tid * BB + b];
    atomicAdd(&dist[(size_t)b * VV + tok], val);
  }
}

extern "C" void kernel_launch(void* const* d_in, const int* in_sizes, int n_in,
                              void* d_out, int out_size, void* d_ws, size_t ws_size,
                              hipStream_t stream) {
  (void)in_sizes; (void)n_in; (void)out_size; (void)ws_size;
  const int*   input  = (const int*)d_in[0];
  const float* hidden = (const float*)d_in[1];
  const int*   src1   = (const int*)d_in[2];
  const float* enc1   = (const float*)d_in[3];
  const int*   mask1  = (const int*)d_in[4];
  const int*   triple = (const int*)d_in[5];
  const float* enc2   = (const float*)d_in[6];
  const int*   mask2  = (const int*)d_in[7];
  const float* embedding = (const float*)d_in[8];
  const float* attn_W = (const float*)d_in[9];
  const float* attn_b = (const float*)d_in[10];
  const float* attn_v = (const float*)d_in[11];
  const float* copy_W = (const float*)d_in[12];
  const float* copy_b = (const float*)d_in[13];
  const float* copy_v = (const float*)d_in[14];
  const float* gru_Wih = (const float*)d_in[15];
  const float* gru_Whh = (const float*)d_in[16];
  const float* gru_bih = (const float*)d_in[17];
  const float* gru_bhh = (const float*)d_in[18];
  const float* fc_W   = (const float*)d_in[19];
  const float* fc_b   = (const float*)d_in[20];
  const float* gate_W = (const float*)d_in[21];
  const float* gate_b = (const float*)d_in[22];

  char* w = (char*)d_ws;
  u16* Wt_a = (u16*)w;                w += (size_t)512 * 1024 * 2;
  u16* Wt_c = (u16*)w;                w += (size_t)512 * 1024 * 2;
  float* partJ = (float*)w;           w += (size_t)2 * 51200 * 4;
  float* partC = (float*)w;           w += (size_t)2 * 25600 * 4;
  float* hWa  = (float*)w;            w += (size_t)BB * DECD * 4;
  float* hWc  = (float*)w;            w += (size_t)BB * DECD * 4;
  float* scJ  = (float*)w;            w += (size_t)BB * SJD * 4;
  float* scC  = (float*)w;            w += (size_t)BB * S1D * 4;
  float* wgt  = (float*)w;            w += (size_t)BB * E2D * 4;
  float* wpart = (float*)w;           w += (size_t)4 * BB * E2D * 4;
  u16*   x_bf = (u16*)w;              w += (size_t)BB * 1280 * 2;
  u16*   hid_bf = (u16*)w;            w += (size_t)BB * DECD * 2;
  float* gx   = (float*)w;            w += (size_t)BB * 1536 * 4;
  float* gh   = (float*)w;            w += (size_t)BB * 1536 * 4;
  u16*   st_bf = (u16*)w;             w += (size_t)BB * 1536 * 2;
  float* pg   = (float*)w;            w += 512;

  float* out  = (float*)d_out;
  float* hnew = out + (size_t)BB * VV;

  // prep
  k_wt<<<dim3(32, 16), 256, 0, stream>>>(attn_W, Wt_a);
  k_wt<<<dim3(32, 16), 256, 0, stream>>>(copy_W, Wt_c);
  k_cvt<<<32, 256, 0, stream>>>(hidden, hid_bf, BB * DECD / 8);
  k_partial<<<dim3(2, BB), 256, 0, stream>>>(hidden, attn_W, attn_b, hWa);
  k_embx<<<BB, 256, 0, stream>>>(input, embedding, x_bf);

  // joint attention scores (hybrid A-direct energy GEMM)
  gemm_energy_h<<<dim3(2, SJD * 2), 256, 0, stream>>>(
      enc1, enc2, Wt_a, hWa, attn_v, partJ, 51200);
  k_softmax_j<<<BB, 256, 0, stream>>>(partJ, 51200, scJ, mask1, mask2);

  // weighted context (fp32 enc reads)
  k_wpart<<<dim3(BB, 2, 4), 256, 0, stream>>>(enc1, enc2, scJ, wpart);
  k_wsum_x<<<512, 256, 0, stream>>>(wpart, wgt, x_bf);

  // GRU (bf16 MFMA with fused weight conversion)
  gemm_fc2<<<1536 / 128, 512, 0, stream>>>(x_bf, gru_Wih, gru_bih, gx, 1536, 1280);
  gemm_fc2<<<1536 / 128, 512, 0, stream>>>(hid_bf, gru_Whh, gru_bhh, gh, 1536, 512);
  k_gru<<<BB, 256, 0, stream>>>(gx, gh, hidden, hnew);

  // vocab logits
  k_concat_state_bf<<<BB, 256, 0, stream>>>(hnew, wgt, st_bf);
  gemm_fc2<<<(VV + 127) / 128, 512, 0, stream>>>(st_bf, fc_W, fc_b, out, VV, 1536);

  // copy path (hybrid energy over enc1 only)
  k_pgen<<<BB, 256, 0, stream>>>(wgt, input, embedding, gate_W, gate_b, pg);
  k_partial<<<dim3(2, BB), 256, 0, stream>>>(hnew, copy_W, copy_b, hWc);
  gemm_energy_h<<<dim3(2, S1D * 2), 256, 0, stream>>>(
      enc1, enc1, Wt_c, hWc, copy_v, partC, 25600);
  k_sum2<<<100, 256, 0, stream>>>(partC, scC, 25600, S1D);
  k_softmax_s<<<BB, 256, 0, stream>>>(scC, S1D, mask1, triple);

  // final distribution
  k_vocab<<<BB, 256, 0, stream>>>(out, pg);
  k_scatter<<<BB, 256, 0, stream>>>(out, scC, pg, src1);
}

// Round 12
// 684.596 us; speedup vs baseline: 1.1695x; 1.1695x over previous
//
#include <hip/hip_runtime.h>
#include <math.h>

#define BB   128
#define DECD 512
#define E2D  1024
#define EMBD 256
#define S1D  200
#define S2D  200
#define SJD  400
#define VV   50000
#define NEGV (-1e10f)

typedef unsigned short u16;
typedef __bf16 bf16x8 __attribute__((ext_vector_type(8)));
typedef float f32x4 __attribute__((ext_vector_type(4)));
typedef u16 u16x8 __attribute__((ext_vector_type(8)));

__device__ __forceinline__ u16 f2bf(float x) {
  unsigned u = __float_as_uint(x);
  unsigned r = (u + 0x7fffu + ((u >> 16) & 1u)) >> 16;
  return (u16)r;
}
__device__ __forceinline__ float bf2f(u16 h) {
  return __uint_as_float(((unsigned)h) << 16);
}
__device__ __forceinline__ u16x8 cvt8u(float4 a, float4 b) {
  u16x8 o;
  o[0] = f2bf(a.x); o[1] = f2bf(a.y); o[2] = f2bf(a.z); o[3] = f2bf(a.w);
  o[4] = f2bf(b.x); o[5] = f2bf(b.y); o[6] = f2bf(b.z); o[7] = f2bf(b.w);
  return o;
}

typedef const __attribute__((address_space(1))) void* gas_t;
typedef __attribute__((address_space(3))) void* las_t;
__device__ __forceinline__ void async_copy16(const u16* g, u16* l) {
  __builtin_amdgcn_global_load_lds((gas_t)g, (las_t)l, 16, 0, 0);
}

// ---------------- generic fp32 -> bf16 ----------------
__global__ __launch_bounds__(256) void k_cvt(const float* __restrict__ src,
    u16* __restrict__ dst, int n8) {
  int i = blockIdx.x * 256 + threadIdx.x;
  if (i >= n8) return;
  const float4 f0 = *(const float4*)(src + (size_t)i * 8);
  const float4 f1 = *(const float4*)(src + (size_t)i * 8 + 4);
  *(u16x8*)(dst + (size_t)i * 8) = cvt8u(f0, f1);
}

// Wt[n][k] = bf16( W[512+k][n] )
__global__ __launch_bounds__(256) void k_wt(const float* __restrict__ W,
    u16* __restrict__ Wt) {
  __shared__ float t[32][33];
  int bk = blockIdx.x, bn = blockIdx.y;
  int tx = threadIdx.x & 31, ty = threadIdx.x >> 5;
  #pragma unroll
  for (int r = 0; r < 4; ++r) {
    int k = bk * 32 + ty + r * 8;
    t[ty + r * 8][tx] = W[(size_t)(512 + k) * 512 + bn * 32 + tx];
  }
  __syncthreads();
  #pragma unroll
  for (int r = 0; r < 4; ++r) {
    int n = bn * 32 + ty + r * 8;
    Wt[(size_t)n * 1024 + bk * 32 + tx] = f2bf(t[tx][ty + r * 8]);
  }
}

// ---------------- energy GEMM, r6/r8 template with BK=64 (two 32-k half-buffers) ----------------
// tile 64x256, grid (2, M/64), 4 waves 2Mx2N, acc[2][8].
// A: fp32 enc reg-convert -> LDS half-buffers, double-buffered (r6-verified path).
// B: bf16 Wt via async_copy16 -> two 16KB half-buffers, single-buffered, staged per step.
// 16 K-steps x 2 barriers = 32 barriers/block (half of r6).
__global__ __launch_bounds__(256) void gemm_energy64(
    const float* __restrict__ encA, const float* __restrict__ encB,
    const u16* __restrict__ Bt,
    const float* __restrict__ hW, const float* __restrict__ v,
    float* __restrict__ part, int M) {
  __shared__ u16 As[2][2][64 * 32];   // [buf][half] : 4 x 4 KB
  __shared__ u16 Bs[2][256 * 32];     // [half]      : 2 x 16 KB
  __shared__ float sbuf[64][2];
  int tid = threadIdx.x;
  int wid = tid >> 6, lane = tid & 63;
  int wr = wid >> 1, wc = wid & 1;
  int bn = blockIdx.x;                 // n-half: 0 or 1
  size_t m0 = (size_t)blockIdx.y * 64;
  int bhalf = (blockIdx.y & 1) * 64;   // batch-row offset within the 128-batch
  int n0 = bn * 256;
  int q = lane >> 4, cl = lane & 15;

  // ---- A staging (reg-convert): row rA, chunk cslot (per half) ----
  int rA = tid >> 2, cslot = tid & 3;
  int lAoff = rA * 32 + ((cslot ^ ((rA >> 1) & 3)) * 8);   // u16 offset within a half
  const float* base = (m0 < (size_t)S1D * BB) ? (encA + m0 * E2D)
                                              : (encB + (m0 - (size_t)S1D * BB) * E2D);
  const float* gA = base + (size_t)rA * E2D + cslot * 8;   // half1 source at +32

  // ---- B staging: 4 row-groups x 2 halves; source half1 at +32 k ----
  const u16* gB4[4];
  #pragma unroll
  for (int i = 0; i < 4; ++i) {
    int rn = i * 64 + wid * 16 + (lane >> 2);
    int c = (lane & 3) ^ ((rn >> 1) & 3);
    gB4[i] = Bt + (size_t)(n0 + rn) * E2D + c * 8;
  }

  // ---- fragment LDS byte offsets (per half; r6-verified swizzle) ----
  int aoff[2], boff[8];
  #pragma unroll
  for (int mi = 0; mi < 2; ++mi) {
    int row = wr * 32 + mi * 16 + cl;
    aoff[mi] = row * 64 + ((q ^ ((row >> 1) & 3)) * 16);
  }
  #pragma unroll
  for (int nj = 0; nj < 8; ++nj) {
    int rn = wc * 128 + nj * 16 + cl;
    boff[nj] = rn * 64 + ((q ^ ((rn >> 1) & 3)) * 16);
  }

  f32x4 acc[2][8];
  #pragma unroll
  for (int mi = 0; mi < 2; ++mi)
    #pragma unroll
    for (int nj = 0; nj < 8; ++nj) {
      f32x4 z = {0.f, 0.f, 0.f, 0.f};
      acc[mi][nj] = z;
    }

  // ---- prologue: store A(0) both halves; prefetch A(1) regs ----
  float4 a00 = *(const float4*)(gA);
  float4 a01 = *(const float4*)(gA + 4);
  float4 a10 = *(const float4*)(gA + 32);
  float4 a11 = *(const float4*)(gA + 36);
  *(u16x8*)(&As[0][0][lAoff]) = cvt8u(a00, a01);
  *(u16x8*)(&As[0][1][lAoff]) = cvt8u(a10, a11);
  a00 = *(const float4*)(gA + 64);
  a01 = *(const float4*)(gA + 68);
  a10 = *(const float4*)(gA + 96);
  a11 = *(const float4*)(gA + 100);

  // ---- main loop: 16 K-steps of 64; A dbuf, B single-buffer, 2 barriers/step ----
  for (int t = 0; t < 16; ++t) {
    int cur = t & 1, nxt = cur ^ 1;
    int kb = t * 64, kn = kb + 64;
    // stage B(t), both halves
    #pragma unroll
    for (int i = 0; i < 4; ++i) {
      async_copy16(gB4[i] + kb,      &Bs[0][2048 * i + wid * 512]);
      async_copy16(gB4[i] + kb + 32, &Bs[1][2048 * i + wid * 512]);
    }
    // store A(t+1) from regs; prefetch A(t+2)
    if (t < 15) {
      *(u16x8*)(&As[nxt][0][lAoff]) = cvt8u(a00, a01);
      *(u16x8*)(&As[nxt][1][lAoff]) = cvt8u(a10, a11);
      if (t < 14) {
        a00 = *(const float4*)(gA + kn + 64);
        a01 = *(const float4*)(gA + kn + 68);
        a10 = *(const float4*)(gA + kn + 96);
        a11 = *(const float4*)(gA + kn + 100);
      }
    }
    __syncthreads();   // B(t) + A(t+1) staged & visible
    #pragma unroll
    for (int h = 0; h < 2; ++h) {
      bf16x8 af0 = *(const bf16x8*)((const char*)As[cur][h] + aoff[0]);
      bf16x8 af1 = *(const bf16x8*)((const char*)As[cur][h] + aoff[1]);
      #pragma unroll
      for (int nj = 0; nj < 8; ++nj) {
        bf16x8 bg = *(const bf16x8*)((const char*)Bs[h] + boff[nj]);
        acc[0][nj] = __builtin_amdgcn_mfma_f32_16x16x32_bf16(af0, bg, acc[0][nj], 0, 0, 0);
        acc[1][nj] = __builtin_amdgcn_mfma_f32_16x16x32_bf16(af1, bg, acc[1][nj], 0, 0, 0);
      }
    }
    __syncthreads();   // readers done before next-step B overwrite
  }

  // ---- epilogue: partial over this n-half's 256 d (r6-verified) ----
  #pragma unroll
  for (int mi = 0; mi < 2; ++mi) {
    #pragma unroll
    for (int j = 0; j < 4; ++j) {
      int m = wr * 32 + mi * 16 + q * 4 + j;
      float s = 0.f;
      #pragma unroll
      for (int nj = 0; nj < 8; ++nj) {
        int d = n0 + wc * 128 + nj * 16 + cl;
        s += tanhf(acc[mi][nj][j] + hW[(size_t)(bhalf + m) * DECD + d]) * v[d];
      }
      s += __shfl_xor(s, 1, 64);
      s += __shfl_xor(s, 2, 64);
      s += __shfl_xor(s, 4, 64);
      s += __shfl_xor(s, 8, 64);
      if (cl == 0) sbuf[m][wc] = s;
    }
  }
  __syncthreads();
  if (tid < 64)
    part[(size_t)bn * M + m0 + tid] = sbuf[tid][0] + sbuf[tid][1];
}

// joint softmax fused with partial-sum (r10/r11-verified)
__global__ __launch_bounds__(256) void k_softmax_j(const float* __restrict__ part,
    int M, float* __restrict__ sc,
    const int* __restrict__ m1, const int* __restrict__ m2) {
  int b = blockIdx.x, tid = threadIdx.x;
  __shared__ float sm[4];
  int s0 = tid, s2 = tid + 256;
  float a0 = -INFINITY, a1 = -INFINITY;
  {
    int msk = (s0 < S1D) ? m1[b * S1D + s0] : m2[b * S2D + (s0 - S1D)];
    int m = s0 * 128 + b;
    a0 = msk ? (part[m] + part[M + m]) : NEGV;
  }
  if (s2 < SJD) {
    int msk = (s2 < S1D) ? m1[b * S1D + s2] : m2[b * S2D + (s2 - S1D)];
    int m = s2 * 128 + b;
    a1 = msk ? (part[m] + part[M + m]) : NEGV;
  }
  float vmax = fmaxf(a0, a1);
  #pragma unroll
  for (int off = 32; off > 0; off >>= 1) vmax = fmaxf(vmax, __shfl_down(vmax, off, 64));
  int lane = tid & 63, wid = tid >> 6;
  if (lane == 0) sm[wid] = vmax;
  __syncthreads();
  vmax = fmaxf(fmaxf(sm[0], sm[1]), fmaxf(sm[2], sm[3]));
  __syncthreads();
  float lsum = expf(a0 - vmax);
  if (s2 < SJD) lsum += expf(a1 - vmax);
  #pragma unroll
  for (int off = 32; off > 0; off >>= 1) lsum += __shfl_down(lsum, off, 64);
  if (lane == 0) sm[wid] = lsum;
  __syncthreads();
  float inv = 1.0f / (sm[0] + sm[1] + sm[2] + sm[3]);
  sc[(size_t)b * SJD + s0] = expf(a0 - vmax) * inv;
  if (s2 < SJD) sc[(size_t)b * SJD + s2] = expf(a1 - vmax) * inv;
}

// copy softmax fused with partial-sum + mask1*triple (mirror of k_softmax_j)
__global__ __launch_bounds__(256) void k_softmax_c(const float* __restrict__ part,
    int M, float* __restrict__ sc,
    const int* __restrict__ m1, const int* __restrict__ m2) {
  int b = blockIdx.x, tid = threadIdx.x;
  __shared__ float sm[4];
  float a0 = -INFINITY;
  if (tid < S1D) {
    int msk = m1[b * S1D + tid] * m2[b * S1D + tid];
    int m = tid * 128 + b;
    a0 = msk ? (part[m] + part[M + m]) : NEGV;
  }
  float vmax = a0;
  #pragma unroll
  for (int off = 32; off > 0; off >>= 1) vmax = fmaxf(vmax, __shfl_down(vmax, off, 64));
  int lane = tid & 63, wid = tid >> 6;
  if (lane == 0) sm[wid] = vmax;
  __syncthreads();
  vmax = fmaxf(fmaxf(sm[0], sm[1]), fmaxf(sm[2], sm[3]));
  __syncthreads();
  float lsum = (tid < S1D) ? expf(a0 - vmax) : 0.f;
  #pragma unroll
  for (int off = 32; off > 0; off >>= 1) lsum += __shfl_down(lsum, off, 64);
  if (lane == 0) sm[wid] = lsum;
  __syncthreads();
  float inv = 1.0f / (sm[0] + sm[1] + sm[2] + sm[3]);
  if (tid < S1D) sc[(size_t)b * S1D + tid] = expf(a0 - vmax) * inv;
}

// ---------------- fc GEMM v2 (r8-verified) ----------------
__global__ __launch_bounds__(512) void gemm_fc2(
    const u16* __restrict__ A, const float* __restrict__ Bf,
    const float* __restrict__ bias, float* __restrict__ C,
    int N, int K) {
  __shared__ u16 As[2][128 * 32];
  __shared__ u16 Bs[2][128 * 32];
  int tid = threadIdx.x;
  int wid = tid >> 6, lane = tid & 63;
  int wr = wid >> 2, wc = wid & 3;
  int n0 = blockIdx.x * 128;

  int rowa = wid * 16 + (lane >> 2);
  int ca = (lane & 3) ^ ((rowa >> 1) & 3);
  const u16* gA = A + (size_t)rowa * K + ca * 8;

  int rB = tid >> 2, cB = tid & 3;
  int gnB = n0 + rB; if (gnB >= N) gnB = N - 1;
  const float* gB = Bf + (size_t)gnB * K + cB * 8;
  int lBoff = rB * 32 + ((cB ^ ((rB >> 1) & 3)) * 8);

  int q = lane >> 4, cl = lane & 15;
  int aoff[4], boff[2];
  #pragma unroll
  for (int mi = 0; mi < 4; ++mi) {
    int row = wr * 64 + mi * 16 + cl;
    aoff[mi] = row * 64 + ((q ^ ((row >> 1) & 3)) * 16);
  }
  #pragma unroll
  for (int nj = 0; nj < 2; ++nj) {
    int rn = wc * 32 + nj * 16 + cl;
    boff[nj] = rn * 64 + ((q ^ ((rn >> 1) & 3)) * 16);
  }

  f32x4 acc[4][2];
  #pragma unroll
  for (int mi = 0; mi < 4; ++mi)
    #pragma unroll
    for (int nj = 0; nj < 2; ++nj) {
      f32x4 z = {0.f, 0.f, 0.f, 0.f};
      acc[mi][nj] = z;
    }

  for (int k0 = 0; k0 < K; k0 += 64) {
    float4 b00 = *(const float4*)(gB + k0);
    float4 b01 = *(const float4*)(gB + k0 + 4);
    float4 b10 = *(const float4*)(gB + k0 + 32);
    float4 b11 = *(const float4*)(gB + k0 + 36);
    *(u16x8*)(&Bs[0][lBoff]) = cvt8u(b00, b01);
    *(u16x8*)(&Bs[1][lBoff]) = cvt8u(b10, b11);
    async_copy16(gA + k0,      &As[0][wid * 512]);
    async_copy16(gA + k0 + 32, &As[1][wid * 512]);
    __syncthreads();
    #pragma unroll
    for (int h = 0; h < 2; ++h) {
      bf16x8 af[4], bg[2];
      #pragma unroll
      for (int mi = 0; mi < 4; ++mi) af[mi] = *(const bf16x8*)((const char*)As[h] + aoff[mi]);
      #pragma unroll
      for (int nj = 0; nj < 2; ++nj) bg[nj] = *(const bf16x8*)((const char*)Bs[h] + boff[nj]);
      #pragma unroll
      for (int mi = 0; mi < 4; ++mi)
        #pragma unroll
        for (int nj = 0; nj < 2; ++nj)
          acc[mi][nj] = __builtin_amdgcn_mfma_f32_16x16x32_bf16(af[mi], bg[nj], acc[mi][nj], 0, 0, 0);
    }
    __syncthreads();
  }

  #pragma unroll
  for (int mi = 0; mi < 4; ++mi) {
    #pragma unroll
    for (int nj = 0; nj < 2; ++nj) {
      int n = n0 + wc * 32 + nj * 16 + cl;
      if (n < N) {
        float bv = bias[n];
        #pragma unroll
        for (int j = 0; j < 4; ++j) {
          int m = wr * 64 + mi * 16 + q * 4 + j;
          C[(size_t)m * N + n] = acc[mi][nj][j] + bv;
        }
      }
    }
  }
}

// ---------------- small kernels (verified) ----------------
__global__ __launch_bounds__(256) void k_partial(const float* __restrict__ h,
    const float* __restrict__ W, const float* __restrict__ bias,
    float* __restrict__ out) {
  int b = blockIdx.y;
  int d = blockIdx.x * 256 + threadIdx.x;
  const float* hr = h + (size_t)b * DECD;
  float acc = bias[d];
  #pragma unroll 8
  for (int k = 0; k < DECD; ++k) acc += hr[k] * W[(size_t)k * DECD + d];
  out[(size_t)b * DECD + d] = acc;
}

__global__ __launch_bounds__(256) void k_wpart(const float* __restrict__ enc1,
    const float* __restrict__ enc2, const float* __restrict__ a,
    float* __restrict__ wp) {
  int b = blockIdx.x;
  int e2 = blockIdx.y * 256 + threadIdx.x;
  int scn = blockIdx.z;
  const float* arow = a + (size_t)b * SJD;
  float acc0 = 0.f, acc1 = 0.f;
  #pragma unroll 4
  for (int s = scn * 100; s < scn * 100 + 100; ++s) {
    const float* ep = (s < S1D) ? (enc1 + ((size_t)s * BB + b) * E2D)
                                : (enc2 + ((size_t)(s - S1D) * BB + b) * E2D);
    float2 u = *(const float2*)(ep + e2 * 2);
    float w = arow[s];
    acc0 += w * u.x;
    acc1 += w * u.y;
  }
  float* dst = wp + ((size_t)scn * BB + b) * E2D + e2 * 2;
  dst[0] = acc0;
  dst[1] = acc1;
}

__global__ __launch_bounds__(256) void k_wsum_x(const float* __restrict__ wp,
    float* __restrict__ wgt, u16* __restrict__ x) {
  int i = blockIdx.x * 256 + threadIdx.x;
  const int NN = BB * E2D;
  float s = wp[i] + wp[NN + i] + wp[2 * NN + i] + wp[3 * NN + i];
  wgt[i] = s;
  int b = i >> 10, e = i & 1023;
  x[(size_t)b * 1280 + EMBD + e] = f2bf(s);
}

__global__ __launch_bounds__(256) void k_embx(const int* __restrict__ inp,
    const float* __restrict__ table, u16* __restrict__ x) {
  int b = blockIdx.x, t = threadIdx.x;
  x[(size_t)b * 1280 + t] = f2bf(table[(size_t)inp[b] * EMBD + t]);
}

__global__ __launch_bounds__(256) void k_concat_state_bf(const float* __restrict__ hnew,
    const float* __restrict__ wgt, u16* __restrict__ st) {
  int b = blockIdx.x;
  for (int i = threadIdx.x; i < DECD + E2D; i += 256) {
    float vv = (i < DECD) ? hnew[(size_t)b * DECD + i] : wgt[(size_t)b * E2D + i - DECD];
    st[(size_t)b * (DECD + E2D) + i] = f2bf(vv);
  }
}

__global__ __launch_bounds__(256) void k_gru(const float* __restrict__ gx,
    const float* __restrict__ gh, const float* __restrict__ hidden,
    float* __restrict__ hnew) {
  int b = blockIdx.x, tid = threadIdx.x;
  #pragma unroll
  for (int qq = 0; qq < 2; ++qq) {
    int d = tid + qq * 256;
    size_t o = (size_t)b * 1536;
    float xr = gx[o + d],        hr = gh[o + d];
    float xz = gx[o + 512 + d],  hz = gh[o + 512 + d];
    float xn = gx[o + 1024 + d], hn = gh[o + 1024 + d];
    float r = 1.f / (1.f + expf(-(xr + hr)));
    float z = 1.f / (1.f + expf(-(xz + hz)));
    float n = tanhf(xn + r * hn);
    hnew[(size_t)b * DECD + d] = (1.f - z) * n + z * hidden[(size_t)b * DECD + d];
  }
}

__global__ __launch_bounds__(256) void k_pgen(const float* __restrict__ wgt,
    const int* __restrict__ inp, const float* __restrict__ table,
    const float* __restrict__ gW, const float* __restrict__ gb,
    float* __restrict__ pg) {
  int b = blockIdx.x, tid = threadIdx.x;
  __shared__ float sm[4];
  float s = 0.f;
  for (int k = tid; k < E2D + EMBD; k += 256)
    s += gW[k] * ((k < E2D) ? wgt[(size_t)b * E2D + k]
                            : table[(size_t)inp[b] * EMBD + k - E2D]);
  #pragma unroll
  for (int off = 32; off > 0; off >>= 1) s += __shfl_down(s, off, 64);
  int lane = tid & 63, wid = tid >> 6;
  if (lane == 0) sm[wid] = s;
  __syncthreads();
  if (tid == 0) {
    float t = sm[0] + sm[1] + sm[2] + sm[3] + gb[0];
    pg[b] = 1.f / (1.f + expf(-t));
  }
}

// vocab softmax + p_gen scale + fused copy-scatter (runs after scC ready)
__global__ __launch_bounds__(256) void k_vocab_sc(float* __restrict__ dist,
    const float* __restrict__ pg, const float* __restrict__ ad,
    const int* __restrict__ src1) {
  int b = blockIdx.x, tid = threadIdx.x;
  float* row = dist + (size_t)b * VV;
  __shared__ float sm[4];
  float m = -INFINITY;
  for (int i = tid; i < VV; i += 256) m = fmaxf(m, row[i]);
  #pragma unroll
  for (int off = 32; off > 0; off >>= 1) m = fmaxf(m, __shfl_down(m, off, 64));
  int lane = tid & 63, wid = tid >> 6;
  if (lane == 0) sm[wid] = m;
  __syncthreads();
  m = fmaxf(fmaxf(sm[0], sm[1]), fmaxf(sm[2], sm[3]));
  __syncthreads();
  float s = 0.f;
  for (int i = tid; i < VV; i += 256) s += expf(row[i] - m);
  #pragma unroll
  for (int off = 32; off > 0; off >>= 1) s += __shfl_down(s, off, 64);
  if (lane == 0) sm[wid] = s;
  __syncthreads();
  s = sm[0] + sm[1] + sm[2] + sm[3];
  float pgb = pg[b];
  float scale = pgb / s;
  for (int i = tid; i < VV; i += 256) row[i] = expf(row[i] - m) * scale;
  __syncthreads();
  if (tid < S1D) {
    float val = (1.f - pgb) * ad[(size_t)b * S1D + tid];
    int tok = src1[(size_t)tid * BB + b];
    atomicAdd(&row[tok], val);
  }
}

extern "C" void kernel_launch(void* const* d_in, const int* in_sizes, int n_in,
                              void* d_out, int out_size, void* d_ws, size_t ws_size,
                              hipStream_t stream) {
  (void)in_sizes; (void)n_in; (void)out_size; (void)ws_size;
  const int*   input  = (const int*)d_in[0];
  const float* hidden = (const float*)d_in[1];
  const int*   src1   = (const int*)d_in[2];
  const float* enc1   = (const float*)d_in[3];
  const int*   mask1  = (const int*)d_in[4];
  const int*   triple = (const int*)d_in[5];
  const float* enc2   = (const float*)d_in[6];
  const int*   mask2  = (const int*)d_in[7];
  const float* embedding = (const float*)d_in[8];
  const float* attn_W = (const float*)d_in[9];
  const float* attn_b = (const float*)d_in[10];
  const float* attn_v = (const float*)d_in[11];
  const float* copy_W = (const float*)d_in[12];
  const float* copy_b = (const float*)d_in[13];
  const float* copy_v = (const float*)d_in[14];
  const float* gru_Wih = (const float*)d_in[15];
  const float* gru_Whh = (const float*)d_in[16];
  const float* gru_bih = (const float*)d_in[17];
  const float* gru_bhh = (const float*)d_in[18];
  const float* fc_W   = (const float*)d_in[19];
  const float* fc_b   = (const float*)d_in[20];
  const float* gate_W = (const float*)d_in[21];
  const float* gate_b = (const float*)d_in[22];

  char* w = (char*)d_ws;
  u16* Wt_a = (u16*)w;                w += (size_t)512 * 1024 * 2;
  u16* Wt_c = (u16*)w;                w += (size_t)512 * 1024 * 2;
  float* partJ = (float*)w;           w += (size_t)2 * 51200 * 4;
  float* partC = (float*)w;           w += (size_t)2 * 25600 * 4;
  float* hWa  = (float*)w;            w += (size_t)BB * DECD * 4;
  float* hWc  = (float*)w;            w += (size_t)BB * DECD * 4;
  float* scJ  = (float*)w;            w += (size_t)BB * SJD * 4;
  float* scC  = (float*)w;            w += (size_t)BB * S1D * 4;
  float* wgt  = (float*)w;            w += (size_t)BB * E2D * 4;
  float* wpart = (float*)w;           w += (size_t)4 * BB * E2D * 4;
  u16*   x_bf = (u16*)w;              w += (size_t)BB * 1280 * 2;
  u16*   hid_bf = (u16*)w;            w += (size_t)BB * DECD * 2;
  float* gx   = (float*)w;            w += (size_t)BB * 1536 * 4;
  float* gh   = (float*)w;            w += (size_t)BB * 1536 * 4;
  u16*   st_bf = (u16*)w;             w += (size_t)BB * 1536 * 2;
  float* pg   = (float*)w;            w += 512;

  float* out  = (float*)d_out;
  float* hnew = out + (size_t)BB * VV;

  // prep
  k_wt<<<dim3(32, 16), 256, 0, stream>>>(attn_W, Wt_a);
  k_wt<<<dim3(32, 16), 256, 0, stream>>>(copy_W, Wt_c);
  k_cvt<<<32, 256, 0, stream>>>(hidden, hid_bf, BB * DECD / 8);
  k_partial<<<dim3(2, BB), 256, 0, stream>>>(hidden, attn_W, attn_b, hWa);
  k_embx<<<BB, 256, 0, stream>>>(input, embedding, x_bf);

  // joint attention scores (BK=64 energy GEMM)
  gemm_energy64<<<dim3(2, SJD * 2), 256, 0, stream>>>(
      enc1, enc2, Wt_a, hWa, attn_v, partJ, 51200);
  k_softmax_j<<<BB, 256, 0, stream>>>(partJ, 51200, scJ, mask1, mask2);

  // weighted context (fp32 enc reads)
  k_wpart<<<dim3(BB, 2, 4), 256, 0, stream>>>(enc1, enc2, scJ, wpart);
  k_wsum_x<<<512, 256, 0, stream>>>(wpart, wgt, x_bf);

  // GRU (bf16 MFMA with fused weight conversion)
  gemm_fc2<<<1536 / 128, 512, 0, stream>>>(x_bf, gru_Wih, gru_bih, gx, 1536, 1280);
  gemm_fc2<<<1536 / 128, 512, 0, stream>>>(hid_bf, gru_Whh, gru_bhh, gh, 1536, 512);
  k_gru<<<BB, 256, 0, stream>>>(gx, gh, hidden, hnew);

  // vocab logits
  k_concat_state_bf<<<BB, 256, 0, stream>>>(hnew, wgt, st_bf);
  gemm_fc2<<<(VV + 127) / 128, 512, 0, stream>>>(st_bf, fc_W, fc_b, out, VV, 1536);

  // copy path (BK=64 energy over enc1 only)
  k_pgen<<<BB, 256, 0, stream>>>(wgt, input, embedding, gate_W, gate_b, pg);
  k_partial<<<dim3(2, BB), 256, 0, stream>>>(hnew, copy_W, copy_b, hWc);
  gemm_energy64<<<dim3(2, S1D * 2), 256, 0, stream>>>(
      enc1, enc1, Wt_c, hWc, copy_v, partC, 25600);
  k_softmax_c<<<BB, 256, 0, stream>>>(partC, 25600, scC, mask1, triple);

  // final distribution (softmax + scale + fused scatter)
  k_vocab_sc<<<BB, 256, 0, stream>>>(out, pg, scC, src1);
}

// Round 13
// 675.337 us; speedup vs baseline: 1.1856x; 1.0137x over previous
//
#include <hip/hip_runtime.h>
#include <math.h>

#define BB   128
#define DECD 512
#define E2D  1024
#define EMBD 256
#define S1D  200
#define S2D  200
#define SJD  400
#define VV   50000
#define NEGV (-1e10f)

typedef unsigned short u16;
typedef __bf16 bf16x8 __attribute__((ext_vector_type(8)));
typedef float f32x4 __attribute__((ext_vector_type(4)));
typedef u16 u16x8 __attribute__((ext_vector_type(8)));

__device__ __forceinline__ u16 f2bf(float x) {
  unsigned u = __float_as_uint(x);
  unsigned r = (u + 0x7fffu + ((u >> 16) & 1u)) >> 16;
  return (u16)r;
}
__device__ __forceinline__ float bf2f(u16 h) {
  return __uint_as_float(((unsigned)h) << 16);
}

typedef const __attribute__((address_space(1))) void* gas_t;
typedef __attribute__((address_space(3))) void* las_t;
__device__ __forceinline__ void async_copy16(const u16* g, u16* l) {
  __builtin_amdgcn_global_load_lds((gas_t)g, (las_t)l, 16, 0, 0);
}

// ---------------- generic fp32 -> bf16 ----------------
__global__ __launch_bounds__(256) void k_cvt(const float* __restrict__ src,
    u16* __restrict__ dst, int n8) {
  int i = blockIdx.x * 256 + threadIdx.x;
  if (i >= n8) return;
  const float4 f0 = *(const float4*)(src + (size_t)i * 8);
  const float4 f1 = *(const float4*)(src + (size_t)i * 8 + 4);
  u16x8 o;
  o[0] = f2bf(f0.x); o[1] = f2bf(f0.y); o[2] = f2bf(f0.z); o[3] = f2bf(f0.w);
  o[4] = f2bf(f1.x); o[5] = f2bf(f1.y); o[6] = f2bf(f1.z); o[7] = f2bf(f1.w);
  *(u16x8*)(dst + (size_t)i * 8) = o;
}

// Wt[n][k] = bf16( W[512+k][n] )
__global__ __launch_bounds__(256) void k_wt(const float* __restrict__ W,
    u16* __restrict__ Wt) {
  __shared__ float t[32][33];
  int bk = blockIdx.x, bn = blockIdx.y;
  int tx = threadIdx.x & 31, ty = threadIdx.x >> 5;
  #pragma unroll
  for (int r = 0; r < 4; ++r) {
    int k = bk * 32 + ty + r * 8;
    t[ty + r * 8][tx] = W[(size_t)(512 + k) * 512 + bn * 32 + tx];
  }
  __syncthreads();
  #pragma unroll
  for (int r = 0; r < 4; ++r) {
    int n = bn * 32 + ty + r * 8;
    Wt[(size_t)n * 1024 + bk * 32 + tx] = f2bf(t[tx][ty + r * 8]);
  }
}

// ---------------- 4-wave fused energy GEMM, tile 64x256, N-split 2 (r6/r8-verified) ----------------
template<int CONV>
__global__ __launch_bounds__(256) void gemm_energy4(
    const float* __restrict__ enc1, const float* __restrict__ enc2,
    const u16* __restrict__ Abf_in, u16* __restrict__ Abf_out,
    const u16* __restrict__ Bt,
    const float* __restrict__ hW, const float* __restrict__ v,
    float* __restrict__ part, int M) {
  __shared__ u16 As[2][64 * 32];   // 2 x 4 KB
  __shared__ u16 Bs[256 * 32];     // 16 KB
  __shared__ float sbuf[64][2];
  int tid = threadIdx.x;
  int wid = tid >> 6, lane = tid & 63;
  int wr = wid >> 1, wc = wid & 1;
  int bn = blockIdx.x;                 // n-half: 0 or 1
  size_t m0 = (size_t)blockIdx.y * 64;
  int bhalf = (blockIdx.y & 1) * 64;   // batch-row offset within the 128-batch
  int n0 = bn * 256;

  // ---- A staging setup ----
  int rA = tid >> 2, cslot = tid & 3;            // 64 rows x 4 chunks
  const float* gA_f = nullptr;
  u16* gA_o = nullptr;
  int lAoff = rA * 32 + ((cslot ^ ((rA >> 1) & 3)) * 8);   // u16 offset, swizzled
  if (CONV) {
    const float* base = (m0 < (size_t)S1D * BB) ? (enc1 + m0 * E2D)
                                                : (enc2 + (m0 - (size_t)S1D * BB) * E2D);
    gA_f = base + (size_t)rA * E2D + cslot * 8;
    if (bn == 0) gA_o = Abf_out + (m0 + rA) * E2D + cslot * 8;
  }
  const u16* gA_b = nullptr;
  if (!CONV) {
    int rowa = wid * 16 + (lane >> 2);
    int ca = (lane & 3) ^ ((rowa >> 1) & 3);
    gA_b = Abf_in + (m0 + rowa) * E2D + ca * 8;
  }

  // ---- B staging: 4 async issues; issue i dest rows [i*64 + wid*16, +16) ----
  const u16* gB[4];
  #pragma unroll
  for (int i = 0; i < 4; ++i) {
    int rn = i * 64 + wid * 16 + (lane >> 2);
    int c = (lane & 3) ^ ((rn >> 1) & 3);
    gB[i] = Bt + (size_t)(n0 + rn) * E2D + c * 8;
  }

  // ---- fragment LDS byte offsets ----
  int q = lane >> 4, cl = lane & 15;
  int aoff[2], boff[8];
  #pragma unroll
  for (int mi = 0; mi < 2; ++mi) {
    int row = wr * 32 + mi * 16 + cl;
    aoff[mi] = row * 64 + ((q ^ ((row >> 1) & 3)) * 16);
  }
  #pragma unroll
  for (int nj = 0; nj < 8; ++nj) {
    int rn = wc * 128 + nj * 16 + cl;
    boff[nj] = rn * 64 + ((q ^ ((rn >> 1) & 3)) * 16);
  }

  f32x4 acc[2][8];
  #pragma unroll
  for (int mi = 0; mi < 2; ++mi)
    #pragma unroll
    for (int nj = 0; nj < 8; ++nj) {
      f32x4 z = {0.f, 0.f, 0.f, 0.f};
      acc[mi][nj] = z;
    }

  // ---- prologue: stage A step 0 into As[0]; prep regs for step 1 ----
  float4 a0, a1;
  if (CONV) {
    a0 = *(const float4*)(gA_f);
    a1 = *(const float4*)(gA_f + 4);
    u16x8 ob;
    ob[0] = f2bf(a0.x); ob[1] = f2bf(a0.y); ob[2] = f2bf(a0.z); ob[3] = f2bf(a0.w);
    ob[4] = f2bf(a1.x); ob[5] = f2bf(a1.y); ob[6] = f2bf(a1.z); ob[7] = f2bf(a1.w);
    *(u16x8*)(&As[0][lAoff]) = ob;
    if (bn == 0) *(u16x8*)(gA_o) = ob;
    a0 = *(const float4*)(gA_f + 32);
    a1 = *(const float4*)(gA_f + 36);
  } else {
    async_copy16(gA_b, &As[0][wid * 512]);
  }

  // ---- main loop: 32 K-steps; A dbuf, B single-buffer, 2 barriers/step ----
  for (int t = 0; t < 32; ++t) {
    int cur = t & 1, nxt = cur ^ 1;
    int k0 = t * 32, k1 = k0 + 32;
    #pragma unroll
    for (int i = 0; i < 4; ++i) async_copy16(gB[i] + k0, &Bs[2048 * i + wid * 512]);
    if (t < 31) {
      if (CONV) {
        u16x8 ob;
        ob[0] = f2bf(a0.x); ob[1] = f2bf(a0.y); ob[2] = f2bf(a0.z); ob[3] = f2bf(a0.w);
        ob[4] = f2bf(a1.x); ob[5] = f2bf(a1.y); ob[6] = f2bf(a1.z); ob[7] = f2bf(a1.w);
        *(u16x8*)(&As[nxt][lAoff]) = ob;
        if (bn == 0) *(u16x8*)(gA_o + k1) = ob;
        if (t < 30) {
          a0 = *(const float4*)(gA_f + k1 + 32);
          a1 = *(const float4*)(gA_f + k1 + 36);
        }
      } else {
        async_copy16(gA_b + k1, &As[nxt][wid * 512]);
      }
    }
    __syncthreads();   // B (and next-A) staged & visible
    bf16x8 af[2];
    #pragma unroll
    for (int mi = 0; mi < 2; ++mi)
      af[mi] = *(const bf16x8*)((const char*)As[cur] + aoff[mi]);
    #pragma unroll
    for (int nj = 0; nj < 8; ++nj) {
      bf16x8 bg = *(const bf16x8*)((const char*)Bs + boff[nj]);
      acc[0][nj] = __builtin_amdgcn_mfma_f32_16x16x32_bf16(af[0], bg, acc[0][nj], 0, 0, 0);
      acc[1][nj] = __builtin_amdgcn_mfma_f32_16x16x32_bf16(af[1], bg, acc[1][nj], 0, 0, 0);
    }
    __syncthreads();   // readers done before next-step B overwrite
  }

  // ---- epilogue: partial over this n-half's 256 d ----
  #pragma unroll
  for (int mi = 0; mi < 2; ++mi) {
    #pragma unroll
    for (int j = 0; j < 4; ++j) {
      int m = wr * 32 + mi * 16 + q * 4 + j;
      float s = 0.f;
      #pragma unroll
      for (int nj = 0; nj < 8; ++nj) {
        int d = n0 + wc * 128 + nj * 16 + cl;
        s += tanhf(acc[mi][nj][j] + hW[(size_t)(bhalf + m) * DECD + d]) * v[d];
      }
      s += __shfl_xor(s, 1, 64);
      s += __shfl_xor(s, 2, 64);
      s += __shfl_xor(s, 4, 64);
      s += __shfl_xor(s, 8, 64);
      if (cl == 0) sbuf[m][wc] = s;
    }
  }
  __syncthreads();
  if (tid < 64)
    part[(size_t)bn * M + m0 + tid] = sbuf[tid][0] + sbuf[tid][1];
}

// joint softmax fused with partial-sum (r10/r11/r12-verified)
__global__ __launch_bounds__(256) void k_softmax_j(const float* __restrict__ part,
    int M, float* __restrict__ sc,
    const int* __restrict__ m1, const int* __restrict__ m2) {
  int b = blockIdx.x, tid = threadIdx.x;
  __shared__ float sm[4];
  int s0 = tid, s2 = tid + 256;
  float a0 = -INFINITY, a1 = -INFINITY;
  {
    int msk = (s0 < S1D) ? m1[b * S1D + s0] : m2[b * S2D + (s0 - S1D)];
    int m = s0 * 128 + b;
    a0 = msk ? (part[m] + part[M + m]) : NEGV;
  }
  if (s2 < SJD) {
    int msk = (s2 < S1D) ? m1[b * S1D + s2] : m2[b * S2D + (s2 - S1D)];
    int m = s2 * 128 + b;
    a1 = msk ? (part[m] + part[M + m]) : NEGV;
  }
  float vmax = fmaxf(a0, a1);
  #pragma unroll
  for (int off = 32; off > 0; off >>= 1) vmax = fmaxf(vmax, __shfl_down(vmax, off, 64));
  int lane = tid & 63, wid = tid >> 6;
  if (lane == 0) sm[wid] = vmax;
  __syncthreads();
  vmax = fmaxf(fmaxf(sm[0], sm[1]), fmaxf(sm[2], sm[3]));
  __syncthreads();
  float lsum = expf(a0 - vmax);
  if (s2 < SJD) lsum += expf(a1 - vmax);
  #pragma unroll
  for (int off = 32; off > 0; off >>= 1) lsum += __shfl_down(lsum, off, 64);
  if (lane == 0) sm[wid] = lsum;
  __syncthreads();
  float inv = 1.0f / (sm[0] + sm[1] + sm[2] + sm[3]);
  sc[(size_t)b * SJD + s0] = expf(a0 - vmax) * inv;
  if (s2 < SJD) sc[(size_t)b * SJD + s2] = expf(a1 - vmax) * inv;
}

// copy softmax fused with partial-sum + mask1*triple (r12-verified)
__global__ __launch_bounds__(256) void k_softmax_c(const float* __restrict__ part,
    int M, float* __restrict__ sc,
    const int* __restrict__ m1, const int* __restrict__ m2) {
  int b = blockIdx.x, tid = threadIdx.x;
  __shared__ float sm[4];
  float a0 = -INFINITY;
  if (tid < S1D) {
    int msk = m1[b * S1D + tid] * m2[b * S1D + tid];
    int m = tid * 128 + b;
    a0 = msk ? (part[m] + part[M + m]) : NEGV;
  }
  float vmax = a0;
  #pragma unroll
  for (int off = 32; off > 0; off >>= 1) vmax = fmaxf(vmax, __shfl_down(vmax, off, 64));
  int lane = tid & 63, wid = tid >> 6;
  if (lane == 0) sm[wid] = vmax;
  __syncthreads();
  vmax = fmaxf(fmaxf(sm[0], sm[1]), fmaxf(sm[2], sm[3]));
  __syncthreads();
  float lsum = (tid < S1D) ? expf(a0 - vmax) : 0.f;
  #pragma unroll
  for (int off = 32; off > 0; off >>= 1) lsum += __shfl_down(lsum, off, 64);
  if (lane == 0) sm[wid] = lsum;
  __syncthreads();
  float inv = 1.0f / (sm[0] + sm[1] + sm[2] + sm[3]);
  if (tid < S1D) sc[(size_t)b * S1D + tid] = expf(a0 - vmax) * inv;
}

// ---------------- fc GEMM v2 (r8-verified) ----------------
__global__ __launch_bounds__(512) void gemm_fc2(
    const u16* __restrict__ A, const float* __restrict__ Bf,
    const float* __restrict__ bias, float* __restrict__ C,
    int N, int K) {
  __shared__ u16 As[2][128 * 32];
  __shared__ u16 Bs[2][128 * 32];
  int tid = threadIdx.x;
  int wid = tid >> 6, lane = tid & 63;
  int wr = wid >> 2, wc = wid & 3;
  int n0 = blockIdx.x * 128;

  int rowa = wid * 16 + (lane >> 2);
  int ca = (lane & 3) ^ ((rowa >> 1) & 3);
  const u16* gA = A + (size_t)rowa * K + ca * 8;

  int rB = tid >> 2, cB = tid & 3;
  int gnB = n0 + rB; if (gnB >= N) gnB = N - 1;
  const float* gB = Bf + (size_t)gnB * K + cB * 8;
  int lBoff = rB * 32 + ((cB ^ ((rB >> 1) & 3)) * 8);

  int q = lane >> 4, cl = lane & 15;
  int aoff[4], boff[2];
  #pragma unroll
  for (int mi = 0; mi < 4; ++mi) {
    int row = wr * 64 + mi * 16 + cl;
    aoff[mi] = row * 64 + ((q ^ ((row >> 1) & 3)) * 16);
  }
  #pragma unroll
  for (int nj = 0; nj < 2; ++nj) {
    int rn = wc * 32 + nj * 16 + cl;
    boff[nj] = rn * 64 + ((q ^ ((rn >> 1) & 3)) * 16);
  }

  f32x4 acc[4][2];
  #pragma unroll
  for (int mi = 0; mi < 4; ++mi)
    #pragma unroll
    for (int nj = 0; nj < 2; ++nj) {
      f32x4 z = {0.f, 0.f, 0.f, 0.f};
      acc[mi][nj] = z;
    }

  for (int k0 = 0; k0 < K; k0 += 64) {
    float4 b00 = *(const float4*)(gB + k0);
    float4 b01 = *(const float4*)(gB + k0 + 4);
    float4 b10 = *(const float4*)(gB + k0 + 32);
    float4 b11 = *(const float4*)(gB + k0 + 36);
    u16x8 o0, o1;
    o0[0] = f2bf(b00.x); o0[1] = f2bf(b00.y); o0[2] = f2bf(b00.z); o0[3] = f2bf(b00.w);
    o0[4] = f2bf(b01.x); o0[5] = f2bf(b01.y); o0[6] = f2bf(b01.z); o0[7] = f2bf(b01.w);
    o1[0] = f2bf(b10.x); o1[1] = f2bf(b10.y); o1[2] = f2bf(b10.z); o1[3] = f2bf(b10.w);
    o1[4] = f2bf(b11.x); o1[5] = f2bf(b11.y); o1[6] = f2bf(b11.z); o1[7] = f2bf(b11.w);
    *(u16x8*)(&Bs[0][lBoff]) = o0;
    *(u16x8*)(&Bs[1][lBoff]) = o1;
    async_copy16(gA + k0,      &As[0][wid * 512]);
    async_copy16(gA + k0 + 32, &As[1][wid * 512]);
    __syncthreads();
    #pragma unroll
    for (int h = 0; h < 2; ++h) {
      bf16x8 af[4], bg[2];
      #pragma unroll
      for (int mi = 0; mi < 4; ++mi) af[mi] = *(const bf16x8*)((const char*)As[h] + aoff[mi]);
      #pragma unroll
      for (int nj = 0; nj < 2; ++nj) bg[nj] = *(const bf16x8*)((const char*)Bs[h] + boff[nj]);
      #pragma unroll
      for (int mi = 0; mi < 4; ++mi)
        #pragma unroll
        for (int nj = 0; nj < 2; ++nj)
          acc[mi][nj] = __builtin_amdgcn_mfma_f32_16x16x32_bf16(af[mi], bg[nj], acc[mi][nj], 0, 0, 0);
    }
    __syncthreads();
  }

  #pragma unroll
  for (int mi = 0; mi < 4; ++mi) {
    #pragma unroll
    for (int nj = 0; nj < 2; ++nj) {
      int n = n0 + wc * 32 + nj * 16 + cl;
      if (n < N) {
        float bv = bias[n];
        #pragma unroll
        for (int j = 0; j < 4; ++j) {
          int m = wr * 64 + mi * 16 + q * 4 + j;
          C[(size_t)m * N + n] = acc[mi][nj][j] + bv;
        }
      }
    }
  }
}

// ---------------- small kernels (r8-verified) ----------------
__global__ __launch_bounds__(256) void k_partial(const float* __restrict__ h,
    const float* __restrict__ W, const float* __restrict__ bias,
    float* __restrict__ out) {
  int b = blockIdx.y;
  int d = blockIdx.x * 256 + threadIdx.x;
  const float* hr = h + (size_t)b * DECD;
  float acc = bias[d];
  #pragma unroll 8
  for (int k = 0; k < DECD; ++k) acc += hr[k] * W[(size_t)k * DECD + d];
  out[(size_t)b * DECD + d] = acc;
}

// weighted partials over s-chunks of 100, bf16 A_bf reads (r8-verified)
__global__ __launch_bounds__(256) void k_wpart(const u16* __restrict__ A,
    const float* __restrict__ a, float* __restrict__ wp) {
  int b = blockIdx.x;
  int e2 = blockIdx.y * 256 + threadIdx.x;
  int scn = blockIdx.z;
  const float* arow = a + (size_t)b * SJD;
  float acc0 = 0.f, acc1 = 0.f;
  #pragma unroll 4
  for (int s = scn * 100; s < scn * 100 + 100; ++s) {
    unsigned u = *(const unsigned*)(A + ((size_t)s * BB + b) * E2D + e2 * 2);
    float w = arow[s];
    acc0 += w * bf2f((u16)(u & 0xffff));
    acc1 += w * bf2f((u16)(u >> 16));
  }
  float* dst = wp + ((size_t)scn * BB + b) * E2D + e2 * 2;
  dst[0] = acc0;
  dst[1] = acc1;
}

__global__ __launch_bounds__(256) void k_wsum_x(const float* __restrict__ wp,
    float* __restrict__ wgt, u16* __restrict__ x) {
  int i = blockIdx.x * 256 + threadIdx.x;
  const int NN = BB * E2D;
  float s = wp[i] + wp[NN + i] + wp[2 * NN + i] + wp[3 * NN + i];
  wgt[i] = s;
  int b = i >> 10, e = i & 1023;
  x[(size_t)b * 1280 + EMBD + e] = f2bf(s);
}

__global__ __launch_bounds__(256) void k_embx(const int* __restrict__ inp,
    const float* __restrict__ table, u16* __restrict__ x) {
  int b = blockIdx.x, t = threadIdx.x;
  x[(size_t)b * 1280 + t] = f2bf(table[(size_t)inp[b] * EMBD + t]);
}

__global__ __launch_bounds__(256) void k_concat_state_bf(const float* __restrict__ hnew,
    const float* __restrict__ wgt, u16* __restrict__ st) {
  int b = blockIdx.x;
  for (int i = threadIdx.x; i < DECD + E2D; i += 256) {
    float vv = (i < DECD) ? hnew[(size_t)b * DECD + i] : wgt[(size_t)b * E2D + i - DECD];
    st[(size_t)b * (DECD + E2D) + i] = f2bf(vv);
  }
}

__global__ __launch_bounds__(256) void k_gru(const float* __restrict__ gx,
    const float* __restrict__ gh, const float* __restrict__ hidden,
    float* __restrict__ hnew) {
  int b = blockIdx.x, tid = threadIdx.x;
  #pragma unroll
  for (int qq = 0; qq < 2; ++qq) {
    int d = tid + qq * 256;
    size_t o = (size_t)b * 1536;
    float xr = gx[o + d],        hr = gh[o + d];
    float xz = gx[o + 512 + d],  hz = gh[o + 512 + d];
    float xn = gx[o + 1024 + d], hn = gh[o + 1024 + d];
    float r = 1.f / (1.f + expf(-(xr + hr)));
    float z = 1.f / (1.f + expf(-(xz + hz)));
    float n = tanhf(xn + r * hn);
    hnew[(size_t)b * DECD + d] = (1.f - z) * n + z * hidden[(size_t)b * DECD + d];
  }
}

__global__ __launch_bounds__(256) void k_pgen(const float* __restrict__ wgt,
    const int* __restrict__ inp, const float* __restrict__ table,
    const float* __restrict__ gW, const float* __restrict__ gb,
    float* __restrict__ pg) {
  int b = blockIdx.x, tid = threadIdx.x;
  __shared__ float sm[4];
  float s = 0.f;
  for (int k = tid; k < E2D + EMBD; k += 256)
    s += gW[k] * ((k < E2D) ? wgt[(size_t)b * E2D + k]
                            : table[(size_t)inp[b] * EMBD + k - E2D]);
  #pragma unroll
  for (int off = 32; off > 0; off >>= 1) s += __shfl_down(s, off, 64);
  int lane = tid & 63, wid = tid >> 6;
  if (lane == 0) sm[wid] = s;
  __syncthreads();
  if (tid == 0) {
    float t = sm[0] + sm[1] + sm[2] + sm[3] + gb[0];
    pg[b] = 1.f / (1.f + expf(-t));
  }
}

// vocab softmax + p_gen scale + fused copy-scatter (r12-verified)
__global__ __launch_bounds__(256) void k_vocab_sc(float* __restrict__ dist,
    const float* __restrict__ pg, const float* __restrict__ ad,
    const int* __restrict__ src1) {
  int b = blockIdx.x, tid = threadIdx.x;
  float* row = dist + (size_t)b * VV;
  __shared__ float sm[4];
  float m = -INFINITY;
  for (int i = tid; i < VV; i += 256) m = fmaxf(m, row[i]);
  #pragma unroll
  for (int off = 32; off > 0; off >>= 1) m = fmaxf(m, __shfl_down(m, off, 64));
  int lane = tid & 63, wid = tid >> 6;
  if (lane == 0) sm[wid] = m;
  __syncthreads();
  m = fmaxf(fmaxf(sm[0], sm[1]), fmaxf(sm[2], sm[3]));
  __syncthreads();
  float s = 0.f;
  for (int i = tid; i < VV; i += 256) s += expf(row[i] - m);
  #pragma unroll
  for (int off = 32; off > 0; off >>= 1) s += __shfl_down(s, off, 64);
  if (lane == 0) sm[wid] = s;
  __syncthreads();
  s = sm[0] + sm[1] + sm[2] + sm[3];
  float pgb = pg[b];
  float scale = pgb / s;
  for (int i = tid; i < VV; i += 256) row[i] = expf(row[i] - m) * scale;
  __syncthreads();
  if (tid < S1D) {
    float val = (1.f - pgb) * ad[(size_t)b * S1D + tid];
    int tok = src1[(size_t)tid * BB + b];
    atomicAdd(&row[tok], val);
  }
}

extern "C" void kernel_launch(void* const* d_in, const int* in_sizes, int n_in,
                              void* d_out, int out_size, void* d_ws, size_t ws_size,
                              hipStream_t stream) {
  (void)in_sizes; (void)n_in; (void)out_size; (void)ws_size;
  const int*   input  = (const int*)d_in[0];
  const float* hidden = (const float*)d_in[1];
  const int*   src1   = (const int*)d_in[2];
  const float* enc1   = (const float*)d_in[3];
  const int*   mask1  = (const int*)d_in[4];
  const int*   triple = (const int*)d_in[5];
  const float* enc2   = (const float*)d_in[6];
  const int*   mask2  = (const int*)d_in[7];
  const float* embedding = (const float*)d_in[8];
  const float* attn_W = (const float*)d_in[9];
  const float* attn_b = (const float*)d_in[10];
  const float* attn_v = (const float*)d_in[11];
  const float* copy_W = (const float*)d_in[12];
  const float* copy_b = (const float*)d_in[13];
  const float* copy_v = (const float*)d_in[14];
  const float* gru_Wih = (const float*)d_in[15];
  const float* gru_Whh = (const float*)d_in[16];
  const float* gru_bih = (const float*)d_in[17];
  const float* gru_bhh = (const float*)d_in[18];
  const float* fc_W   = (const float*)d_in[19];
  const float* fc_b   = (const float*)d_in[20];
  const float* gate_W = (const float*)d_in[21];
  const float* gate_b = (const float*)d_in[22];

  char* w = (char*)d_ws;
  u16* A_bf = (u16*)w;                w += (size_t)51200 * 1024 * 2;
  u16* Wt_a = (u16*)w;                w += (size_t)512 * 1024 * 2;
  u16* Wt_c = (u16*)w;                w += (size_t)512 * 1024 * 2;
  float* partJ = (float*)w;           w += (size_t)2 * 51200 * 4;
  float* partC = (float*)w;           w += (size_t)2 * 25600 * 4;
  float* hWa  = (float*)w;            w += (size_t)BB * DECD * 4;
  float* hWc  = (float*)w;            w += (size_t)BB * DECD * 4;
  float* scJ  = (float*)w;            w += (size_t)BB * SJD * 4;
  float* scC  = (float*)w;            w += (size_t)BB * S1D * 4;
  float* wgt  = (float*)w;            w += (size_t)BB * E2D * 4;
  float* wpart = (float*)w;           w += (size_t)4 * BB * E2D * 4;
  u16*   x_bf = (u16*)w;              w += (size_t)BB * 1280 * 2;
  u16*   hid_bf = (u16*)w;            w += (size_t)BB * DECD * 2;
  float* gx   = (float*)w;            w += (size_t)BB * 1536 * 4;
  float* gh   = (float*)w;            w += (size_t)BB * 1536 * 4;
  u16*   st_bf = (u16*)w;             w += (size_t)BB * 1536 * 2;
  float* pg   = (float*)w;            w += 512;

  float* out  = (float*)d_out;
  float* hnew = out + (size_t)BB * VV;

  // prep
  k_wt<<<dim3(32, 16), 256, 0, stream>>>(attn_W, Wt_a);
  k_wt<<<dim3(32, 16), 256, 0, stream>>>(copy_W, Wt_c);
  k_cvt<<<32, 256, 0, stream>>>(hidden, hid_bf, BB * DECD / 8);
  k_partial<<<dim3(2, BB), 256, 0, stream>>>(hidden, attn_W, attn_b, hWa);
  k_embx<<<BB, 256, 0, stream>>>(input, embedding, x_bf);

  // joint attention scores (+ enc -> bf16 conversion side effect on n-half 0)
  gemm_energy4<1><<<dim3(2, SJD * 2), 256, 0, stream>>>(
      enc1, enc2, nullptr, A_bf, Wt_a, hWa, attn_v, partJ, 51200);
  k_softmax_j<<<BB, 256, 0, stream>>>(partJ, 51200, scJ, mask1, mask2);

  // weighted context (bf16 A_bf reads)
  k_wpart<<<dim3(BB, 2, 4), 256, 0, stream>>>(A_bf, scJ, wpart);
  k_wsum_x<<<512, 256, 0, stream>>>(wpart, wgt, x_bf);

  // GRU (bf16 MFMA with fused weight conversion)
  gemm_fc2<<<1536 / 128, 512, 0, stream>>>(x_bf, gru_Wih, gru_bih, gx, 1536, 1280);
  gemm_fc2<<<1536 / 128, 512, 0, stream>>>(hid_bf, gru_Whh, gru_bhh, gh, 1536, 512);
  k_gru<<<BB, 256, 0, stream>>>(gx, gh, hidden, hnew);

  // vocab logits
  k_concat_state_bf<<<BB, 256, 0, stream>>>(hnew, wgt, st_bf);
  gemm_fc2<<<(VV + 127) / 128, 512, 0, stream>>>(st_bf, fc_W, fc_b, out, VV, 1536);

  // copy path (bf16 A_bf energy over enc1 rows)
  k_pgen<<<BB, 256, 0, stream>>>(wgt, input, embedding, gate_W, gate_b, pg);
  k_partial<<<dim3(2, BB), 256, 0, stream>>>(hnew, copy_W, copy_b, hWc);
  gemm_energy4<0><<<dim3(2, S1D * 2), 256, 0, stream>>>(
      nullptr, nullptr, A_bf, nullptr, Wt_c, hWc, copy_v, partC, 25600);
  k_softmax_c<<<BB, 256, 0, stream>>>(partC, 25600, scC, mask1, triple);

  // final distribution (softmax + scale + fused scatter)
  k_vocab_sc<<<BB, 256, 0, stream>>>(out, pg, scC, src1);
}

// Round 14
// 633.258 us; speedup vs baseline: 1.2643x; 1.0664x over previous
//
#include <hip/hip_runtime.h>
#include <math.h>

#define BB   128
#define DECD 512
#define E2D  1024
#define EMBD 256
#define S1D  200
#define S2D  200
#define SJD  400
#define VV   50000
#define NEGV (-1e10f)
#define JY   800   // joint tiles (51200 rows / 64); copy tiles follow

typedef unsigned short u16;
typedef __bf16 bf16x8 __attribute__((ext_vector_type(8)));
typedef float f32x4 __attribute__((ext_vector_type(4)));
typedef u16 u16x8 __attribute__((ext_vector_type(8)));

__device__ __forceinline__ u16 f2bf(float x) {
  unsigned u = __float_as_uint(x);
  unsigned r = (u + 0x7fffu + ((u >> 16) & 1u)) >> 16;
  return (u16)r;
}
__device__ __forceinline__ float bf2f(u16 h) {
  return __uint_as_float(((unsigned)h) << 16);
}

typedef const __attribute__((address_space(1))) void* gas_t;
typedef __attribute__((address_space(3))) void* las_t;
__device__ __forceinline__ void async_copy16(const u16* g, u16* l) {
  __builtin_amdgcn_global_load_lds((gas_t)g, (las_t)l, 16, 0, 0);
}

// ---------------- generic fp32 -> bf16 ----------------
__global__ __launch_bounds__(256) void k_cvt(const float* __restrict__ src,
    u16* __restrict__ dst, int n8) {
  int i = blockIdx.x * 256 + threadIdx.x;
  if (i >= n8) return;
  const float4 f0 = *(const float4*)(src + (size_t)i * 8);
  const float4 f1 = *(const float4*)(src + (size_t)i * 8 + 4);
  u16x8 o;
  o[0] = f2bf(f0.x); o[1] = f2bf(f0.y); o[2] = f2bf(f0.z); o[3] = f2bf(f0.w);
  o[4] = f2bf(f1.x); o[5] = f2bf(f1.y); o[6] = f2bf(f1.z); o[7] = f2bf(f1.w);
  *(u16x8*)(dst + (size_t)i * 8) = o;
}

// Wt[n][k] = bf16( W[512+k][n] )
__global__ __launch_bounds__(256) void k_wt(const float* __restrict__ W,
    u16* __restrict__ Wt) {
  __shared__ float t[32][33];
  int bk = blockIdx.x, bn = blockIdx.y;
  int tx = threadIdx.x & 31, ty = threadIdx.x >> 5;
  #pragma unroll
  for (int r = 0; r < 4; ++r) {
    int k = bk * 32 + ty + r * 8;
    t[ty + r * 8][tx] = W[(size_t)(512 + k) * 512 + bn * 32 + tx];
  }
  __syncthreads();
  #pragma unroll
  for (int r = 0; r < 4; ++r) {
    int n = bn * 32 + ty + r * 8;
    Wt[(size_t)n * 1024 + bk * 32 + tx] = f2bf(t[tx][ty + r * 8]);
  }
}

// ---------------- combined joint+copy energy GEMM (r6/r8-verified core) ----------------
// grid (2, 1200): blockIdx.y < JY -> joint tile (attn epilogue -> partJ);
//                 blockIdx.y >= JY -> copy tile over enc1 (raw store -> preC).
// tile 64x256, 4 waves 2Mx2N, acc[2][8]; A: fp32 reg-convert, dbuf; B: 16KB single-buffer.
__global__ __launch_bounds__(256) void gemm_energy_jc(
    const float* __restrict__ enc1, const float* __restrict__ enc2,
    const u16* __restrict__ BtA, const u16* __restrict__ BtC,
    const float* __restrict__ hW, const float* __restrict__ v,
    float* __restrict__ partJ, float* __restrict__ preC) {
  __shared__ u16 As[2][64 * 32];   // 2 x 4 KB
  __shared__ u16 Bs[256 * 32];     // 16 KB
  __shared__ float sbuf[64][2];
  int tid = threadIdx.x;
  int wid = tid >> 6, lane = tid & 63;
  int wr = wid >> 1, wc = wid & 1;
  int bn = blockIdx.x;                 // n-half: 0 or 1
  int jy = blockIdx.y;
  int joint = (jy < JY);
  size_t m0 = joint ? (size_t)jy * 64 : (size_t)(jy - JY) * 64;
  int bhalf = (jy & 1) * 64;           // batch-row offset (joint only)
  int n0 = bn * 256;

  // ---- A staging (fp32 reg-convert path) ----
  int rA = tid >> 2, cslot = tid & 3;            // 64 rows x 4 chunks
  int lAoff = rA * 32 + ((cslot ^ ((rA >> 1) & 3)) * 8);   // u16 offset, swizzled
  const float* base;
  if (joint)
    base = (m0 < (size_t)S1D * BB) ? (enc1 + m0 * E2D)
                                   : (enc2 + (m0 - (size_t)S1D * BB) * E2D);
  else
    base = enc1 + m0 * E2D;
  const float* gA_f = base + (size_t)rA * E2D + cslot * 8;

  // ---- B staging: 4 async issues; issue i dest rows [i*64 + wid*16, +16) ----
  const u16* Bt = joint ? BtA : BtC;
  const u16* gB[4];
  #pragma unroll
  for (int i = 0; i < 4; ++i) {
    int rn = i * 64 + wid * 16 + (lane >> 2);
    int c = (lane & 3) ^ ((rn >> 1) & 3);
    gB[i] = Bt + (size_t)(n0 + rn) * E2D + c * 8;
  }

  // ---- fragment LDS byte offsets ----
  int q = lane >> 4, cl = lane & 15;
  int aoff[2], boff[8];
  #pragma unroll
  for (int mi = 0; mi < 2; ++mi) {
    int row = wr * 32 + mi * 16 + cl;
    aoff[mi] = row * 64 + ((q ^ ((row >> 1) & 3)) * 16);
  }
  #pragma unroll
  for (int nj = 0; nj < 8; ++nj) {
    int rn = wc * 128 + nj * 16 + cl;
    boff[nj] = rn * 64 + ((q ^ ((rn >> 1) & 3)) * 16);
  }

  f32x4 acc[2][8];
  #pragma unroll
  for (int mi = 0; mi < 2; ++mi)
    #pragma unroll
    for (int nj = 0; nj < 8; ++nj) {
      f32x4 z = {0.f, 0.f, 0.f, 0.f};
      acc[mi][nj] = z;
    }

  // ---- prologue: stage A step 0 into As[0]; prep regs for step 1 ----
  float4 a0 = *(const float4*)(gA_f);
  float4 a1 = *(const float4*)(gA_f + 4);
  {
    u16x8 ob;
    ob[0] = f2bf(a0.x); ob[1] = f2bf(a0.y); ob[2] = f2bf(a0.z); ob[3] = f2bf(a0.w);
    ob[4] = f2bf(a1.x); ob[5] = f2bf(a1.y); ob[6] = f2bf(a1.z); ob[7] = f2bf(a1.w);
    *(u16x8*)(&As[0][lAoff]) = ob;
  }
  a0 = *(const float4*)(gA_f + 32);
  a1 = *(const float4*)(gA_f + 36);

  // ---- main loop: 32 K-steps; A dbuf, B single-buffer, 2 barriers/step ----
  for (int t = 0; t < 32; ++t) {
    int cur = t & 1, nxt = cur ^ 1;
    int k0 = t * 32, k1 = k0 + 32;
    #pragma unroll
    for (int i = 0; i < 4; ++i) async_copy16(gB[i] + k0, &Bs[2048 * i + wid * 512]);
    if (t < 31) {
      u16x8 ob;
      ob[0] = f2bf(a0.x); ob[1] = f2bf(a0.y); ob[2] = f2bf(a0.z); ob[3] = f2bf(a0.w);
      ob[4] = f2bf(a1.x); ob[5] = f2bf(a1.y); ob[6] = f2bf(a1.z); ob[7] = f2bf(a1.w);
      *(u16x8*)(&As[nxt][lAoff]) = ob;
      if (t < 30) {
        a0 = *(const float4*)(gA_f + k1 + 32);
        a1 = *(const float4*)(gA_f + k1 + 36);
      }
    }
    __syncthreads();   // B (and next-A) staged & visible
    bf16x8 af[2];
    #pragma unroll
    for (int mi = 0; mi < 2; ++mi)
      af[mi] = *(const bf16x8*)((const char*)As[cur] + aoff[mi]);
    #pragma unroll
    for (int nj = 0; nj < 8; ++nj) {
      bf16x8 bg = *(const bf16x8*)((const char*)Bs + boff[nj]);
      acc[0][nj] = __builtin_amdgcn_mfma_f32_16x16x32_bf16(af[0], bg, acc[0][nj], 0, 0, 0);
      acc[1][nj] = __builtin_amdgcn_mfma_f32_16x16x32_bf16(af[1], bg, acc[1][nj], 0, 0, 0);
    }
    __syncthreads();   // readers done before next-step B overwrite
  }

  if (joint) {
    // ---- attn epilogue: sum_d tanh(acc + hW)*v over this n-half (r6-verified) ----
    #pragma unroll
    for (int mi = 0; mi < 2; ++mi) {
      #pragma unroll
      for (int j = 0; j < 4; ++j) {
        int m = wr * 32 + mi * 16 + q * 4 + j;
        float s = 0.f;
        #pragma unroll
        for (int nj = 0; nj < 8; ++nj) {
          int d = n0 + wc * 128 + nj * 16 + cl;
          s += tanhf(acc[mi][nj][j] + hW[(size_t)(bhalf + m) * DECD + d]) * v[d];
        }
        s += __shfl_xor(s, 1, 64);
        s += __shfl_xor(s, 2, 64);
        s += __shfl_xor(s, 4, 64);
        s += __shfl_xor(s, 8, 64);
        if (cl == 0) sbuf[m][wc] = s;
      }
    }
    __syncthreads();
    if (tid < 64)
      partJ[(size_t)bn * 51200 + m0 + tid] = sbuf[tid][0] + sbuf[tid][1];
  } else {
    // ---- copy epilogue: raw pre-activation store (r10-verified layout) ----
    #pragma unroll
    for (int mi = 0; mi < 2; ++mi) {
      #pragma unroll
      for (int nj = 0; nj < 8; ++nj) {
        int d = n0 + wc * 128 + nj * 16 + cl;
        #pragma unroll
        for (int j = 0; j < 4; ++j) {
          int m = wr * 32 + mi * 16 + q * 4 + j;
          preC[(m0 + m) * (size_t)DECD + d] = acc[mi][nj][j];
        }
      }
    }
  }
}

// copy epilogue: scC[b][s] = sum_d tanh(preC[r][d] + hWc[b][d]) * v[d], r = s*128+b (r10-verified)
__global__ __launch_bounds__(256) void k_copy_epi(const float* __restrict__ preC,
    const float* __restrict__ hWc, const float* __restrict__ v,
    float* __restrict__ scC) {
  int r = blockIdx.x * 4 + (threadIdx.x >> 6);
  int lane = threadIdx.x & 63;
  int b = r & 127, s = r >> 7;
  const float* pr = preC + (size_t)r * DECD + lane * 8;
  const float* hr = hWc + (size_t)b * DECD + lane * 8;
  const float* vr = v + lane * 8;
  float4 p0 = *(const float4*)(pr),     p1 = *(const float4*)(pr + 4);
  float4 h0 = *(const float4*)(hr),     h1 = *(const float4*)(hr + 4);
  float4 v0 = *(const float4*)(vr),     v1 = *(const float4*)(vr + 4);
  float acc = tanhf(p0.x + h0.x) * v0.x + tanhf(p0.y + h0.y) * v0.y
            + tanhf(p0.z + h0.z) * v0.z + tanhf(p0.w + h0.w) * v0.w
            + tanhf(p1.x + h1.x) * v1.x + tanhf(p1.y + h1.y) * v1.y
            + tanhf(p1.z + h1.z) * v1.z + tanhf(p1.w + h1.w) * v1.w;
  #pragma unroll
  for (int off = 32; off > 0; off >>= 1) acc += __shfl_xor(acc, off, 64);
  if (lane == 0) scC[(size_t)b * S1D + s] = acc;
}

// joint softmax fused with partial-sum (r10-r13-verified)
__global__ __launch_bounds__(256) void k_softmax_j(const float* __restrict__ part,
    int M, float* __restrict__ sc,
    const int* __restrict__ m1, const int* __restrict__ m2) {
  int b = blockIdx.x, tid = threadIdx.x;
  __shared__ float sm[4];
  int s0 = tid, s2 = tid + 256;
  float a0 = -INFINITY, a1 = -INFINITY;
  {
    int msk = (s0 < S1D) ? m1[b * S1D + s0] : m2[b * S2D + (s0 - S1D)];
    int m = s0 * 128 + b;
    a0 = msk ? (part[m] + part[M + m]) : NEGV;
  }
  if (s2 < SJD) {
    int msk = (s2 < S1D) ? m1[b * S1D + s2] : m2[b * S2D + (s2 - S1D)];
    int m = s2 * 128 + b;
    a1 = msk ? (part[m] + part[M + m]) : NEGV;
  }
  float vmax = fmaxf(a0, a1);
  #pragma unroll
  for (int off = 32; off > 0; off >>= 1) vmax = fmaxf(vmax, __shfl_down(vmax, off, 64));
  int lane = tid & 63, wid = tid >> 6;
  if (lane == 0) sm[wid] = vmax;
  __syncthreads();
  vmax = fmaxf(fmaxf(sm[0], sm[1]), fmaxf(sm[2], sm[3]));
  __syncthreads();
  float lsum = expf(a0 - vmax);
  if (s2 < SJD) lsum += expf(a1 - vmax);
  #pragma unroll
  for (int off = 32; off > 0; off >>= 1) lsum += __shfl_down(lsum, off, 64);
  if (lane == 0) sm[wid] = lsum;
  __syncthreads();
  float inv = 1.0f / (sm[0] + sm[1] + sm[2] + sm[3]);
  sc[(size_t)b * SJD + s0] = expf(a0 - vmax) * inv;
  if (s2 < SJD) sc[(size_t)b * SJD + s2] = expf(a1 - vmax) * inv;
}

// copy-path masked softmax, in place (r10-verified)
__global__ __launch_bounds__(256) void k_softmax_s(float* __restrict__ sc, int S,
    const int* __restrict__ m1, const int* __restrict__ m2) {
  int b = blockIdx.x, tid = threadIdx.x;
  __shared__ float sm[4];
  int s0 = tid;
  float a0 = -INFINITY;
  if (s0 < S) {
    int msk = m1[b * S + s0] * m2[b * S + s0];
    a0 = msk ? sc[(size_t)b * S + s0] : NEGV;
  }
  float vmax = a0;
  #pragma unroll
  for (int off = 32; off > 0; off >>= 1) vmax = fmaxf(vmax, __shfl_down(vmax, off, 64));
  int lane = tid & 63, wid = tid >> 6;
  if (lane == 0) sm[wid] = vmax;
  __syncthreads();
  vmax = fmaxf(fmaxf(sm[0], sm[1]), fmaxf(sm[2], sm[3]));
  __syncthreads();
  float lsum = (s0 < S) ? expf(a0 - vmax) : 0.f;
  #pragma unroll
  for (int off = 32; off > 0; off >>= 1) lsum += __shfl_down(lsum, off, 64);
  if (lane == 0) sm[wid] = lsum;
  __syncthreads();
  float inv = 1.0f / (sm[0] + sm[1] + sm[2] + sm[3]);
  if (s0 < S) sc[(size_t)b * S + s0] = expf(a0 - vmax) * inv;
}

// ---------------- fc GEMM v2 (r8-verified) ----------------
__global__ __launch_bounds__(512) void gemm_fc2(
    const u16* __restrict__ A, const float* __restrict__ Bf,
    const float* __restrict__ bias, float* __restrict__ C,
    int N, int K) {
  __shared__ u16 As[2][128 * 32];
  __shared__ u16 Bs[2][128 * 32];
  int tid = threadIdx.x;
  int wid = tid >> 6, lane = tid & 63;
  int wr = wid >> 2, wc = wid & 3;
  int n0 = blockIdx.x * 128;

  int rowa = wid * 16 + (lane >> 2);
  int ca = (lane & 3) ^ ((rowa >> 1) & 3);
  const u16* gA = A + (size_t)rowa * K + ca * 8;

  int rB = tid >> 2, cB = tid & 3;
  int gnB = n0 + rB; if (gnB >= N) gnB = N - 1;
  const float* gB = Bf + (size_t)gnB * K + cB * 8;
  int lBoff = rB * 32 + ((cB ^ ((rB >> 1) & 3)) * 8);

  int q = lane >> 4, cl = lane & 15;
  int aoff[4], boff[2];
  #pragma unroll
  for (int mi = 0; mi < 4; ++mi) {
    int row = wr * 64 + mi * 16 + cl;
    aoff[mi] = row * 64 + ((q ^ ((row >> 1) & 3)) * 16);
  }
  #pragma unroll
  for (int nj = 0; nj < 2; ++nj) {
    int rn = wc * 32 + nj * 16 + cl;
    boff[nj] = rn * 64 + ((q ^ ((rn >> 1) & 3)) * 16);
  }

  f32x4 acc[4][2];
  #pragma unroll
  for (int mi = 0; mi < 4; ++mi)
    #pragma unroll
    for (int nj = 0; nj < 2; ++nj) {
      f32x4 z = {0.f, 0.f, 0.f, 0.f};
      acc[mi][nj] = z;
    }

  for (int k0 = 0; k0 < K; k0 += 64) {
    float4 b00 = *(const float4*)(gB + k0);
    float4 b01 = *(const float4*)(gB + k0 + 4);
    float4 b10 = *(const float4*)(gB + k0 + 32);
    float4 b11 = *(const float4*)(gB + k0 + 36);
    u16x8 o0, o1;
    o0[0] = f2bf(b00.x); o0[1] = f2bf(b00.y); o0[2] = f2bf(b00.z); o0[3] = f2bf(b00.w);
    o0[4] = f2bf(b01.x); o0[5] = f2bf(b01.y); o0[6] = f2bf(b01.z); o0[7] = f2bf(b01.w);
    o1[0] = f2bf(b10.x); o1[1] = f2bf(b10.y); o1[2] = f2bf(b10.z); o1[3] = f2bf(b10.w);
    o1[4] = f2bf(b11.x); o1[5] = f2bf(b11.y); o1[6] = f2bf(b11.z); o1[7] = f2bf(b11.w);
    *(u16x8*)(&Bs[0][lBoff]) = o0;
    *(u16x8*)(&Bs[1][lBoff]) = o1;
    async_copy16(gA + k0,      &As[0][wid * 512]);
    async_copy16(gA + k0 + 32, &As[1][wid * 512]);
    __syncthreads();
    #pragma unroll
    for (int h = 0; h < 2; ++h) {
      bf16x8 af[4], bg[2];
      #pragma unroll
      for (int mi = 0; mi < 4; ++mi) af[mi] = *(const bf16x8*)((const char*)As[h] + aoff[mi]);
      #pragma unroll
      for (int nj = 0; nj < 2; ++nj) bg[nj] = *(const bf16x8*)((const char*)Bs[h] + boff[nj]);
      #pragma unroll
      for (int mi = 0; mi < 4; ++mi)
        #pragma unroll
        for (int nj = 0; nj < 2; ++nj)
          acc[mi][nj] = __builtin_amdgcn_mfma_f32_16x16x32_bf16(af[mi], bg[nj], acc[mi][nj], 0, 0, 0);
    }
    __syncthreads();
  }

  #pragma unroll
  for (int mi = 0; mi < 4; ++mi) {
    #pragma unroll
    for (int nj = 0; nj < 2; ++nj) {
      int n = n0 + wc * 32 + nj * 16 + cl;
      if (n < N) {
        float bv = bias[n];
        #pragma unroll
        for (int j = 0; j < 4; ++j) {
          int m = wr * 64 + mi * 16 + q * 4 + j;
          C[(size_t)m * N + n] = acc[mi][nj][j] + bv;
        }
      }
    }
  }
}

// ---------------- small kernels (verified) ----------------
__global__ __launch_bounds__(256) void k_partial(const float* __restrict__ h,
    const float* __restrict__ W, const float* __restrict__ bias,
    float* __restrict__ out) {
  int b = blockIdx.y;
  int d = blockIdx.x * 256 + threadIdx.x;
  const float* hr = h + (size_t)b * DECD;
  float acc = bias[d];
  #pragma unroll 8
  for (int k = 0; k < DECD; ++k) acc += hr[k] * W[(size_t)k * DECD + d];
  out[(size_t)b * DECD + d] = acc;
}

// weighted partials over s-chunks of 100, fp32 enc reads (r9-verified)
__global__ __launch_bounds__(256) void k_wpart(const float* __restrict__ enc1,
    const float* __restrict__ enc2, const float* __restrict__ a,
    float* __restrict__ wp) {
  int b = blockIdx.x;
  int e2 = blockIdx.y * 256 + threadIdx.x;
  int scn = blockIdx.z;
  const float* arow = a + (size_t)b * SJD;
  float acc0 = 0.f, acc1 = 0.f;
  #pragma unroll 4
  for (int s = scn * 100; s < scn * 100 + 100; ++s) {
    const float* ep = (s < S1D) ? (enc1 + ((size_t)s * BB + b) * E2D)
                                : (enc2 + ((size_t)(s - S1D) * BB + b) * E2D);
    float2 u = *(const float2*)(ep + e2 * 2);
    float w = arow[s];
    acc0 += w * u.x;
    acc1 += w * u.y;
  }
  float* dst = wp + ((size_t)scn * BB + b) * E2D + e2 * 2;
  dst[0] = acc0;
  dst[1] = acc1;
}

__global__ __launch_bounds__(256) void k_wsum_x(const float* __restrict__ wp,
    float* __restrict__ wgt, u16* __restrict__ x) {
  int i = blockIdx.x * 256 + threadIdx.x;
  const int NN = BB * E2D;
  float s = wp[i] + wp[NN + i] + wp[2 * NN + i] + wp[3 * NN + i];
  wgt[i] = s;
  int b = i >> 10, e = i & 1023;
  x[(size_t)b * 1280 + EMBD + e] = f2bf(s);
}

__global__ __launch_bounds__(256) void k_embx(const int* __restrict__ inp,
    const float* __restrict__ table, u16* __restrict__ x) {
  int b = blockIdx.x, t = threadIdx.x;
  x[(size_t)b * 1280 + t] = f2bf(table[(size_t)inp[b] * EMBD + t]);
}

__global__ __launch_bounds__(256) void k_concat_state_bf(const float* __restrict__ hnew,
    const float* __restrict__ wgt, u16* __restrict__ st) {
  int b = blockIdx.x;
  for (int i = threadIdx.x; i < DECD + E2D; i += 256) {
    float vv = (i < DECD) ? hnew[(size_t)b * DECD + i] : wgt[(size_t)b * E2D + i - DECD];
    st[(size_t)b * (DECD + E2D) + i] = f2bf(vv);
  }
}

__global__ __launch_bounds__(256) void k_gru(const float* __restrict__ gx,
    const float* __restrict__ gh, const float* __restrict__ hidden,
    float* __restrict__ hnew) {
  int b = blockIdx.x, tid = threadIdx.x;
  #pragma unroll
  for (int qq = 0; qq < 2; ++qq) {
    int d = tid + qq * 256;
    size_t o = (size_t)b * 1536;
    float xr = gx[o + d],        hr = gh[o + d];
    float xz = gx[o + 512 + d],  hz = gh[o + 512 + d];
    float xn = gx[o + 1024 + d], hn = gh[o + 1024 + d];
    float r = 1.f / (1.f + expf(-(xr + hr)));
    float z = 1.f / (1.f + expf(-(xz + hz)));
    float n = tanhf(xn + r * hn);
    hnew[(size_t)b * DECD + d] = (1.f - z) * n + z * hidden[(size_t)b * DECD + d];
  }
}

__global__ __launch_bounds__(256) void k_pgen(const float* __restrict__ wgt,
    const int* __restrict__ inp, const float* __restrict__ table,
    const float* __restrict__ gW, const float* __restrict__ gb,
    float* __restrict__ pg) {
  int b = blockIdx.x, tid = threadIdx.x;
  __shared__ float sm[4];
  float s = 0.f;
  for (int k = tid; k < E2D + EMBD; k += 256)
    s += gW[k] * ((k < E2D) ? wgt[(size_t)b * E2D + k]
                            : table[(size_t)inp[b] * EMBD + k - E2D]);
  #pragma unroll
  for (int off = 32; off > 0; off >>= 1) s += __shfl_down(s, off, 64);
  int lane = tid & 63, wid = tid >> 6;
  if (lane == 0) sm[wid] = s;
  __syncthreads();
  if (tid == 0) {
    float t = sm[0] + sm[1] + sm[2] + sm[3] + gb[0];
    pg[b] = 1.f / (1.f + expf(-t));
  }
}

// vocab softmax + p_gen scale + fused copy-scatter (r12/r13-verified)
__global__ __launch_bounds__(256) void k_vocab_sc(float* __restrict__ dist,
    const float* __restrict__ pg, const float* __restrict__ ad,
    const int* __restrict__ src1) {
  int b = blockIdx.x, tid = threadIdx.x;
  float* row = dist + (size_t)b * VV;
  __shared__ float sm[4];
  float m = -INFINITY;
  for (int i = tid; i < VV; i += 256) m = fmaxf(m, row[i]);
  #pragma unroll
  for (int off = 32; off > 0; off >>= 1) m = fmaxf(m, __shfl_down(m, off, 64));
  int lane = tid & 63, wid = tid >> 6;
  if (lane == 0) sm[wid] = m;
  __syncthreads();
  m = fmaxf(fmaxf(sm[0], sm[1]), fmaxf(sm[2], sm[3]));
  __syncthreads();
  float s = 0.f;
  for (int i = tid; i < VV; i += 256) s += expf(row[i] - m);
  #pragma unroll
  for (int off = 32; off > 0; off >>= 1) s += __shfl_down(s, off, 64);
  if (lane == 0) sm[wid] = s;
  __syncthreads();
  s = sm[0] + sm[1] + sm[2] + sm[3];
  float pgb = pg[b];
  float scale = pgb / s;
  for (int i = tid; i < VV; i += 256) row[i] = expf(row[i] - m) * scale;
  __syncthreads();
  if (tid < S1D) {
    float val = (1.f - pgb) * ad[(size_t)b * S1D + tid];
    int tok = src1[(size_t)tid * BB + b];
    atomicAdd(&row[tok], val);
  }
}

extern "C" void kernel_launch(void* const* d_in, const int* in_sizes, int n_in,
                              void* d_out, int out_size, void* d_ws, size_t ws_size,
                              hipStream_t stream) {
  (void)in_sizes; (void)n_in; (void)out_size; (void)ws_size;
  const int*   input  = (const int*)d_in[0];
  const float* hidden = (const float*)d_in[1];
  const int*   src1   = (const int*)d_in[2];
  const float* enc1   = (const float*)d_in[3];
  const int*   mask1  = (const int*)d_in[4];
  const int*   triple = (const int*)d_in[5];
  const float* enc2   = (const float*)d_in[6];
  const int*   mask2  = (const int*)d_in[7];
  const float* embedding = (const float*)d_in[8];
  const float* attn_W = (const float*)d_in[9];
  const float* attn_b = (const float*)d_in[10];
  const float* attn_v = (const float*)d_in[11];
  const float* copy_W = (const float*)d_in[12];
  const float* copy_b = (const float*)d_in[13];
  const float* copy_v = (const float*)d_in[14];
  const float* gru_Wih = (const float*)d_in[15];
  const float* gru_Whh = (const float*)d_in[16];
  const float* gru_bih = (const float*)d_in[17];
  const float* gru_bhh = (const float*)d_in[18];
  const float* fc_W   = (const float*)d_in[19];
  const float* fc_b   = (const float*)d_in[20];
  const float* gate_W = (const float*)d_in[21];
  const float* gate_b = (const float*)d_in[22];

  char* w = (char*)d_ws;
  u16* Wt_a = (u16*)w;                w += (size_t)512 * 1024 * 2;
  u16* Wt_c = (u16*)w;                w += (size_t)512 * 1024 * 2;
  float* partJ = (float*)w;           w += (size_t)2 * 51200 * 4;
  float* preC = (float*)w;            w += (size_t)25600 * 512 * 4;
  float* hWa  = (float*)w;            w += (size_t)BB * DECD * 4;
  float* hWc  = (float*)w;            w += (size_t)BB * DECD * 4;
  float* scJ  = (float*)w;            w += (size_t)BB * SJD * 4;
  float* scC  = (float*)w;            w += (size_t)BB * S1D * 4;
  float* wgt  = (float*)w;            w += (size_t)BB * E2D * 4;
  float* wpart = (float*)w;           w += (size_t)4 * BB * E2D * 4;
  u16*   x_bf = (u16*)w;              w += (size_t)BB * 1280 * 2;
  u16*   hid_bf = (u16*)w;            w += (size_t)BB * DECD * 2;
  float* gx   = (float*)w;            w += (size_t)BB * 1536 * 4;
  float* gh   = (float*)w;            w += (size_t)BB * 1536 * 4;
  u16*   st_bf = (u16*)w;             w += (size_t)BB * 1536 * 2;
  float* pg   = (float*)w;            w += 512;

  float* out  = (float*)d_out;
  float* hnew = out + (size_t)BB * VV;

  // prep
  k_wt<<<dim3(32, 16), 256, 0, stream>>>(attn_W, Wt_a);
  k_wt<<<dim3(32, 16), 256, 0, stream>>>(copy_W, Wt_c);
  k_cvt<<<32, 256, 0, stream>>>(hidden, hid_bf, BB * DECD / 8);
  k_partial<<<dim3(2, BB), 256, 0, stream>>>(hidden, attn_W, attn_b, hWa);
  k_embx<<<BB, 256, 0, stream>>>(input, embedding, x_bf);

  // combined joint-attn + copy-preactivation energy GEMM (co-resident blocks)
  gemm_energy_jc<<<dim3(2, JY + 400), 256, 0, stream>>>(
      enc1, enc2, Wt_a, Wt_c, hWa, attn_v, partJ, preC);
  k_softmax_j<<<BB, 256, 0, stream>>>(partJ, 51200, scJ, mask1, mask2);

  // weighted context (fp32 enc reads)
  k_wpart<<<dim3(BB, 2, 4), 256, 0, stream>>>(enc1, enc2, scJ, wpart);
  k_wsum_x<<<512, 256, 0, stream>>>(wpart, wgt, x_bf);

  // GRU (bf16 MFMA with fused weight conversion)
  gemm_fc2<<<1536 / 128, 512, 0, stream>>>(x_bf, gru_Wih, gru_bih, gx, 1536, 1280);
  gemm_fc2<<<1536 / 128, 512, 0, stream>>>(hid_bf, gru_Whh, gru_bhh, gh, 1536, 512);
  k_gru<<<BB, 256, 0, stream>>>(gx, gh, hidden, hnew);

  // vocab logits
  k_concat_state_bf<<<BB, 256, 0, stream>>>(hnew, wgt, st_bf);
  gemm_fc2<<<(VV + 127) / 128, 512, 0, stream>>>(st_bf, fc_W, fc_b, out, VV, 1536);

  // copy path: epilogue over precomputed enc1@copy_Wt
  k_pgen<<<BB, 256, 0, stream>>>(wgt, input, embedding, gate_W, gate_b, pg);
  k_partial<<<dim3(2, BB), 256, 0, stream>>>(hnew, copy_W, copy_b, hWc);
  k_copy_epi<<<25600 / 4, 256, 0, stream>>>(preC, hWc, copy_v, scC);
  k_softmax_s<<<BB, 256, 0, stream>>>(scC, S1D, mask1, triple);

  // final distribution (softmax + scale + fused scatter)
  k_vocab_sc<<<BB, 256, 0, stream>>>(out, pg, scC, src1);
}

// Round 15
// 598.616 us; speedup vs baseline: 1.3375x; 1.0579x over previous
//
#include <hip/hip_runtime.h>
#include <math.h>

#define BB   128
#define DECD 512
#define E2D  1024
#define EMBD 256
#define S1D  200
#define S2D  200
#define SJD  400
#define VV   50000
#define NEGV (-1e10f)
#define JY   800   // joint tiles (51200 rows / 64); copy tiles follow

typedef unsigned short u16;
typedef __bf16 bf16x8 __attribute__((ext_vector_type(8)));
typedef float f32x4 __attribute__((ext_vector_type(4)));
typedef u16 u16x8 __attribute__((ext_vector_type(8)));

__device__ __forceinline__ u16 f2bf(float x) {
  unsigned u = __float_as_uint(x);
  unsigned r = (u + 0x7fffu + ((u >> 16) & 1u)) >> 16;
  return (u16)r;
}
__device__ __forceinline__ float bf2f(u16 h) {
  return __uint_as_float(((unsigned)h) << 16);
}

typedef const __attribute__((address_space(1))) void* gas_t;
typedef __attribute__((address_space(3))) void* las_t;
__device__ __forceinline__ void async_copy16(const u16* g, u16* l) {
  __builtin_amdgcn_global_load_lds((gas_t)g, (las_t)l, 16, 0, 0);
}

// ---------------- generic fp32 -> bf16 ----------------
__global__ __launch_bounds__(256) void k_cvt(const float* __restrict__ src,
    u16* __restrict__ dst, int n8) {
  int i = blockIdx.x * 256 + threadIdx.x;
  if (i >= n8) return;
  const float4 f0 = *(const float4*)(src + (size_t)i * 8);
  const float4 f1 = *(const float4*)(src + (size_t)i * 8 + 4);
  u16x8 o;
  o[0] = f2bf(f0.x); o[1] = f2bf(f0.y); o[2] = f2bf(f0.z); o[3] = f2bf(f0.w);
  o[4] = f2bf(f1.x); o[5] = f2bf(f1.y); o[6] = f2bf(f1.z); o[7] = f2bf(f1.w);
  *(u16x8*)(dst + (size_t)i * 8) = o;
}

// Wt[n][k] = bf16( W[512+k][n] ); grid.z selects (attn_W->Wt_a) / (copy_W->Wt_c)
__global__ __launch_bounds__(256) void k_wt2(const float* __restrict__ Wa,
    const float* __restrict__ Wc, u16* __restrict__ Wta, u16* __restrict__ Wtc) {
  __shared__ float t[32][33];
  const float* W = blockIdx.z ? Wc : Wa;
  u16* Wt = blockIdx.z ? Wtc : Wta;
  int bk = blockIdx.x, bn = blockIdx.y;
  int tx = threadIdx.x & 31, ty = threadIdx.x >> 5;
  #pragma unroll
  for (int r = 0; r < 4; ++r) {
    int k = bk * 32 + ty + r * 8;
    t[ty + r * 8][tx] = W[(size_t)(512 + k) * 512 + bn * 32 + tx];
  }
  __syncthreads();
  #pragma unroll
  for (int r = 0; r < 4; ++r) {
    int n = bn * 32 + ty + r * 8;
    Wt[(size_t)n * 1024 + bk * 32 + tx] = f2bf(t[tx][ty + r * 8]);
  }
}

// ---------------- combined joint+copy energy GEMM (r14-verified) ----------------
__global__ __launch_bounds__(256) void gemm_energy_jc(
    const float* __restrict__ enc1, const float* __restrict__ enc2,
    const u16* __restrict__ BtA, const u16* __restrict__ BtC,
    const float* __restrict__ hW, const float* __restrict__ v,
    float* __restrict__ partJ, float* __restrict__ preC) {
  __shared__ u16 As[2][64 * 32];   // 2 x 4 KB
  __shared__ u16 Bs[256 * 32];     // 16 KB
  __shared__ float sbuf[64][2];
  int tid = threadIdx.x;
  int wid = tid >> 6, lane = tid & 63;
  int wr = wid >> 1, wc = wid & 1;
  int bn = blockIdx.x;                 // n-half: 0 or 1
  int jy = blockIdx.y;
  int joint = (jy < JY);
  size_t m0 = joint ? (size_t)jy * 64 : (size_t)(jy - JY) * 64;
  int bhalf = (jy & 1) * 64;           // batch-row offset (joint only)
  int n0 = bn * 256;

  int rA = tid >> 2, cslot = tid & 3;
  int lAoff = rA * 32 + ((cslot ^ ((rA >> 1) & 3)) * 8);
  const float* base;
  if (joint)
    base = (m0 < (size_t)S1D * BB) ? (enc1 + m0 * E2D)
                                   : (enc2 + (m0 - (size_t)S1D * BB) * E2D);
  else
    base = enc1 + m0 * E2D;
  const float* gA_f = base + (size_t)rA * E2D + cslot * 8;

  const u16* Bt = joint ? BtA : BtC;
  const u16* gB[4];
  #pragma unroll
  for (int i = 0; i < 4; ++i) {
    int rn = i * 64 + wid * 16 + (lane >> 2);
    int c = (lane & 3) ^ ((rn >> 1) & 3);
    gB[i] = Bt + (size_t)(n0 + rn) * E2D + c * 8;
  }

  int q = lane >> 4, cl = lane & 15;
  int aoff[2], boff[8];
  #pragma unroll
  for (int mi = 0; mi < 2; ++mi) {
    int row = wr * 32 + mi * 16 + cl;
    aoff[mi] = row * 64 + ((q ^ ((row >> 1) & 3)) * 16);
  }
  #pragma unroll
  for (int nj = 0; nj < 8; ++nj) {
    int rn = wc * 128 + nj * 16 + cl;
    boff[nj] = rn * 64 + ((q ^ ((rn >> 1) & 3)) * 16);
  }

  f32x4 acc[2][8];
  #pragma unroll
  for (int mi = 0; mi < 2; ++mi)
    #pragma unroll
    for (int nj = 0; nj < 8; ++nj) {
      f32x4 z = {0.f, 0.f, 0.f, 0.f};
      acc[mi][nj] = z;
    }

  float4 a0 = *(const float4*)(gA_f);
  float4 a1 = *(const float4*)(gA_f + 4);
  {
    u16x8 ob;
    ob[0] = f2bf(a0.x); ob[1] = f2bf(a0.y); ob[2] = f2bf(a0.z); ob[3] = f2bf(a0.w);
    ob[4] = f2bf(a1.x); ob[5] = f2bf(a1.y); ob[6] = f2bf(a1.z); ob[7] = f2bf(a1.w);
    *(u16x8*)(&As[0][lAoff]) = ob;
  }
  a0 = *(const float4*)(gA_f + 32);
  a1 = *(const float4*)(gA_f + 36);

  for (int t = 0; t < 32; ++t) {
    int cur = t & 1, nxt = cur ^ 1;
    int k0 = t * 32, k1 = k0 + 32;
    #pragma unroll
    for (int i = 0; i < 4; ++i) async_copy16(gB[i] + k0, &Bs[2048 * i + wid * 512]);
    if (t < 31) {
      u16x8 ob;
      ob[0] = f2bf(a0.x); ob[1] = f2bf(a0.y); ob[2] = f2bf(a0.z); ob[3] = f2bf(a0.w);
      ob[4] = f2bf(a1.x); ob[5] = f2bf(a1.y); ob[6] = f2bf(a1.z); ob[7] = f2bf(a1.w);
      *(u16x8*)(&As[nxt][lAoff]) = ob;
      if (t < 30) {
        a0 = *(const float4*)(gA_f + k1 + 32);
        a1 = *(const float4*)(gA_f + k1 + 36);
      }
    }
    __syncthreads();
    bf16x8 af[2];
    #pragma unroll
    for (int mi = 0; mi < 2; ++mi)
      af[mi] = *(const bf16x8*)((const char*)As[cur] + aoff[mi]);
    #pragma unroll
    for (int nj = 0; nj < 8; ++nj) {
      bf16x8 bg = *(const bf16x8*)((const char*)Bs + boff[nj]);
      acc[0][nj] = __builtin_amdgcn_mfma_f32_16x16x32_bf16(af[0], bg, acc[0][nj], 0, 0, 0);
      acc[1][nj] = __builtin_amdgcn_mfma_f32_16x16x32_bf16(af[1], bg, acc[1][nj], 0, 0, 0);
    }
    __syncthreads();
  }

  if (joint) {
    #pragma unroll
    for (int mi = 0; mi < 2; ++mi) {
      #pragma unroll
      for (int j = 0; j < 4; ++j) {
        int m = wr * 32 + mi * 16 + q * 4 + j;
        float s = 0.f;
        #pragma unroll
        for (int nj = 0; nj < 8; ++nj) {
          int d = n0 + wc * 128 + nj * 16 + cl;
          s += tanhf(acc[mi][nj][j] + hW[(size_t)(bhalf + m) * DECD + d]) * v[d];
        }
        s += __shfl_xor(s, 1, 64);
        s += __shfl_xor(s, 2, 64);
        s += __shfl_xor(s, 4, 64);
        s += __shfl_xor(s, 8, 64);
        if (cl == 0) sbuf[m][wc] = s;
      }
    }
    __syncthreads();
    if (tid < 64)
      partJ[(size_t)bn * 51200 + m0 + tid] = sbuf[tid][0] + sbuf[tid][1];
  } else {
    #pragma unroll
    for (int mi = 0; mi < 2; ++mi) {
      #pragma unroll
      for (int nj = 0; nj < 8; ++nj) {
        int d = n0 + wc * 128 + nj * 16 + cl;
        #pragma unroll
        for (int j = 0; j < 4; ++j) {
          int m = wr * 32 + mi * 16 + q * 4 + j;
          preC[(m0 + m) * (size_t)DECD + d] = acc[mi][nj][j];
        }
      }
    }
  }
}

// copy epilogue (r10/r14-verified)
__global__ __launch_bounds__(256) void k_copy_epi(const float* __restrict__ preC,
    const float* __restrict__ hWc, const float* __restrict__ v,
    float* __restrict__ scC) {
  int r = blockIdx.x * 4 + (threadIdx.x >> 6);
  int lane = threadIdx.x & 63;
  int b = r & 127, s = r >> 7;
  const float* pr = preC + (size_t)r * DECD + lane * 8;
  const float* hr = hWc + (size_t)b * DECD + lane * 8;
  const float* vr = v + lane * 8;
  float4 p0 = *(const float4*)(pr),     p1 = *(const float4*)(pr + 4);
  float4 h0 = *(const float4*)(hr),     h1 = *(const float4*)(hr + 4);
  float4 v0 = *(const float4*)(vr),     v1 = *(const float4*)(vr + 4);
  float acc = tanhf(p0.x + h0.x) * v0.x + tanhf(p0.y + h0.y) * v0.y
            + tanhf(p0.z + h0.z) * v0.z + tanhf(p0.w + h0.w) * v0.w
            + tanhf(p1.x + h1.x) * v1.x + tanhf(p1.y + h1.y) * v1.y
            + tanhf(p1.z + h1.z) * v1.z + tanhf(p1.w + h1.w) * v1.w;
  #pragma unroll
  for (int off = 32; off > 0; off >>= 1) acc += __shfl_xor(acc, off, 64);
  if (lane == 0) scC[(size_t)b * S1D + s] = acc;
}

// joint softmax fused with partial-sum (r10-r14-verified)
__global__ __launch_bounds__(256) void k_softmax_j(const float* __restrict__ part,
    int M, float* __restrict__ sc,
    const int* __restrict__ m1, const int* __restrict__ m2) {
  int b = blockIdx.x, tid = threadIdx.x;
  __shared__ float sm[4];
  int s0 = tid, s2 = tid + 256;
  float a0 = -INFINITY, a1 = -INFINITY;
  {
    int msk = (s0 < S1D) ? m1[b * S1D + s0] : m2[b * S2D + (s0 - S1D)];
    int m = s0 * 128 + b;
    a0 = msk ? (part[m] + part[M + m]) : NEGV;
  }
  if (s2 < SJD) {
    int msk = (s2 < S1D) ? m1[b * S1D + s2] : m2[b * S2D + (s2 - S1D)];
    int m = s2 * 128 + b;
    a1 = msk ? (part[m] + part[M + m]) : NEGV;
  }
  float vmax = fmaxf(a0, a1);
  #pragma unroll
  for (int off = 32; off > 0; off >>= 1) vmax = fmaxf(vmax, __shfl_down(vmax, off, 64));
  int lane = tid & 63, wid = tid >> 6;
  if (lane == 0) sm[wid] = vmax;
  __syncthreads();
  vmax = fmaxf(fmaxf(sm[0], sm[1]), fmaxf(sm[2], sm[3]));
  __syncthreads();
  float lsum = expf(a0 - vmax);
  if (s2 < SJD) lsum += expf(a1 - vmax);
  #pragma unroll
  for (int off = 32; off > 0; off >>= 1) lsum += __shfl_down(lsum, off, 64);
  if (lane == 0) sm[wid] = lsum;
  __syncthreads();
  float inv = 1.0f / (sm[0] + sm[1] + sm[2] + sm[3]);
  sc[(size_t)b * SJD + s0] = expf(a0 - vmax) * inv;
  if (s2 < SJD) sc[(size_t)b * SJD + s2] = expf(a1 - vmax) * inv;
}

// copy-path masked softmax, in place (r10/r14-verified)
__global__ __launch_bounds__(256) void k_softmax_s(float* __restrict__ sc, int S,
    const int* __restrict__ m1, const int* __restrict__ m2) {
  int b = blockIdx.x, tid = threadIdx.x;
  __shared__ float sm[4];
  int s0 = tid;
  float a0 = -INFINITY;
  if (s0 < S) {
    int msk = m1[b * S + s0] * m2[b * S + s0];
    a0 = msk ? sc[(size_t)b * S + s0] : NEGV;
  }
  float vmax = a0;
  #pragma unroll
  for (int off = 32; off > 0; off >>= 1) vmax = fmaxf(vmax, __shfl_down(vmax, off, 64));
  int lane = tid & 63, wid = tid >> 6;
  if (lane == 0) sm[wid] = vmax;
  __syncthreads();
  vmax = fmaxf(fmaxf(sm[0], sm[1]), fmaxf(sm[2], sm[3]));
  __syncthreads();
  float lsum = (s0 < S) ? expf(a0 - vmax) : 0.f;
  #pragma unroll
  for (int off = 32; off > 0; off >>= 1) lsum += __shfl_down(lsum, off, 64);
  if (lane == 0) sm[wid] = lsum;
  __syncthreads();
  float inv = 1.0f / (sm[0] + sm[1] + sm[2] + sm[3]);
  if (s0 < S) sc[(size_t)b * S + s0] = expf(a0 - vmax) * inv;
}

// ---------------- fc2 body as device function (r8-verified structure) ----------------
__device__ __forceinline__ void fc2_body(
    const u16* __restrict__ A, const float* __restrict__ Bf,
    const float* __restrict__ bias, float* __restrict__ C,
    int N, int K, int n0) {
  __shared__ u16 As[2][128 * 32];
  __shared__ u16 Bs[2][128 * 32];
  int tid = threadIdx.x;
  int wid = tid >> 6, lane = tid & 63;
  int wr = wid >> 2, wc = wid & 3;

  int rowa = wid * 16 + (lane >> 2);
  int ca = (lane & 3) ^ ((rowa >> 1) & 3);
  const u16* gA = A + (size_t)rowa * K + ca * 8;

  int rB = tid >> 2, cB = tid & 3;
  int gnB = n0 + rB; if (gnB >= N) gnB = N - 1;
  const float* gB = Bf + (size_t)gnB * K + cB * 8;
  int lBoff = rB * 32 + ((cB ^ ((rB >> 1) & 3)) * 8);

  int q = lane >> 4, cl = lane & 15;
  int aoff[4], boff[2];
  #pragma unroll
  for (int mi = 0; mi < 4; ++mi) {
    int row = wr * 64 + mi * 16 + cl;
    aoff[mi] = row * 64 + ((q ^ ((row >> 1) & 3)) * 16);
  }
  #pragma unroll
  for (int nj = 0; nj < 2; ++nj) {
    int rn = wc * 32 + nj * 16 + cl;
    boff[nj] = rn * 64 + ((q ^ ((rn >> 1) & 3)) * 16);
  }

  f32x4 acc[4][2];
  #pragma unroll
  for (int mi = 0; mi < 4; ++mi)
    #pragma unroll
    for (int nj = 0; nj < 2; ++nj) {
      f32x4 z = {0.f, 0.f, 0.f, 0.f};
      acc[mi][nj] = z;
    }

  for (int k0 = 0; k0 < K; k0 += 64) {
    float4 b00 = *(const float4*)(gB + k0);
    float4 b01 = *(const float4*)(gB + k0 + 4);
    float4 b10 = *(const float4*)(gB + k0 + 32);
    float4 b11 = *(const float4*)(gB + k0 + 36);
    u16x8 o0, o1;
    o0[0] = f2bf(b00.x); o0[1] = f2bf(b00.y); o0[2] = f2bf(b00.z); o0[3] = f2bf(b00.w);
    o0[4] = f2bf(b01.x); o0[5] = f2bf(b01.y); o0[6] = f2bf(b01.z); o0[7] = f2bf(b01.w);
    o1[0] = f2bf(b10.x); o1[1] = f2bf(b10.y); o1[2] = f2bf(b10.z); o1[3] = f2bf(b10.w);
    o1[4] = f2bf(b11.x); o1[5] = f2bf(b11.y); o1[6] = f2bf(b11.z); o1[7] = f2bf(b11.w);
    *(u16x8*)(&Bs[0][lBoff]) = o0;
    *(u16x8*)(&Bs[1][lBoff]) = o1;
    async_copy16(gA + k0,      &As[0][wid * 512]);
    async_copy16(gA + k0 + 32, &As[1][wid * 512]);
    __syncthreads();
    #pragma unroll
    for (int h = 0; h < 2; ++h) {
      bf16x8 af[4], bg[2];
      #pragma unroll
      for (int mi = 0; mi < 4; ++mi) af[mi] = *(const bf16x8*)((const char*)As[h] + aoff[mi]);
      #pragma unroll
      for (int nj = 0; nj < 2; ++nj) bg[nj] = *(const bf16x8*)((const char*)Bs[h] + boff[nj]);
      #pragma unroll
      for (int mi = 0; mi < 4; ++mi)
        #pragma unroll
        for (int nj = 0; nj < 2; ++nj)
          acc[mi][nj] = __builtin_amdgcn_mfma_f32_16x16x32_bf16(af[mi], bg[nj], acc[mi][nj], 0, 0, 0);
    }
    __syncthreads();
  }

  #pragma unroll
  for (int mi = 0; mi < 4; ++mi) {
    #pragma unroll
    for (int nj = 0; nj < 2; ++nj) {
      int n = n0 + wc * 32 + nj * 16 + cl;
      if (n < N) {
        float bv = bias[n];
        #pragma unroll
        for (int j = 0; j < 4; ++j) {
          int m = wr * 64 + mi * 16 + q * 4 + j;
          C[(size_t)m * N + n] = acc[mi][nj][j] + bv;
        }
      }
    }
  }
}

// merged GRU GEMMs: blocks 0..11 -> gx (K=1280), 12..23 -> gh (K=512)
__global__ __launch_bounds__(512) void gemm_gru(
    const u16* __restrict__ x_bf, const float* __restrict__ Wih,
    const float* __restrict__ bih, float* __restrict__ gx,
    const u16* __restrict__ h_bf, const float* __restrict__ Whh,
    const float* __restrict__ bhh, float* __restrict__ gh) {
  if (blockIdx.x < 12)
    fc2_body(x_bf, Wih, bih, gx, 1536, 1280, blockIdx.x * 128);
  else
    fc2_body(h_bf, Whh, bhh, gh, 1536, 512, (blockIdx.x - 12) * 128);
}

// ---------------- fc GEMM v3: BM=128, BN=64, BK=64, 512 thr (8 waves 2Mx4N) ----------------
__global__ __launch_bounds__(512) void gemm_fc3(
    const u16* __restrict__ A, const float* __restrict__ Bf,
    const float* __restrict__ bias, float* __restrict__ C,
    int N, int K) {
  __shared__ u16 As[2][128 * 32];   // 2 x 8 KB
  __shared__ u16 Bs[2][64 * 32];    // 2 x 4 KB
  int tid = threadIdx.x;
  int wid = tid >> 6, lane = tid & 63;
  int wr = wid >> 2, wc = wid & 3;   // 2M x 4N (N=64, 16 each)
  int n0 = blockIdx.x * 64;

  // A staging (identical to fc2)
  int rowa = wid * 16 + (lane >> 2);
  int ca = (lane & 3) ^ ((rowa >> 1) & 3);
  const u16* gA = A + (size_t)rowa * K + ca * 8;

  // B reg staging: rB = tid>>3 (64 rows), cB = tid&7 (8-float chunk); half = cB>>2
  int rB = tid >> 3, cB = tid & 7;
  int gnB = n0 + rB; if (gnB >= N) gnB = N - 1;
  const float* gB = Bf + (size_t)gnB * K + cB * 8;
  int hB = cB >> 2, s4 = cB & 3;
  int lBoff = rB * 32 + ((s4 ^ ((rB >> 1) & 3)) * 8);  // u16 offset within half hB

  int q = lane >> 4, cl = lane & 15;
  int aoff[4], boff;
  #pragma unroll
  for (int mi = 0; mi < 4; ++mi) {
    int row = wr * 64 + mi * 16 + cl;
    aoff[mi] = row * 64 + ((q ^ ((row >> 1) & 3)) * 16);
  }
  {
    int rn = wc * 16 + cl;
    boff = rn * 64 + ((q ^ ((rn >> 1) & 3)) * 16);
  }

  f32x4 acc[4];
  #pragma unroll
  for (int mi = 0; mi < 4; ++mi) {
    f32x4 z = {0.f, 0.f, 0.f, 0.f};
    acc[mi] = z;
  }

  for (int k0 = 0; k0 < K; k0 += 64) {
    float4 b0 = *(const float4*)(gB + k0);
    float4 b1 = *(const float4*)(gB + k0 + 4);
    u16x8 ob;
    ob[0] = f2bf(b0.x); ob[1] = f2bf(b0.y); ob[2] = f2bf(b0.z); ob[3] = f2bf(b0.w);
    ob[4] = f2bf(b1.x); ob[5] = f2bf(b1.y); ob[6] = f2bf(b1.z); ob[7] = f2bf(b1.w);
    *(u16x8*)(&Bs[hB][lBoff]) = ob;
    async_copy16(gA + k0,      &As[0][wid * 512]);
    async_copy16(gA + k0 + 32, &As[1][wid * 512]);
    __syncthreads();
    #pragma unroll
    for (int h = 0; h < 2; ++h) {
      bf16x8 af[4];
      #pragma unroll
      for (int mi = 0; mi < 4; ++mi) af[mi] = *(const bf16x8*)((const char*)As[h] + aoff[mi]);
      bf16x8 bg = *(const bf16x8*)((const char*)Bs[h] + boff);
      #pragma unroll
      for (int mi = 0; mi < 4; ++mi)
        acc[mi] = __builtin_amdgcn_mfma_f32_16x16x32_bf16(af[mi], bg, acc[mi], 0, 0, 0);
    }
    __syncthreads();
  }

  int n = n0 + wc * 16 + cl;
  if (n < N) {
    float bv = bias[n];
    #pragma unroll
    for (int mi = 0; mi < 4; ++mi)
      #pragma unroll
      for (int j = 0; j < 4; ++j) {
        int m = wr * 64 + mi * 16 + q * 4 + j;
        C[(size_t)m * N + n] = acc[mi][j] + bv;
      }
  }
}

// ---------------- small kernels (verified) ----------------
__global__ __launch_bounds__(256) void k_partial(const float* __restrict__ h,
    const float* __restrict__ W, const float* __restrict__ bias,
    float* __restrict__ out) {
  int b = blockIdx.y;
  int d = blockIdx.x * 256 + threadIdx.x;
  const float* hr = h + (size_t)b * DECD;
  float acc = bias[d];
  #pragma unroll 8
  for (int k = 0; k < DECD; ++k) acc += hr[k] * W[(size_t)k * DECD + d];
  out[(size_t)b * DECD + d] = acc;
}

// weighted partials over s-chunks of 100, fp32 enc reads (r9/r14-verified)
__global__ __launch_bounds__(256) void k_wpart(const float* __restrict__ enc1,
    const float* __restrict__ enc2, const float* __restrict__ a,
    float* __restrict__ wp) {
  int b = blockIdx.x;
  int e2 = blockIdx.y * 256 + threadIdx.x;
  int scn = blockIdx.z;
  const float* arow = a + (size_t)b * SJD;
  float acc0 = 0.f, acc1 = 0.f;
  #pragma unroll 4
  for (int s = scn * 100; s < scn * 100 + 100; ++s) {
    const float* ep = (s < S1D) ? (enc1 + ((size_t)s * BB + b) * E2D)
                                : (enc2 + ((size_t)(s - S1D) * BB + b) * E2D);
    float2 u = *(const float2*)(ep + e2 * 2);
    float w = arow[s];
    acc0 += w * u.x;
    acc1 += w * u.y;
  }
  float* dst = wp + ((size_t)scn * BB + b) * E2D + e2 * 2;
  dst[0] = acc0;
  dst[1] = acc1;
}

__global__ __launch_bounds__(256) void k_wsum_x(const float* __restrict__ wp,
    float* __restrict__ wgt, u16* __restrict__ x) {
  int i = blockIdx.x * 256 + threadIdx.x;
  const int NN = BB * E2D;
  float s = wp[i] + wp[NN + i] + wp[2 * NN + i] + wp[3 * NN + i];
  wgt[i] = s;
  int b = i >> 10, e = i & 1023;
  x[(size_t)b * 1280 + EMBD + e] = f2bf(s);
}

__global__ __launch_bounds__(256) void k_embx(const int* __restrict__ inp,
    const float* __restrict__ table, u16* __restrict__ x) {
  int b = blockIdx.x, t = threadIdx.x;
  x[(size_t)b * 1280 + t] = f2bf(table[(size_t)inp[b] * EMBD + t]);
}

// GRU pointwise + fused concat(h_new, wgt) -> st_bf
__global__ __launch_bounds__(256) void k_gru_concat(const float* __restrict__ gx,
    const float* __restrict__ gh, const float* __restrict__ hidden,
    const float* __restrict__ wgt, float* __restrict__ hnew,
    u16* __restrict__ st) {
  int b = blockIdx.x, tid = threadIdx.x;
  #pragma unroll
  for (int qq = 0; qq < 2; ++qq) {
    int d = tid + qq * 256;
    size_t o = (size_t)b * 1536;
    float xr = gx[o + d],        hr = gh[o + d];
    float xz = gx[o + 512 + d],  hz = gh[o + 512 + d];
    float xn = gx[o + 1024 + d], hn = gh[o + 1024 + d];
    float r = 1.f / (1.f + expf(-(xr + hr)));
    float z = 1.f / (1.f + expf(-(xz + hz)));
    float n = tanhf(xn + r * hn);
    float hv = (1.f - z) * n + z * hidden[(size_t)b * DECD + d];
    hnew[(size_t)b * DECD + d] = hv;
    st[(size_t)b * 1536 + d] = f2bf(hv);
  }
  #pragma unroll
  for (int qq = 0; qq < 4; ++qq) {
    int e = tid + qq * 256;
    st[(size_t)b * 1536 + DECD + e] = f2bf(wgt[(size_t)b * E2D + e]);
  }
}

__global__ __launch_bounds__(256) void k_pgen(const float* __restrict__ wgt,
    const int* __restrict__ inp, const float* __restrict__ table,
    const float* __restrict__ gW, const float* __restrict__ gb,
    float* __restrict__ pg) {
  int b = blockIdx.x, tid = threadIdx.x;
  __shared__ float sm[4];
  float s = 0.f;
  for (int k = tid; k < E2D + EMBD; k += 256)
    s += gW[k] * ((k < E2D) ? wgt[(size_t)b * E2D + k]
                            : table[(size_t)inp[b] * EMBD + k - E2D]);
  #pragma unroll
  for (int off = 32; off > 0; off >>= 1) s += __shfl_down(s, off, 64);
  int lane = tid & 63, wid = tid >> 6;
  if (lane == 0) sm[wid] = s;
  __syncthreads();
  if (tid == 0) {
    float t = sm[0] + sm[1] + sm[2] + sm[3] + gb[0];
    pg[b] = 1.f / (1.f + expf(-t));
  }
}

// vocab softmax + p_gen scale + fused copy-scatter (r12-r14-verified)
__global__ __launch_bounds__(256) void k_vocab_sc(float* __restrict__ dist,
    const float* __restrict__ pg, const float* __restrict__ ad,
    const int* __restrict__ src1) {
  int b = blockIdx.x, tid = threadIdx.x;
  float* row = dist + (size_t)b * VV;
  __shared__ float sm[4];
  float m = -INFINITY;
  for (int i = tid; i < VV; i += 256) m = fmaxf(m, row[i]);
  #pragma unroll
  for (int off = 32; off > 0; off >>= 1) m = fmaxf(m, __shfl_down(m, off, 64));
  int lane = tid & 63, wid = tid >> 6;
  if (lane == 0) sm[wid] = m;
  __syncthreads();
  m = fmaxf(fmaxf(sm[0], sm[1]), fmaxf(sm[2], sm[3]));
  __syncthreads();
  float s = 0.f;
  for (int i = tid; i < VV; i += 256) s += expf(row[i] - m);
  #pragma unroll
  for (int off = 32; off > 0; off >>= 1) s += __shfl_down(s, off, 64);
  if (lane == 0) sm[wid] = s;
  __syncthreads();
  s = sm[0] + sm[1] + sm[2] + sm[3];
  float pgb = pg[b];
  float scale = pgb / s;
  for (int i = tid; i < VV; i += 256) row[i] = expf(row[i] - m) * scale;
  __syncthreads();
  if (tid < S1D) {
    float val = (1.f - pgb) * ad[(size_t)b * S1D + tid];
    int tok = src1[(size_t)tid * BB + b];
    atomicAdd(&row[tok], val);
  }
}

extern "C" void kernel_launch(void* const* d_in, const int* in_sizes, int n_in,
                              void* d_out, int out_size, void* d_ws, size_t ws_size,
                              hipStream_t stream) {
  (void)in_sizes; (void)n_in; (void)out_size; (void)ws_size;
  const int*   input  = (const int*)d_in[0];
  const float* hidden = (const float*)d_in[1];
  const int*   src1   = (const int*)d_in[2];
  const float* enc1   = (const float*)d_in[3];
  const int*   mask1  = (const int*)d_in[4];
  const int*   triple = (const int*)d_in[5];
  const float* enc2   = (const float*)d_in[6];
  const int*   mask2  = (const int*)d_in[7];
  const float* embedding = (const float*)d_in[8];
  const float* attn_W = (const float*)d_in[9];
  const float* attn_b = (const float*)d_in[10];
  const float* attn_v = (const float*)d_in[11];
  const float* copy_W = (const float*)d_in[12];
  const float* copy_b = (const float*)d_in[13];
  const float* copy_v = (const float*)d_in[14];
  const float* gru_Wih = (const float*)d_in[15];
  const float* gru_Whh = (const float*)d_in[16];
  const float* gru_bih = (const float*)d_in[17];
  const float* gru_bhh = (const float*)d_in[18];
  const float* fc_W   = (const float*)d_in[19];
  const float* fc_b   = (const float*)d_in[20];
  const float* gate_W = (const float*)d_in[21];
  const float* gate_b = (const float*)d_in[22];

  char* w = (char*)d_ws;
  u16* Wt_a = (u16*)w;                w += (size_t)512 * 1024 * 2;
  u16* Wt_c = (u16*)w;                w += (size_t)512 * 1024 * 2;
  float* partJ = (float*)w;           w += (size_t)2 * 51200 * 4;
  float* preC = (float*)w;            w += (size_t)25600 * 512 * 4;
  float* hWa  = (float*)w;            w += (size_t)BB * DECD * 4;
  float* hWc  = (float*)w;            w += (size_t)BB * DECD * 4;
  float* scJ  = (float*)w;            w += (size_t)BB * SJD * 4;
  float* scC  = (float*)w;            w += (size_t)BB * S1D * 4;
  float* wgt  = (float*)w;            w += (size_t)BB * E2D * 4;
  float* wpart = (float*)w;           w += (size_t)4 * BB * E2D * 4;
  u16*   x_bf = (u16*)w;              w += (size_t)BB * 1280 * 2;
  u16*   hid_bf = (u16*)w;            w += (size_t)BB * DECD * 2;
  float* gx   = (float*)w;            w += (size_t)BB * 1536 * 4;
  float* gh   = (float*)w;            w += (size_t)BB * 1536 * 4;
  u16*   st_bf = (u16*)w;             w += (size_t)BB * 1536 * 2;
  float* pg   = (float*)w;            w += 512;

  float* out  = (float*)d_out;
  float* hnew = out + (size_t)BB * VV;

  // prep
  k_wt2<<<dim3(32, 16, 2), 256, 0, stream>>>(attn_W, copy_W, Wt_a, Wt_c);
  k_cvt<<<32, 256, 0, stream>>>(hidden, hid_bf, BB * DECD / 8);
  k_partial<<<dim3(2, BB), 256, 0, stream>>>(hidden, attn_W, attn_b, hWa);
  k_embx<<<BB, 256, 0, stream>>>(input, embedding, x_bf);

  // combined joint-attn + copy-preactivation energy GEMM (co-resident blocks)
  gemm_energy_jc<<<dim3(2, JY + 400), 256, 0, stream>>>(
      enc1, enc2, Wt_a, Wt_c, hWa, attn_v, partJ, preC);
  k_softmax_j<<<BB, 256, 0, stream>>>(partJ, 51200, scJ, mask1, mask2);

  // weighted context (fp32 enc reads)
  k_wpart<<<dim3(BB, 2, 4), 256, 0, stream>>>(enc1, enc2, scJ, wpart);
  k_wsum_x<<<512, 256, 0, stream>>>(wpart, wgt, x_bf);

  // GRU (merged bf16 MFMA GEMMs + pointwise with fused concat)
  gemm_gru<<<24, 512, 0, stream>>>(x_bf, gru_Wih, gru_bih, gx,
                                   hid_bf, gru_Whh, gru_bhh, gh);
  k_gru_concat<<<BB, 256, 0, stream>>>(gx, gh, hidden, wgt, hnew, st_bf);

  // vocab logits (BN=64 for 782-block latency hiding)
  gemm_fc3<<<(VV + 63) / 64, 512, 0, stream>>>(st_bf, fc_W, fc_b, out, VV, 1536);

  // copy path: epilogue over precomputed enc1@copy_Wt
  k_pgen<<<BB, 256, 0, stream>>>(wgt, input, embedding, gate_W, gate_b, pg);
  k_partial<<<dim3(2, BB), 256, 0, stream>>>(hnew, copy_W, copy_b, hWc);
  k_copy_epi<<<25600 / 4, 256, 0, stream>>>(preC, hWc, copy_v, scC);
  k_softmax_s<<<BB, 256, 0, stream>>>(scC, S1D, mask1, triple);

  // final distribution (softmax + scale + fused scatter)
  k_vocab_sc<<<BB, 256, 0, stream>>>(out, pg, scC, src1);
}

// Round 16
// 576.612 us; speedup vs baseline: 1.3886x; 1.0382x over previous
//
#include <hip/hip_runtime.h>
#include <math.h>

#define BB   128
#define DECD 512
#define E2D  1024
#define EMBD 256
#define S1D  200
#define S2D  200
#define SJD  400
#define VV   50000
#define NEGV (-1e10f)
#define JY   800   // joint tiles (51200 rows / 64); copy tiles follow

typedef unsigned short u16;
typedef __bf16 bf16x8 __attribute__((ext_vector_type(8)));
typedef float f32x4 __attribute__((ext_vector_type(4)));
typedef u16 u16x8 __attribute__((ext_vector_type(8)));

__device__ __forceinline__ u16 f2bf(float x) {
  unsigned u = __float_as_uint(x);
  unsigned r = (u + 0x7fffu + ((u >> 16) & 1u)) >> 16;
  return (u16)r;
}
__device__ __forceinline__ float bf2f(u16 h) {
  return __uint_as_float(((unsigned)h) << 16);
}
// hardware RTNE pack (r7-verified: identical absmax to manual f2bf)
__device__ __forceinline__ u16x8 cvt8h(float4 a, float4 b) {
  bf16x8 r;
  r[0] = (__bf16)a.x; r[1] = (__bf16)a.y; r[2] = (__bf16)a.z; r[3] = (__bf16)a.w;
  r[4] = (__bf16)b.x; r[5] = (__bf16)b.y; r[6] = (__bf16)b.z; r[7] = (__bf16)b.w;
  return *reinterpret_cast<u16x8*>(&r);
}

typedef const __attribute__((address_space(1))) void* gas_t;
typedef __attribute__((address_space(3))) void* las_t;
__device__ __forceinline__ void async_copy16(const u16* g, u16* l) {
  __builtin_amdgcn_global_load_lds((gas_t)g, (las_t)l, 16, 0, 0);
}

// ---------------- fused prep: wt2 (0..1023) | cvt hid (1024..1055) | hWa (1056..1311) | embx (1312..1439)
__global__ __launch_bounds__(256) void k_prep(
    const float* __restrict__ Wa, const float* __restrict__ Wc,
    u16* __restrict__ Wta, u16* __restrict__ Wtc,
    const float* __restrict__ hidden, u16* __restrict__ hid_bf,
    const float* __restrict__ attn_b, float* __restrict__ hWa,
    const int* __restrict__ inp, const float* __restrict__ table,
    u16* __restrict__ x_bf) {
  int blk = blockIdx.x, tid = threadIdx.x;
  if (blk < 1024) {
    __shared__ float t[32][33];
    int z = blk >> 9, rem = blk & 511;
    int bk = rem & 31, bn = rem >> 5;
    const float* W = z ? Wc : Wa;
    u16* Wt = z ? Wtc : Wta;
    int tx = tid & 31, ty = tid >> 5;
    #pragma unroll
    for (int r = 0; r < 4; ++r) {
      int k = bk * 32 + ty + r * 8;
      t[ty + r * 8][tx] = W[(size_t)(512 + k) * 512 + bn * 32 + tx];
    }
    __syncthreads();
    #pragma unroll
    for (int r = 0; r < 4; ++r) {
      int n = bn * 32 + ty + r * 8;
      Wt[(size_t)n * 1024 + bk * 32 + tx] = f2bf(t[tx][ty + r * 8]);
    }
  } else if (blk < 1056) {
    int i = (blk - 1024) * 256 + tid;    // 8192 groups of 8
    const float4 f0 = *(const float4*)(hidden + (size_t)i * 8);
    const float4 f1 = *(const float4*)(hidden + (size_t)i * 8 + 4);
    *(u16x8*)(hid_bf + (size_t)i * 8) = cvt8h(f0, f1);
  } else if (blk < 1312) {
    int idx = blk - 1056;
    int b = idx >> 1;
    int d = (idx & 1) * 256 + tid;
    const float* hr = hidden + (size_t)b * DECD;
    float acc = attn_b[d];
    #pragma unroll 8
    for (int k = 0; k < DECD; ++k) acc += hr[k] * Wa[(size_t)k * DECD + d];
    hWa[(size_t)b * DECD + d] = acc;
  } else {
    int b = blk - 1312;
    x_bf[(size_t)b * 1280 + tid] = f2bf(table[(size_t)inp[b] * EMBD + tid]);
  }
}

// ---------------- combined joint+copy energy GEMM (r14/r15-verified; hw-cast staging) ----------------
__global__ __launch_bounds__(256) void gemm_energy_jc(
    const float* __restrict__ enc1, const float* __restrict__ enc2,
    const u16* __restrict__ BtA, const u16* __restrict__ BtC,
    const float* __restrict__ hW, const float* __restrict__ v,
    float* __restrict__ partJ, float* __restrict__ preC) {
  __shared__ u16 As[2][64 * 32];   // 2 x 4 KB
  __shared__ u16 Bs[256 * 32];     // 16 KB
  __shared__ float sbuf[64][2];
  int tid = threadIdx.x;
  int wid = tid >> 6, lane = tid & 63;
  int wr = wid >> 1, wc = wid & 1;
  int bn = blockIdx.x;
  int jy = blockIdx.y;
  int joint = (jy < JY);
  size_t m0 = joint ? (size_t)jy * 64 : (size_t)(jy - JY) * 64;
  int bhalf = (jy & 1) * 64;
  int n0 = bn * 256;

  int rA = tid >> 2, cslot = tid & 3;
  int lAoff = rA * 32 + ((cslot ^ ((rA >> 1) & 3)) * 8);
  const float* base;
  if (joint)
    base = (m0 < (size_t)S1D * BB) ? (enc1 + m0 * E2D)
                                   : (enc2 + (m0 - (size_t)S1D * BB) * E2D);
  else
    base = enc1 + m0 * E2D;
  const float* gA_f = base + (size_t)rA * E2D + cslot * 8;

  const u16* Bt = joint ? BtA : BtC;
  const u16* gB[4];
  #pragma unroll
  for (int i = 0; i < 4; ++i) {
    int rn = i * 64 + wid * 16 + (lane >> 2);
    int c = (lane & 3) ^ ((rn >> 1) & 3);
    gB[i] = Bt + (size_t)(n0 + rn) * E2D + c * 8;
  }

  int q = lane >> 4, cl = lane & 15;
  int aoff[2], boff[8];
  #pragma unroll
  for (int mi = 0; mi < 2; ++mi) {
    int row = wr * 32 + mi * 16 + cl;
    aoff[mi] = row * 64 + ((q ^ ((row >> 1) & 3)) * 16);
  }
  #pragma unroll
  for (int nj = 0; nj < 8; ++nj) {
    int rn = wc * 128 + nj * 16 + cl;
    boff[nj] = rn * 64 + ((q ^ ((rn >> 1) & 3)) * 16);
  }

  f32x4 acc[2][8];
  #pragma unroll
  for (int mi = 0; mi < 2; ++mi)
    #pragma unroll
    for (int nj = 0; nj < 8; ++nj) {
      f32x4 z = {0.f, 0.f, 0.f, 0.f};
      acc[mi][nj] = z;
    }

  float4 a0 = *(const float4*)(gA_f);
  float4 a1 = *(const float4*)(gA_f + 4);
  *(u16x8*)(&As[0][lAoff]) = cvt8h(a0, a1);
  a0 = *(const float4*)(gA_f + 32);
  a1 = *(const float4*)(gA_f + 36);

  for (int t = 0; t < 32; ++t) {
    int cur = t & 1, nxt = cur ^ 1;
    int k0 = t * 32, k1 = k0 + 32;
    #pragma unroll
    for (int i = 0; i < 4; ++i) async_copy16(gB[i] + k0, &Bs[2048 * i + wid * 512]);
    if (t < 31) {
      *(u16x8*)(&As[nxt][lAoff]) = cvt8h(a0, a1);
      if (t < 30) {
        a0 = *(const float4*)(gA_f + k1 + 32);
        a1 = *(const float4*)(gA_f + k1 + 36);
      }
    }
    __syncthreads();
    bf16x8 af[2];
    #pragma unroll
    for (int mi = 0; mi < 2; ++mi)
      af[mi] = *(const bf16x8*)((const char*)As[cur] + aoff[mi]);
    #pragma unroll
    for (int nj = 0; nj < 8; ++nj) {
      bf16x8 bg = *(const bf16x8*)((const char*)Bs + boff[nj]);
      acc[0][nj] = __builtin_amdgcn_mfma_f32_16x16x32_bf16(af[0], bg, acc[0][nj], 0, 0, 0);
      acc[1][nj] = __builtin_amdgcn_mfma_f32_16x16x32_bf16(af[1], bg, acc[1][nj], 0, 0, 0);
    }
    __syncthreads();
  }

  if (joint) {
    #pragma unroll
    for (int mi = 0; mi < 2; ++mi) {
      #pragma unroll
      for (int j = 0; j < 4; ++j) {
        int m = wr * 32 + mi * 16 + q * 4 + j;
        float s = 0.f;
        #pragma unroll
        for (int nj = 0; nj < 8; ++nj) {
          int d = n0 + wc * 128 + nj * 16 + cl;
          s += tanhf(acc[mi][nj][j] + hW[(size_t)(bhalf + m) * DECD + d]) * v[d];
        }
        s += __shfl_xor(s, 1, 64);
        s += __shfl_xor(s, 2, 64);
        s += __shfl_xor(s, 4, 64);
        s += __shfl_xor(s, 8, 64);
        if (cl == 0) sbuf[m][wc] = s;
      }
    }
    __syncthreads();
    if (tid < 64)
      partJ[(size_t)bn * 51200 + m0 + tid] = sbuf[tid][0] + sbuf[tid][1];
  } else {
    #pragma unroll
    for (int mi = 0; mi < 2; ++mi) {
      #pragma unroll
      for (int nj = 0; nj < 8; ++nj) {
        int d = n0 + wc * 128 + nj * 16 + cl;
        #pragma unroll
        for (int j = 0; j < 4; ++j) {
          int m = wr * 32 + mi * 16 + q * 4 + j;
          preC[(m0 + m) * (size_t)DECD + d] = acc[mi][nj][j];
        }
      }
    }
  }
}

// copy epilogue (r10/r14/r15-verified): raw energies -> scC
__global__ __launch_bounds__(256) void k_copy_epi(const float* __restrict__ preC,
    const float* __restrict__ hWc, const float* __restrict__ v,
    float* __restrict__ scC) {
  int r = blockIdx.x * 4 + (threadIdx.x >> 6);
  int lane = threadIdx.x & 63;
  int b = r & 127, s = r >> 7;
  const float* pr = preC + (size_t)r * DECD + lane * 8;
  const float* hr = hWc + (size_t)b * DECD + lane * 8;
  const float* vr = v + lane * 8;
  float4 p0 = *(const float4*)(pr),     p1 = *(const float4*)(pr + 4);
  float4 h0 = *(const float4*)(hr),     h1 = *(const float4*)(hr + 4);
  float4 v0 = *(const float4*)(vr),     v1 = *(const float4*)(vr + 4);
  float acc = tanhf(p0.x + h0.x) * v0.x + tanhf(p0.y + h0.y) * v0.y
            + tanhf(p0.z + h0.z) * v0.z + tanhf(p0.w + h0.w) * v0.w
            + tanhf(p1.x + h1.x) * v1.x + tanhf(p1.y + h1.y) * v1.y
            + tanhf(p1.z + h1.z) * v1.z + tanhf(p1.w + h1.w) * v1.w;
  #pragma unroll
  for (int off = 32; off > 0; off >>= 1) acc += __shfl_xor(acc, off, 64);
  if (lane == 0) scC[(size_t)b * S1D + s] = acc;
}

// weighted partials with inline joint softmax (recomputed per block from partJ)
__global__ __launch_bounds__(256) void k_wpart_sm(const float* __restrict__ part,
    const float* __restrict__ enc1, const float* __restrict__ enc2,
    const int* __restrict__ m1, const int* __restrict__ m2,
    float* __restrict__ wp) {
  int b = blockIdx.x, tid = threadIdx.x;
  int e2 = blockIdx.y * 256 + tid;
  int scn = blockIdx.z;
  __shared__ float sm[4];
  __shared__ float ws[100];
  // masked energies (same math as r10-r15 k_softmax_j)
  int s0 = tid, s2 = tid + 256;
  float a0, a1 = -INFINITY;
  {
    int msk = (s0 < S1D) ? m1[b * S1D + s0] : m2[b * S2D + (s0 - S1D)];
    int m = s0 * 128 + b;
    a0 = msk ? (part[m] + part[51200 + m]) : NEGV;
  }
  if (s2 < SJD) {
    int msk = (s2 < S1D) ? m1[b * S1D + s2] : m2[b * S2D + (s2 - S1D)];
    int m = s2 * 128 + b;
    a1 = msk ? (part[m] + part[51200 + m]) : NEGV;
  }
  float vmax = fmaxf(a0, a1);
  #pragma unroll
  for (int off = 32; off > 0; off >>= 1) vmax = fmaxf(vmax, __shfl_down(vmax, off, 64));
  int lane = tid & 63, wid = tid >> 6;
  if (lane == 0) sm[wid] = vmax;
  __syncthreads();
  vmax = fmaxf(fmaxf(sm[0], sm[1]), fmaxf(sm[2], sm[3]));
  __syncthreads();
  float lsum = expf(a0 - vmax);
  if (s2 < SJD) lsum += expf(a1 - vmax);
  #pragma unroll
  for (int off = 32; off > 0; off >>= 1) lsum += __shfl_down(lsum, off, 64);
  if (lane == 0) sm[wid] = lsum;
  __syncthreads();
  float inv = 1.0f / (sm[0] + sm[1] + sm[2] + sm[3]);
  // this chunk's 100 weights -> LDS
  if (tid < 100) {
    int s = scn * 100 + tid;
    int msk = (s < S1D) ? m1[b * S1D + s] : m2[b * S2D + (s - S1D)];
    int m = s * 128 + b;
    float av = msk ? (part[m] + part[51200 + m]) : NEGV;
    ws[tid] = expf(av - vmax) * inv;
  }
  __syncthreads();
  // accumulate (r9/r14-verified fp32 enc reads)
  float acc0 = 0.f, acc1 = 0.f;
  #pragma unroll 4
  for (int i = 0; i < 100; ++i) {
    int s = scn * 100 + i;
    const float* ep = (s < S1D) ? (enc1 + ((size_t)s * BB + b) * E2D)
                                : (enc2 + ((size_t)(s - S1D) * BB + b) * E2D);
    float2 u = *(const float2*)(ep + e2 * 2);
    float w = ws[i];
    acc0 += w * u.x;
    acc1 += w * u.y;
  }
  float* dst = wp + ((size_t)scn * BB + b) * E2D + e2 * 2;
  dst[0] = acc0;
  dst[1] = acc1;
}

__global__ __launch_bounds__(256) void k_wsum_x(const float* __restrict__ wp,
    float* __restrict__ wgt, u16* __restrict__ x) {
  int i = blockIdx.x * 256 + threadIdx.x;
  const int NN = BB * E2D;
  float s = wp[i] + wp[NN + i] + wp[2 * NN + i] + wp[3 * NN + i];
  wgt[i] = s;
  int b = i >> 10, e = i & 1023;
  x[(size_t)b * 1280 + EMBD + e] = f2bf(s);
}

// ---------------- fc2 body as device function (r8/r15-verified structure) ----------------
__device__ __forceinline__ void fc2_body(
    const u16* __restrict__ A, const float* __restrict__ Bf,
    const float* __restrict__ bias, float* __restrict__ C,
    int N, int K, int n0) {
  __shared__ u16 As[2][128 * 32];
  __shared__ u16 Bs[2][128 * 32];
  int tid = threadIdx.x;
  int wid = tid >> 6, lane = tid & 63;
  int wr = wid >> 2, wc = wid & 3;

  int rowa = wid * 16 + (lane >> 2);
  int ca = (lane & 3) ^ ((rowa >> 1) & 3);
  const u16* gA = A + (size_t)rowa * K + ca * 8;

  int rB = tid >> 2, cB = tid & 3;
  int gnB = n0 + rB; if (gnB >= N) gnB = N - 1;
  const float* gB = Bf + (size_t)gnB * K + cB * 8;
  int lBoff = rB * 32 + ((cB ^ ((rB >> 1) & 3)) * 8);

  int q = lane >> 4, cl = lane & 15;
  int aoff[4], boff[2];
  #pragma unroll
  for (int mi = 0; mi < 4; ++mi) {
    int row = wr * 64 + mi * 16 + cl;
    aoff[mi] = row * 64 + ((q ^ ((row >> 1) & 3)) * 16);
  }
  #pragma unroll
  for (int nj = 0; nj < 2; ++nj) {
    int rn = wc * 32 + nj * 16 + cl;
    boff[nj] = rn * 64 + ((q ^ ((rn >> 1) & 3)) * 16);
  }

  f32x4 acc[4][2];
  #pragma unroll
  for (int mi = 0; mi < 4; ++mi)
    #pragma unroll
    for (int nj = 0; nj < 2; ++nj) {
      f32x4 z = {0.f, 0.f, 0.f, 0.f};
      acc[mi][nj] = z;
    }

  for (int k0 = 0; k0 < K; k0 += 64) {
    float4 b00 = *(const float4*)(gB + k0);
    float4 b01 = *(const float4*)(gB + k0 + 4);
    float4 b10 = *(const float4*)(gB + k0 + 32);
    float4 b11 = *(const float4*)(gB + k0 + 36);
    *(u16x8*)(&Bs[0][lBoff]) = cvt8h(b00, b01);
    *(u16x8*)(&Bs[1][lBoff]) = cvt8h(b10, b11);
    async_copy16(gA + k0,      &As[0][wid * 512]);
    async_copy16(gA + k0 + 32, &As[1][wid * 512]);
    __syncthreads();
    #pragma unroll
    for (int h = 0; h < 2; ++h) {
      bf16x8 af[4], bg[2];
      #pragma unroll
      for (int mi = 0; mi < 4; ++mi) af[mi] = *(const bf16x8*)((const char*)As[h] + aoff[mi]);
      #pragma unroll
      for (int nj = 0; nj < 2; ++nj) bg[nj] = *(const bf16x8*)((const char*)Bs[h] + boff[nj]);
      #pragma unroll
      for (int mi = 0; mi < 4; ++mi)
        #pragma unroll
        for (int nj = 0; nj < 2; ++nj)
          acc[mi][nj] = __builtin_amdgcn_mfma_f32_16x16x32_bf16(af[mi], bg[nj], acc[mi][nj], 0, 0, 0);
    }
    __syncthreads();
  }

  #pragma unroll
  for (int mi = 0; mi < 4; ++mi) {
    #pragma unroll
    for (int nj = 0; nj < 2; ++nj) {
      int n = n0 + wc * 32 + nj * 16 + cl;
      if (n < N) {
        float bv = bias[n];
        #pragma unroll
        for (int j = 0; j < 4; ++j) {
          int m = wr * 64 + mi * 16 + q * 4 + j;
          C[(size_t)m * N + n] = acc[mi][nj][j] + bv;
        }
      }
    }
  }
}

// merged GRU GEMMs (r15-verified)
__global__ __launch_bounds__(512) void gemm_gru(
    const u16* __restrict__ x_bf, const float* __restrict__ Wih,
    const float* __restrict__ bih, float* __restrict__ gx,
    const u16* __restrict__ h_bf, const float* __restrict__ Whh,
    const float* __restrict__ bhh, float* __restrict__ gh) {
  if (blockIdx.x < 12)
    fc2_body(x_bf, Wih, bih, gx, 1536, 1280, blockIdx.x * 128);
  else
    fc2_body(h_bf, Whh, bhh, gh, 1536, 512, (blockIdx.x - 12) * 128);
}

// ---------------- fc GEMM v3 with 1-deep B register prefetch (r3-verified pattern) ----------------
__global__ __launch_bounds__(512) void gemm_fc3(
    const u16* __restrict__ A, const float* __restrict__ Bf,
    const float* __restrict__ bias, float* __restrict__ C,
    int N, int K) {
  __shared__ u16 As[2][128 * 32];   // 2 x 8 KB
  __shared__ u16 Bs[2][64 * 32];    // 2 x 4 KB
  int tid = threadIdx.x;
  int wid = tid >> 6, lane = tid & 63;
  int wr = wid >> 2, wc = wid & 3;
  int n0 = blockIdx.x * 64;

  int rowa = wid * 16 + (lane >> 2);
  int ca = (lane & 3) ^ ((rowa >> 1) & 3);
  const u16* gA = A + (size_t)rowa * K + ca * 8;

  int rB = tid >> 3, cB = tid & 7;
  int gnB = n0 + rB; if (gnB >= N) gnB = N - 1;
  const float* gB = Bf + (size_t)gnB * K + cB * 8;
  int hB = cB >> 2, s4 = cB & 3;
  int lBoff = rB * 32 + ((s4 ^ ((rB >> 1) & 3)) * 8);

  int q = lane >> 4, cl = lane & 15;
  int aoff[4], boff;
  #pragma unroll
  for (int mi = 0; mi < 4; ++mi) {
    int row = wr * 64 + mi * 16 + cl;
    aoff[mi] = row * 64 + ((q ^ ((row >> 1) & 3)) * 16);
  }
  {
    int rn = wc * 16 + cl;
    boff = rn * 64 + ((q ^ ((rn >> 1) & 3)) * 16);
  }

  f32x4 acc[4];
  #pragma unroll
  for (int mi = 0; mi < 4; ++mi) {
    f32x4 z = {0.f, 0.f, 0.f, 0.f};
    acc[mi] = z;
  }

  float4 b0 = *(const float4*)(gB);
  float4 b1 = *(const float4*)(gB + 4);

  for (int k0 = 0; k0 < K; k0 += 64) {
    *(u16x8*)(&Bs[hB][lBoff]) = cvt8h(b0, b1);
    async_copy16(gA + k0,      &As[0][wid * 512]);
    async_copy16(gA + k0 + 32, &As[1][wid * 512]);
    __syncthreads();
    if (k0 + 64 < K) {               // prefetch next-phase B under MFMA
      b0 = *(const float4*)(gB + k0 + 64);
      b1 = *(const float4*)(gB + k0 + 68);
    }
    #pragma unroll
    for (int h = 0; h < 2; ++h) {
      bf16x8 af[4];
      #pragma unroll
      for (int mi = 0; mi < 4; ++mi) af[mi] = *(const bf16x8*)((const char*)As[h] + aoff[mi]);
      bf16x8 bg = *(const bf16x8*)((const char*)Bs[h] + boff);
      #pragma unroll
      for (int mi = 0; mi < 4; ++mi)
        acc[mi] = __builtin_amdgcn_mfma_f32_16x16x32_bf16(af[mi], bg, acc[mi], 0, 0, 0);
    }
    __syncthreads();
  }

  int n = n0 + wc * 16 + cl;
  if (n < N) {
    float bv = bias[n];
    #pragma unroll
    for (int mi = 0; mi < 4; ++mi)
      #pragma unroll
      for (int j = 0; j < 4; ++j) {
        int m = wr * 64 + mi * 16 + q * 4 + j;
        C[(size_t)m * N + n] = acc[mi][j] + bv;
      }
  }
}

// GRU pointwise + fused concat (r15-verified)
__global__ __launch_bounds__(256) void k_gru_concat(const float* __restrict__ gx,
    const float* __restrict__ gh, const float* __restrict__ hidden,
    const float* __restrict__ wgt, float* __restrict__ hnew,
    u16* __restrict__ st) {
  int b = blockIdx.x, tid = threadIdx.x;
  #pragma unroll
  for (int qq = 0; qq < 2; ++qq) {
    int d = tid + qq * 256;
    size_t o = (size_t)b * 1536;
    float xr = gx[o + d],        hr = gh[o + d];
    float xz = gx[o + 512 + d],  hz = gh[o + 512 + d];
    float xn = gx[o + 1024 + d], hn = gh[o + 1024 + d];
    float r = 1.f / (1.f + expf(-(xr + hr)));
    float z = 1.f / (1.f + expf(-(xz + hz)));
    float n = tanhf(xn + r * hn);
    float hv = (1.f - z) * n + z * hidden[(size_t)b * DECD + d];
    hnew[(size_t)b * DECD + d] = hv;
    st[(size_t)b * 1536 + d] = f2bf(hv);
  }
  #pragma unroll
  for (int qq = 0; qq < 4; ++qq) {
    int e = tid + qq * 256;
    st[(size_t)b * 1536 + DECD + e] = f2bf(wgt[(size_t)b * E2D + e]);
  }
}

// merged p_gen (blocks 0..127) + hWc partial (blocks 128..383)
__global__ __launch_bounds__(256) void k_pgen_partial(const float* __restrict__ wgt,
    const int* __restrict__ inp, const float* __restrict__ table,
    const float* __restrict__ gW, const float* __restrict__ gb,
    float* __restrict__ pg,
    const float* __restrict__ hnew, const float* __restrict__ copy_W,
    const float* __restrict__ copy_b, float* __restrict__ hWc) {
  int tid = threadIdx.x;
  if (blockIdx.x < 128) {
    int b = blockIdx.x;
    __shared__ float sm[4];
    float s = 0.f;
    for (int k = tid; k < E2D + EMBD; k += 256)
      s += gW[k] * ((k < E2D) ? wgt[(size_t)b * E2D + k]
                              : table[(size_t)inp[b] * EMBD + k - E2D]);
    #pragma unroll
    for (int off = 32; off > 0; off >>= 1) s += __shfl_down(s, off, 64);
    int lane = tid & 63, wid = tid >> 6;
    if (lane == 0) sm[wid] = s;
    __syncthreads();
    if (tid == 0) {
      float t = sm[0] + sm[1] + sm[2] + sm[3] + gb[0];
      pg[b] = 1.f / (1.f + expf(-t));
    }
  } else {
    int idx = blockIdx.x - 128;
    int b = idx >> 1;
    int d = (idx & 1) * 256 + tid;
    const float* hr = hnew + (size_t)b * DECD;
    float acc = copy_b[d];
    #pragma unroll 8
    for (int k = 0; k < DECD; ++k) acc += hr[k] * copy_W[(size_t)k * DECD + d];
    hWc[(size_t)b * DECD + d] = acc;
  }
}

// vocab softmax + p_gen scale + inline copy-softmax + scatter
__global__ __launch_bounds__(256) void k_vocab_sc2(float* __restrict__ dist,
    const float* __restrict__ pg, const float* __restrict__ scC,
    const int* __restrict__ m1, const int* __restrict__ tr,
    const int* __restrict__ src1) {
  int b = blockIdx.x, tid = threadIdx.x;
  float* row = dist + (size_t)b * VV;
  __shared__ float sm[4];
  int lane = tid & 63, wid = tid >> 6;
  // vocab softmax (r12-r15-verified)
  float m = -INFINITY;
  for (int i = tid; i < VV; i += 256) m = fmaxf(m, row[i]);
  #pragma unroll
  for (int off = 32; off > 0; off >>= 1) m = fmaxf(m, __shfl_down(m, off, 64));
  if (lane == 0) sm[wid] = m;
  __syncthreads();
  m = fmaxf(fmaxf(sm[0], sm[1]), fmaxf(sm[2], sm[3]));
  __syncthreads();
  float s = 0.f;
  for (int i = tid; i < VV; i += 256) s += expf(row[i] - m);
  #pragma unroll
  for (int off = 32; off > 0; off >>= 1) s += __shfl_down(s, off, 64);
  if (lane == 0) sm[wid] = s;
  __syncthreads();
  s = sm[0] + sm[1] + sm[2] + sm[3];
  float pgb = pg[b];
  float scale = pgb / s;
  for (int i = tid; i < VV; i += 256) row[i] = expf(row[i] - m) * scale;
  __syncthreads();
  // copy masked softmax over raw scC (same math as r10-r15 k_softmax_s)
  float c0 = -INFINITY;
  if (tid < S1D) {
    int msk = m1[b * S1D + tid] * tr[b * S1D + tid];
    c0 = msk ? scC[(size_t)b * S1D + tid] : NEGV;
  }
  float cmax = c0;
  #pragma unroll
  for (int off = 32; off > 0; off >>= 1) cmax = fmaxf(cmax, __shfl_down(cmax, off, 64));
  if (lane == 0) sm[wid] = cmax;
  __syncthreads();
  cmax = fmaxf(fmaxf(sm[0], sm[1]), fmaxf(sm[2], sm[3]));
  __syncthreads();
  float csum = (tid < S1D) ? expf(c0 - cmax) : 0.f;
  #pragma unroll
  for (int off = 32; off > 0; off >>= 1) csum += __shfl_down(csum, off, 64);
  if (lane == 0) sm[wid] = csum;
  __syncthreads();
  float cinv = 1.0f / (sm[0] + sm[1] + sm[2] + sm[3]);
  if (tid < S1D) {
    float val = (1.f - pgb) * expf(c0 - cmax) * cinv;
    int tok = src1[(size_t)tid * BB + b];
    atomicAdd(&row[tok], val);
  }
}

extern "C" void kernel_launch(void* const* d_in, const int* in_sizes, int n_in,
                              void* d_out, int out_size, void* d_ws, size_t ws_size,
                              hipStream_t stream) {
  (void)in_sizes; (void)n_in; (void)out_size; (void)ws_size;
  const int*   input  = (const int*)d_in[0];
  const float* hidden = (const float*)d_in[1];
  const int*   src1   = (const int*)d_in[2];
  const float* enc1   = (const float*)d_in[3];
  const int*   mask1  = (const int*)d_in[4];
  const int*   triple = (const int*)d_in[5];
  const float* enc2   = (const float*)d_in[6];
  const int*   mask2  = (const int*)d_in[7];
  const float* embedding = (const float*)d_in[8];
  const float* attn_W = (const float*)d_in[9];
  const float* attn_b = (const float*)d_in[10];
  const float* attn_v = (const float*)d_in[11];
  const float* copy_W = (const float*)d_in[12];
  const float* copy_b = (const float*)d_in[13];
  const float* copy_v = (const float*)d_in[14];
  const float* gru_Wih = (const float*)d_in[15];
  const float* gru_Whh = (const float*)d_in[16];
  const float* gru_bih = (const float*)d_in[17];
  const float* gru_bhh = (const float*)d_in[18];
  const float* fc_W   = (const float*)d_in[19];
  const float* fc_b   = (const float*)d_in[20];
  const float* gate_W = (const float*)d_in[21];
  const float* gate_b = (const float*)d_in[22];

  char* w = (char*)d_ws;
  u16* Wt_a = (u16*)w;                w += (size_t)512 * 1024 * 2;
  u16* Wt_c = (u16*)w;                w += (size_t)512 * 1024 * 2;
  float* partJ = (float*)w;           w += (size_t)2 * 51200 * 4;
  float* preC = (float*)w;            w += (size_t)25600 * 512 * 4;
  float* hWa  = (float*)w;            w += (size_t)BB * DECD * 4;
  float* hWc  = (float*)w;            w += (size_t)BB * DECD * 4;
  float* scC  = (float*)w;            w += (size_t)BB * S1D * 4;
  float* wgt  = (float*)w;            w += (size_t)BB * E2D * 4;
  float* wpart = (float*)w;           w += (size_t)4 * BB * E2D * 4;
  u16*   x_bf = (u16*)w;              w += (size_t)BB * 1280 * 2;
  u16*   hid_bf = (u16*)w;            w += (size_t)BB * DECD * 2;
  float* gx   = (float*)w;            w += (size_t)BB * 1536 * 4;
  float* gh   = (float*)w;            w += (size_t)BB * 1536 * 4;
  u16*   st_bf = (u16*)w;             w += (size_t)BB * 1536 * 2;
  float* pg   = (float*)w;            w += 512;

  float* out  = (float*)d_out;
  float* hnew = out + (size_t)BB * VV;

  // fused prep
  k_prep<<<1440, 256, 0, stream>>>(attn_W, copy_W, Wt_a, Wt_c,
                                   hidden, hid_bf, attn_b, hWa,
                                   input, embedding, x_bf);

  // combined joint-attn + copy-preactivation energy GEMM
  gemm_energy_jc<<<dim3(2, JY + 400), 256, 0, stream>>>(
      enc1, enc2, Wt_a, Wt_c, hWa, attn_v, partJ, preC);

  // weighted context with inline joint softmax
  k_wpart_sm<<<dim3(BB, 2, 4), 256, 0, stream>>>(partJ, enc1, enc2, mask1, mask2, wpart);
  k_wsum_x<<<512, 256, 0, stream>>>(wpart, wgt, x_bf);

  // GRU
  gemm_gru<<<24, 512, 0, stream>>>(x_bf, gru_Wih, gru_bih, gx,
                                   hid_bf, gru_Whh, gru_bhh, gh);
  k_gru_concat<<<BB, 256, 0, stream>>>(gx, gh, hidden, wgt, hnew, st_bf);

  // vocab logits
  gemm_fc3<<<(VV + 63) / 64, 512, 0, stream>>>(st_bf, fc_W, fc_b, out, VV, 1536);

  // copy path
  k_pgen_partial<<<384, 256, 0, stream>>>(wgt, input, embedding, gate_W, gate_b, pg,
                                          hnew, copy_W, copy_b, hWc);
  k_copy_epi<<<25600 / 4, 256, 0, stream>>>(preC, hWc, copy_v, scC);

  // final distribution (vocab softmax + copy softmax + scatter)
  k_vocab_sc2<<<BB, 256, 0, stream>>>(out, pg, scC, mask1, triple, src1);
}

// Round 17
// 565.501 us; speedup vs baseline: 1.4158x; 1.0196x over previous
//
#include <hip/hip_runtime.h>
#include <math.h>

#define BB   128
#define DECD 512
#define E2D  1024
#define EMBD 256
#define S1D  200
#define S2D  200
#define SJD  400
#define VV   50000
#define NEGV (-1e10f)
#define JY   800   // joint tiles (51200 rows / 64); copy tiles follow

typedef unsigned short u16;
typedef __bf16 bf16x8 __attribute__((ext_vector_type(8)));
typedef float f32x4 __attribute__((ext_vector_type(4)));
typedef u16 u16x8 __attribute__((ext_vector_type(8)));

__device__ __forceinline__ u16 f2bf(float x) {
  unsigned u = __float_as_uint(x);
  unsigned r = (u + 0x7fffu + ((u >> 16) & 1u)) >> 16;
  return (u16)r;
}
__device__ __forceinline__ float bf2f(u16 h) {
  return __uint_as_float(((unsigned)h) << 16);
}
// hardware RTNE pack (r7/r16-verified: identical absmax to manual f2bf)
__device__ __forceinline__ u16x8 cvt8h(float4 a, float4 b) {
  bf16x8 r;
  r[0] = (__bf16)a.x; r[1] = (__bf16)a.y; r[2] = (__bf16)a.z; r[3] = (__bf16)a.w;
  r[4] = (__bf16)b.x; r[5] = (__bf16)b.y; r[6] = (__bf16)b.z; r[7] = (__bf16)b.w;
  return *reinterpret_cast<u16x8*>(&r);
}

typedef const __attribute__((address_space(1))) void* gas_t;
typedef __attribute__((address_space(3))) void* las_t;
__device__ __forceinline__ void async_copy16(const u16* g, u16* l) {
  __builtin_amdgcn_global_load_lds((gas_t)g, (las_t)l, 16, 0, 0);
}

// ---------------- fused prep (r16-verified): wt2 | cvt hid | hWa | embx ----------------
__global__ __launch_bounds__(256) void k_prep(
    const float* __restrict__ Wa, const float* __restrict__ Wc,
    u16* __restrict__ Wta, u16* __restrict__ Wtc,
    const float* __restrict__ hidden, u16* __restrict__ hid_bf,
    const float* __restrict__ attn_b, float* __restrict__ hWa,
    const int* __restrict__ inp, const float* __restrict__ table,
    u16* __restrict__ x_bf) {
  int blk = blockIdx.x, tid = threadIdx.x;
  if (blk < 1024) {
    __shared__ float t[32][33];
    int z = blk >> 9, rem = blk & 511;
    int bk = rem & 31, bn = rem >> 5;
    const float* W = z ? Wc : Wa;
    u16* Wt = z ? Wtc : Wta;
    int tx = tid & 31, ty = tid >> 5;
    #pragma unroll
    for (int r = 0; r < 4; ++r) {
      int k = bk * 32 + ty + r * 8;
      t[ty + r * 8][tx] = W[(size_t)(512 + k) * 512 + bn * 32 + tx];
    }
    __syncthreads();
    #pragma unroll
    for (int r = 0; r < 4; ++r) {
      int n = bn * 32 + ty + r * 8;
      Wt[(size_t)n * 1024 + bk * 32 + tx] = f2bf(t[tx][ty + r * 8]);
    }
  } else if (blk < 1056) {
    int i = (blk - 1024) * 256 + tid;
    const float4 f0 = *(const float4*)(hidden + (size_t)i * 8);
    const float4 f1 = *(const float4*)(hidden + (size_t)i * 8 + 4);
    *(u16x8*)(hid_bf + (size_t)i * 8) = cvt8h(f0, f1);
  } else if (blk < 1312) {
    int idx = blk - 1056;
    int b = idx >> 1;
    int d = (idx & 1) * 256 + tid;
    const float* hr = hidden + (size_t)b * DECD;
    float acc = attn_b[d];
    #pragma unroll 8
    for (int k = 0; k < DECD; ++k) acc += hr[k] * Wa[(size_t)k * DECD + d];
    hWa[(size_t)b * DECD + d] = acc;
  } else {
    int b = blk - 1312;
    x_bf[(size_t)b * 1280 + tid] = f2bf(table[(size_t)inp[b] * EMBD + tid]);
  }
}

// ---------------- combined joint+copy energy GEMM (r14-r16-verified) ----------------
__global__ __launch_bounds__(256) void gemm_energy_jc(
    const float* __restrict__ enc1, const float* __restrict__ enc2,
    const u16* __restrict__ BtA, const u16* __restrict__ BtC,
    const float* __restrict__ hW, const float* __restrict__ v,
    float* __restrict__ partJ, float* __restrict__ preC) {
  __shared__ u16 As[2][64 * 32];   // 2 x 4 KB
  __shared__ u16 Bs[256 * 32];     // 16 KB
  __shared__ float sbuf[64][2];
  int tid = threadIdx.x;
  int wid = tid >> 6, lane = tid & 63;
  int wr = wid >> 1, wc = wid & 1;
  int bn = blockIdx.x;
  int jy = blockIdx.y;
  int joint = (jy < JY);
  size_t m0 = joint ? (size_t)jy * 64 : (size_t)(jy - JY) * 64;
  int bhalf = (jy & 1) * 64;
  int n0 = bn * 256;

  int rA = tid >> 2, cslot = tid & 3;
  int lAoff = rA * 32 + ((cslot ^ ((rA >> 1) & 3)) * 8);
  const float* base;
  if (joint)
    base = (m0 < (size_t)S1D * BB) ? (enc1 + m0 * E2D)
                                   : (enc2 + (m0 - (size_t)S1D * BB) * E2D);
  else
    base = enc1 + m0 * E2D;
  const float* gA_f = base + (size_t)rA * E2D + cslot * 8;

  const u16* Bt = joint ? BtA : BtC;
  const u16* gB[4];
  #pragma unroll
  for (int i = 0; i < 4; ++i) {
    int rn = i * 64 + wid * 16 + (lane >> 2);
    int c = (lane & 3) ^ ((rn >> 1) & 3);
    gB[i] = Bt + (size_t)(n0 + rn) * E2D + c * 8;
  }

  int q = lane >> 4, cl = lane & 15;
  int aoff[2], boff[8];
  #pragma unroll
  for (int mi = 0; mi < 2; ++mi) {
    int row = wr * 32 + mi * 16 + cl;
    aoff[mi] = row * 64 + ((q ^ ((row >> 1) & 3)) * 16);
  }
  #pragma unroll
  for (int nj = 0; nj < 8; ++nj) {
    int rn = wc * 128 + nj * 16 + cl;
    boff[nj] = rn * 64 + ((q ^ ((rn >> 1) & 3)) * 16);
  }

  f32x4 acc[2][8];
  #pragma unroll
  for (int mi = 0; mi < 2; ++mi)
    #pragma unroll
    for (int nj = 0; nj < 8; ++nj) {
      f32x4 z = {0.f, 0.f, 0.f, 0.f};
      acc[mi][nj] = z;
    }

  float4 a0 = *(const float4*)(gA_f);
  float4 a1 = *(const float4*)(gA_f + 4);
  *(u16x8*)(&As[0][lAoff]) = cvt8h(a0, a1);
  a0 = *(const float4*)(gA_f + 32);
  a1 = *(const float4*)(gA_f + 36);

  for (int t = 0; t < 32; ++t) {
    int cur = t & 1, nxt = cur ^ 1;
    int k0 = t * 32, k1 = k0 + 32;
    #pragma unroll
    for (int i = 0; i < 4; ++i) async_copy16(gB[i] + k0, &Bs[2048 * i + wid * 512]);
    if (t < 31) {
      *(u16x8*)(&As[nxt][lAoff]) = cvt8h(a0, a1);
      if (t < 30) {
        a0 = *(const float4*)(gA_f + k1 + 32);
        a1 = *(const float4*)(gA_f + k1 + 36);
      }
    }
    __syncthreads();
    bf16x8 af[2];
    #pragma unroll
    for (int mi = 0; mi < 2; ++mi)
      af[mi] = *(const bf16x8*)((const char*)As[cur] + aoff[mi]);
    #pragma unroll
    for (int nj = 0; nj < 8; ++nj) {
      bf16x8 bg = *(const bf16x8*)((const char*)Bs + boff[nj]);
      acc[0][nj] = __builtin_amdgcn_mfma_f32_16x16x32_bf16(af[0], bg, acc[0][nj], 0, 0, 0);
      acc[1][nj] = __builtin_amdgcn_mfma_f32_16x16x32_bf16(af[1], bg, acc[1][nj], 0, 0, 0);
    }
    __syncthreads();
  }

  if (joint) {
    #pragma unroll
    for (int mi = 0; mi < 2; ++mi) {
      #pragma unroll
      for (int j = 0; j < 4; ++j) {
        int m = wr * 32 + mi * 16 + q * 4 + j;
        float s = 0.f;
        #pragma unroll
        for (int nj = 0; nj < 8; ++nj) {
          int d = n0 + wc * 128 + nj * 16 + cl;
          s += tanhf(acc[mi][nj][j] + hW[(size_t)(bhalf + m) * DECD + d]) * v[d];
        }
        s += __shfl_xor(s, 1, 64);
        s += __shfl_xor(s, 2, 64);
        s += __shfl_xor(s, 4, 64);
        s += __shfl_xor(s, 8, 64);
        if (cl == 0) sbuf[m][wc] = s;
      }
    }
    __syncthreads();
    if (tid < 64)
      partJ[(size_t)bn * 51200 + m0 + tid] = sbuf[tid][0] + sbuf[tid][1];
  } else {
    #pragma unroll
    for (int mi = 0; mi < 2; ++mi) {
      #pragma unroll
      for (int nj = 0; nj < 8; ++nj) {
        int d = n0 + wc * 128 + nj * 16 + cl;
        #pragma unroll
        for (int j = 0; j < 4; ++j) {
          int m = wr * 32 + mi * 16 + q * 4 + j;
          preC[(m0 + m) * (size_t)DECD + d] = acc[mi][nj][j];
        }
      }
    }
  }
}

// weighted partials with inline joint softmax (r16-verified)
__global__ __launch_bounds__(256) void k_wpart_sm(const float* __restrict__ part,
    const float* __restrict__ enc1, const float* __restrict__ enc2,
    const int* __restrict__ m1, const int* __restrict__ m2,
    float* __restrict__ wp) {
  int b = blockIdx.x, tid = threadIdx.x;
  int e2 = blockIdx.y * 256 + tid;
  int scn = blockIdx.z;
  __shared__ float sm[4];
  __shared__ float ws[100];
  int s0 = tid, s2 = tid + 256;
  float a0, a1 = -INFINITY;
  {
    int msk = (s0 < S1D) ? m1[b * S1D + s0] : m2[b * S2D + (s0 - S1D)];
    int m = s0 * 128 + b;
    a0 = msk ? (part[m] + part[51200 + m]) : NEGV;
  }
  if (s2 < SJD) {
    int msk = (s2 < S1D) ? m1[b * S1D + s2] : m2[b * S2D + (s2 - S1D)];
    int m = s2 * 128 + b;
    a1 = msk ? (part[m] + part[51200 + m]) : NEGV;
  }
  float vmax = fmaxf(a0, a1);
  #pragma unroll
  for (int off = 32; off > 0; off >>= 1) vmax = fmaxf(vmax, __shfl_down(vmax, off, 64));
  int lane = tid & 63, wid = tid >> 6;
  if (lane == 0) sm[wid] = vmax;
  __syncthreads();
  vmax = fmaxf(fmaxf(sm[0], sm[1]), fmaxf(sm[2], sm[3]));
  __syncthreads();
  float lsum = expf(a0 - vmax);
  if (s2 < SJD) lsum += expf(a1 - vmax);
  #pragma unroll
  for (int off = 32; off > 0; off >>= 1) lsum += __shfl_down(lsum, off, 64);
  if (lane == 0) sm[wid] = lsum;
  __syncthreads();
  float inv = 1.0f / (sm[0] + sm[1] + sm[2] + sm[3]);
  if (tid < 100) {
    int s = scn * 100 + tid;
    int msk = (s < S1D) ? m1[b * S1D + s] : m2[b * S2D + (s - S1D)];
    int m = s * 128 + b;
    float av = msk ? (part[m] + part[51200 + m]) : NEGV;
    ws[tid] = expf(av - vmax) * inv;
  }
  __syncthreads();
  float acc0 = 0.f, acc1 = 0.f;
  #pragma unroll 4
  for (int i = 0; i < 100; ++i) {
    int s = scn * 100 + i;
    const float* ep = (s < S1D) ? (enc1 + ((size_t)s * BB + b) * E2D)
                                : (enc2 + ((size_t)(s - S1D) * BB + b) * E2D);
    float2 u = *(const float2*)(ep + e2 * 2);
    float w = ws[i];
    acc0 += w * u.x;
    acc1 += w * u.y;
  }
  float* dst = wp + ((size_t)scn * BB + b) * E2D + e2 * 2;
  dst[0] = acc0;
  dst[1] = acc1;
}

__global__ __launch_bounds__(256) void k_wsum_x(const float* __restrict__ wp,
    float* __restrict__ wgt, u16* __restrict__ x) {
  int i = blockIdx.x * 256 + threadIdx.x;
  const int NN = BB * E2D;
  float s = wp[i] + wp[NN + i] + wp[2 * NN + i] + wp[3 * NN + i];
  wgt[i] = s;
  int b = i >> 10, e = i & 1023;
  x[(size_t)b * 1280 + EMBD + e] = f2bf(s);
}

// ---------------- fc2 body as device function (r8/r15/r16-verified) ----------------
__device__ __forceinline__ void fc2_body(
    const u16* __restrict__ A, const float* __restrict__ Bf,
    const float* __restrict__ bias, float* __restrict__ C,
    int N, int K, int n0) {
  __shared__ u16 As[2][128 * 32];
  __shared__ u16 Bs[2][128 * 32];
  int tid = threadIdx.x;
  int wid = tid >> 6, lane = tid & 63;
  int wr = wid >> 2, wc = wid & 3;

  int rowa = wid * 16 + (lane >> 2);
  int ca = (lane & 3) ^ ((rowa >> 1) & 3);
  const u16* gA = A + (size_t)rowa * K + ca * 8;

  int rB = tid >> 2, cB = tid & 3;
  int gnB = n0 + rB; if (gnB >= N) gnB = N - 1;
  const float* gB = Bf + (size_t)gnB * K + cB * 8;
  int lBoff = rB * 32 + ((cB ^ ((rB >> 1) & 3)) * 8);

  int q = lane >> 4, cl = lane & 15;
  int aoff[4], boff[2];
  #pragma unroll
  for (int mi = 0; mi < 4; ++mi) {
    int row = wr * 64 + mi * 16 + cl;
    aoff[mi] = row * 64 + ((q ^ ((row >> 1) & 3)) * 16);
  }
  #pragma unroll
  for (int nj = 0; nj < 2; ++nj) {
    int rn = wc * 32 + nj * 16 + cl;
    boff[nj] = rn * 64 + ((q ^ ((rn >> 1) & 3)) * 16);
  }

  f32x4 acc[4][2];
  #pragma unroll
  for (int mi = 0; mi < 4; ++mi)
    #pragma unroll
    for (int nj = 0; nj < 2; ++nj) {
      f32x4 z = {0.f, 0.f, 0.f, 0.f};
      acc[mi][nj] = z;
    }

  for (int k0 = 0; k0 < K; k0 += 64) {
    float4 b00 = *(const float4*)(gB + k0);
    float4 b01 = *(const float4*)(gB + k0 + 4);
    float4 b10 = *(const float4*)(gB + k0 + 32);
    float4 b11 = *(const float4*)(gB + k0 + 36);
    *(u16x8*)(&Bs[0][lBoff]) = cvt8h(b00, b01);
    *(u16x8*)(&Bs[1][lBoff]) = cvt8h(b10, b11);
    async_copy16(gA + k0,      &As[0][wid * 512]);
    async_copy16(gA + k0 + 32, &As[1][wid * 512]);
    __syncthreads();
    #pragma unroll
    for (int h = 0; h < 2; ++h) {
      bf16x8 af[4], bg[2];
      #pragma unroll
      for (int mi = 0; mi < 4; ++mi) af[mi] = *(const bf16x8*)((const char*)As[h] + aoff[mi]);
      #pragma unroll
      for (int nj = 0; nj < 2; ++nj) bg[nj] = *(const bf16x8*)((const char*)Bs[h] + boff[nj]);
      #pragma unroll
      for (int mi = 0; mi < 4; ++mi)
        #pragma unroll
        for (int nj = 0; nj < 2; ++nj)
          acc[mi][nj] = __builtin_amdgcn_mfma_f32_16x16x32_bf16(af[mi], bg[nj], acc[mi][nj], 0, 0, 0);
    }
    __syncthreads();
  }

  #pragma unroll
  for (int mi = 0; mi < 4; ++mi) {
    #pragma unroll
    for (int nj = 0; nj < 2; ++nj) {
      int n = n0 + wc * 32 + nj * 16 + cl;
      if (n < N) {
        float bv = bias[n];
        #pragma unroll
        for (int j = 0; j < 4; ++j) {
          int m = wr * 64 + mi * 16 + q * 4 + j;
          C[(size_t)m * N + n] = acc[mi][nj][j] + bv;
        }
      }
    }
  }
}

// merged GRU GEMMs (r15/r16-verified)
__global__ __launch_bounds__(512) void gemm_gru(
    const u16* __restrict__ x_bf, const float* __restrict__ Wih,
    const float* __restrict__ bih, float* __restrict__ gx,
    const u16* __restrict__ h_bf, const float* __restrict__ Whh,
    const float* __restrict__ bhh, float* __restrict__ gh) {
  if (blockIdx.x < 12)
    fc2_body(x_bf, Wih, bih, gx, 1536, 1280, blockIdx.x * 128);
  else
    fc2_body(h_bf, Whh, bhh, gh, 1536, 512, (blockIdx.x - 12) * 128);
}

// ---------------- combined fc3 + pgen + copy-epilogue launch ----------------
// blocks 0..781   : fc3 (r15/r16-verified body, B 1-deep prefetch)
// blocks 782..909 : p_gen per b (r16-verified math, 512-thread stride)
// blocks 910..1037: copy epilogue per b (hWc in-block + 200 energies -> raw scC)
__global__ __launch_bounds__(512) void gemm_fc3c(
    const u16* __restrict__ A, const float* __restrict__ Bf,
    const float* __restrict__ bias, float* __restrict__ C, int N, int K,
    const float* __restrict__ wgt, const int* __restrict__ inp,
    const float* __restrict__ table, const float* __restrict__ gW,
    const float* __restrict__ gb, float* __restrict__ pg,
    const float* __restrict__ hnew, const float* __restrict__ copy_W,
    const float* __restrict__ copy_b, const float* __restrict__ copy_v,
    const float* __restrict__ preC, float* __restrict__ scC) {
  __shared__ u16 smem[12288];   // 24.6 KB pool, aliased per role
  int tid = threadIdx.x;
  if (blockIdx.x < 782) {
    // ---- fc3 body ----
    u16* As0 = smem;            u16* As1 = smem + 4096;
    u16* Bs0 = smem + 8192;     u16* Bs1 = smem + 10240;
    u16* AsH[2] = {As0, As1};
    u16* BsH[2] = {Bs0, Bs1};
    int wid = tid >> 6, lane = tid & 63;
    int wr = wid >> 2, wc = wid & 3;
    int n0 = blockIdx.x * 64;

    int rowa = wid * 16 + (lane >> 2);
    int ca = (lane & 3) ^ ((rowa >> 1) & 3);
    const u16* gA = A + (size_t)rowa * K + ca * 8;

    int rB = tid >> 3, cB = tid & 7;
    int gnB = n0 + rB; if (gnB >= N) gnB = N - 1;
    const float* gB = Bf + (size_t)gnB * K + cB * 8;
    int hB = cB >> 2, s4 = cB & 3;
    int lBoff = rB * 32 + ((s4 ^ ((rB >> 1) & 3)) * 8);

    int q = lane >> 4, cl = lane & 15;
    int aoff[4], boff;
    #pragma unroll
    for (int mi = 0; mi < 4; ++mi) {
      int row = wr * 64 + mi * 16 + cl;
      aoff[mi] = row * 64 + ((q ^ ((row >> 1) & 3)) * 16);
    }
    {
      int rn = wc * 16 + cl;
      boff = rn * 64 + ((q ^ ((rn >> 1) & 3)) * 16);
    }

    f32x4 acc[4];
    #pragma unroll
    for (int mi = 0; mi < 4; ++mi) {
      f32x4 z = {0.f, 0.f, 0.f, 0.f};
      acc[mi] = z;
    }

    float4 b0 = *(const float4*)(gB);
    float4 b1 = *(const float4*)(gB + 4);

    for (int k0 = 0; k0 < K; k0 += 64) {
      *(u16x8*)(&BsH[hB][lBoff]) = cvt8h(b0, b1);
      async_copy16(gA + k0,      &As0[wid * 512]);
      async_copy16(gA + k0 + 32, &As1[wid * 512]);
      __syncthreads();
      if (k0 + 64 < K) {
        b0 = *(const float4*)(gB + k0 + 64);
        b1 = *(const float4*)(gB + k0 + 68);
      }
      #pragma unroll
      for (int h = 0; h < 2; ++h) {
        bf16x8 af[4];
        #pragma unroll
        for (int mi = 0; mi < 4; ++mi) af[mi] = *(const bf16x8*)((const char*)AsH[h] + aoff[mi]);
        bf16x8 bg = *(const bf16x8*)((const char*)BsH[h] + boff);
        #pragma unroll
        for (int mi = 0; mi < 4; ++mi)
          acc[mi] = __builtin_amdgcn_mfma_f32_16x16x32_bf16(af[mi], bg, acc[mi], 0, 0, 0);
      }
      __syncthreads();
    }

    int n = n0 + wc * 16 + cl;
    if (n < N) {
      float bv = bias[n];
      #pragma unroll
      for (int mi = 0; mi < 4; ++mi)
        #pragma unroll
        for (int j = 0; j < 4; ++j) {
          int m = wr * 64 + mi * 16 + q * 4 + j;
          C[(size_t)m * N + n] = acc[mi][j] + bv;
        }
    }
  } else if (blockIdx.x < 910) {
    // ---- p_gen per b (r16-verified math) ----
    int b = blockIdx.x - 782;
    float* sm = (float*)smem;
    float s = 0.f;
    for (int k = tid; k < E2D + EMBD; k += 512)
      s += gW[k] * ((k < E2D) ? wgt[(size_t)b * E2D + k]
                              : table[(size_t)inp[b] * EMBD + k - E2D]);
    #pragma unroll
    for (int off = 32; off > 0; off >>= 1) s += __shfl_down(s, off, 64);
    int lane = tid & 63, wid = tid >> 6;
    if (lane == 0) sm[wid] = s;
    __syncthreads();
    if (tid == 0) {
      float t = sm[0] + sm[1] + sm[2] + sm[3] + sm[4] + sm[5] + sm[6] + sm[7] + gb[0];
      pg[b] = 1.f / (1.f + expf(-t));
    }
  } else {
    // ---- copy epilogue per b: hWc in-block, then 200 energies -> raw scC ----
    int b = blockIdx.x - 910;
    float* hn  = (float*)smem;          // 512 floats
    float* hwc = (float*)smem + 512;    // 512 floats
    hn[tid] = hnew[(size_t)b * DECD + tid];
    __syncthreads();
    {
      float acc = copy_b[tid];
      #pragma unroll 8
      for (int k = 0; k < DECD; ++k) acc += hn[k] * copy_W[(size_t)k * DECD + tid];
      hwc[tid] = acc;
    }
    __syncthreads();
    int wid = tid >> 6, lane = tid & 63;
    float4 h0 = *(const float4*)(hwc + lane * 8);
    float4 h1 = *(const float4*)(hwc + lane * 8 + 4);
    float4 v0 = *(const float4*)(copy_v + lane * 8);
    float4 v1 = *(const float4*)(copy_v + lane * 8 + 4);
    for (int s = wid; s < S1D; s += 8) {
      const float* pr = preC + ((size_t)s * 128 + b) * DECD + lane * 8;
      float4 p0 = *(const float4*)(pr);
      float4 p1 = *(const float4*)(pr + 4);
      float e = tanhf(p0.x + h0.x) * v0.x + tanhf(p0.y + h0.y) * v0.y
              + tanhf(p0.z + h0.z) * v0.z + tanhf(p0.w + h0.w) * v0.w
              + tanhf(p1.x + h1.x) * v1.x + tanhf(p1.y + h1.y) * v1.y
              + tanhf(p1.z + h1.z) * v1.z + tanhf(p1.w + h1.w) * v1.w;
      #pragma unroll
      for (int off = 32; off > 0; off >>= 1) e += __shfl_xor(e, off, 64);
      if (lane == 0) scC[(size_t)b * S1D + s] = e;
    }
  }
}

// GRU pointwise + fused concat (r15/r16-verified)
__global__ __launch_bounds__(256) void k_gru_concat(const float* __restrict__ gx,
    const float* __restrict__ gh, const float* __restrict__ hidden,
    const float* __restrict__ wgt, float* __restrict__ hnew,
    u16* __restrict__ st) {
  int b = blockIdx.x, tid = threadIdx.x;
  #pragma unroll
  for (int qq = 0; qq < 2; ++qq) {
    int d = tid + qq * 256;
    size_t o = (size_t)b * 1536;
    float xr = gx[o + d],        hr = gh[o + d];
    float xz = gx[o + 512 + d],  hz = gh[o + 512 + d];
    float xn = gx[o + 1024 + d], hn = gh[o + 1024 + d];
    float r = 1.f / (1.f + expf(-(xr + hr)));
    float z = 1.f / (1.f + expf(-(xz + hz)));
    float n = tanhf(xn + r * hn);
    float hv = (1.f - z) * n + z * hidden[(size_t)b * DECD + d];
    hnew[(size_t)b * DECD + d] = hv;
    st[(size_t)b * 1536 + d] = f2bf(hv);
  }
  #pragma unroll
  for (int qq = 0; qq < 4; ++qq) {
    int e = tid + qq * 256;
    st[(size_t)b * 1536 + DECD + e] = f2bf(wgt[(size_t)b * E2D + e]);
  }
}

// vocab softmax + p_gen scale + inline copy-softmax + scatter (r16-verified)
__global__ __launch_bounds__(256) void k_vocab_sc2(float* __restrict__ dist,
    const float* __restrict__ pg, const float* __restrict__ scC,
    const int* __restrict__ m1, const int* __restrict__ tr,
    const int* __restrict__ src1) {
  int b = blockIdx.x, tid = threadIdx.x;
  float* row = dist + (size_t)b * VV;
  __shared__ float sm[4];
  int lane = tid & 63, wid = tid >> 6;
  float m = -INFINITY;
  for (int i = tid; i < VV; i += 256) m = fmaxf(m, row[i]);
  #pragma unroll
  for (int off = 32; off > 0; off >>= 1) m = fmaxf(m, __shfl_down(m, off, 64));
  if (lane == 0) sm[wid] = m;
  __syncthreads();
  m = fmaxf(fmaxf(sm[0], sm[1]), fmaxf(sm[2], sm[3]));
  __syncthreads();
  float s = 0.f;
  for (int i = tid; i < VV; i += 256) s += expf(row[i] - m);
  #pragma unroll
  for (int off = 32; off > 0; off >>= 1) s += __shfl_down(s, off, 64);
  if (lane == 0) sm[wid] = s;
  __syncthreads();
  s = sm[0] + sm[1] + sm[2] + sm[3];
  float pgb = pg[b];
  float scale = pgb / s;
  for (int i = tid; i < VV; i += 256) row[i] = expf(row[i] - m) * scale;
  __syncthreads();
  float c0 = -INFINITY;
  if (tid < S1D) {
    int msk = m1[b * S1D + tid] * tr[b * S1D + tid];
    c0 = msk ? scC[(size_t)b * S1D + tid] : NEGV;
  }
  float cmax = c0;
  #pragma unroll
  for (int off = 32; off > 0; off >>= 1) cmax = fmaxf(cmax, __shfl_down(cmax, off, 64));
  if (lane == 0) sm[wid] = cmax;
  __syncthreads();
  cmax = fmaxf(fmaxf(sm[0], sm[1]), fmaxf(sm[2], sm[3]));
  __syncthreads();
  float csum = (tid < S1D) ? expf(c0 - cmax) : 0.f;
  #pragma unroll
  for (int off = 32; off > 0; off >>= 1) csum += __shfl_down(csum, off, 64);
  if (lane == 0) sm[wid] = csum;
  __syncthreads();
  float cinv = 1.0f / (sm[0] + sm[1] + sm[2] + sm[3]);
  if (tid < S1D) {
    float val = (1.f - pgb) * expf(c0 - cmax) * cinv;
    int tok = src1[(size_t)tid * BB + b];
    atomicAdd(&row[tok], val);
  }
}

extern "C" void kernel_launch(void* const* d_in, const int* in_sizes, int n_in,
                              void* d_out, int out_size, void* d_ws, size_t ws_size,
                              hipStream_t stream) {
  (void)in_sizes; (void)n_in; (void)out_size; (void)ws_size;
  const int*   input  = (const int*)d_in[0];
  const float* hidden = (const float*)d_in[1];
  const int*   src1   = (const int*)d_in[2];
  const float* enc1   = (const float*)d_in[3];
  const int*   mask1  = (const int*)d_in[4];
  const int*   triple = (const int*)d_in[5];
  const float* enc2   = (const float*)d_in[6];
  const int*   mask2  = (const int*)d_in[7];
  const float* embedding = (const float*)d_in[8];
  const float* attn_W = (const float*)d_in[9];
  const float* attn_b = (const float*)d_in[10];
  const float* attn_v = (const float*)d_in[11];
  const float* copy_W = (const float*)d_in[12];
  const float* copy_b = (const float*)d_in[13];
  const float* copy_v = (const float*)d_in[14];
  const float* gru_Wih = (const float*)d_in[15];
  const float* gru_Whh = (const float*)d_in[16];
  const float* gru_bih = (const float*)d_in[17];
  const float* gru_bhh = (const float*)d_in[18];
  const float* fc_W   = (const float*)d_in[19];
  const float* fc_b   = (const float*)d_in[20];
  const float* gate_W = (const float*)d_in[21];
  const float* gate_b = (const float*)d_in[22];

  char* w = (char*)d_ws;
  u16* Wt_a = (u16*)w;                w += (size_t)512 * 1024 * 2;
  u16* Wt_c = (u16*)w;                w += (size_t)512 * 1024 * 2;
  float* partJ = (float*)w;           w += (size_t)2 * 51200 * 4;
  float* preC = (float*)w;            w += (size_t)25600 * 512 * 4;
  float* hWa  = (float*)w;            w += (size_t)BB * DECD * 4;
  float* scC  = (float*)w;            w += (size_t)BB * S1D * 4;
  float* wgt  = (float*)w;            w += (size_t)BB * E2D * 4;
  float* wpart = (float*)w;           w += (size_t)4 * BB * E2D * 4;
  u16*   x_bf = (u16*)w;              w += (size_t)BB * 1280 * 2;
  u16*   hid_bf = (u16*)w;            w += (size_t)BB * DECD * 2;
  float* gx   = (float*)w;            w += (size_t)BB * 1536 * 4;
  float* gh   = (float*)w;            w += (size_t)BB * 1536 * 4;
  u16*   st_bf = (u16*)w;             w += (size_t)BB * 1536 * 2;
  float* pg   = (float*)w;            w += 512;

  float* out  = (float*)d_out;
  float* hnew = out + (size_t)BB * VV;

  // fused prep
  k_prep<<<1440, 256, 0, stream>>>(attn_W, copy_W, Wt_a, Wt_c,
                                   hidden, hid_bf, attn_b, hWa,
                                   input, embedding, x_bf);

  // combined joint-attn + copy-preactivation energy GEMM
  gemm_energy_jc<<<dim3(2, JY + 400), 256, 0, stream>>>(
      enc1, enc2, Wt_a, Wt_c, hWa, attn_v, partJ, preC);

  // weighted context with inline joint softmax
  k_wpart_sm<<<dim3(BB, 2, 4), 256, 0, stream>>>(partJ, enc1, enc2, mask1, mask2, wpart);
  k_wsum_x<<<512, 256, 0, stream>>>(wpart, wgt, x_bf);

  // GRU
  gemm_gru<<<24, 512, 0, stream>>>(x_bf, gru_Wih, gru_bih, gx,
                                   hid_bf, gru_Whh, gru_bhh, gh);
  k_gru_concat<<<BB, 256, 0, stream>>>(gx, gh, hidden, wgt, hnew, st_bf);

  // vocab logits + p_gen + copy-epilogue (co-resident blocks)
  gemm_fc3c<<<782 + 128 + 128, 512, 0, stream>>>(
      st_bf, fc_W, fc_b, out, VV, 1536,
      wgt, input, embedding, gate_W, gate_b, pg,
      hnew, copy_W, copy_b, copy_v, preC, scC);

  // final distribution (vocab softmax + copy softmax + scatter)
  k_vocab_sc2<<<BB, 256, 0, stream>>>(out, pg, scC, mask1, triple, src1);
}

// Round 18
// 525.372 us; speedup vs baseline: 1.5240x; 1.0764x over previous
//
#include <hip/hip_runtime.h>
#include <math.h>

#define BB   128
#define DECD 512
#define E2D  1024
#define EMBD 256
#define S1D  200
#define S2D  200
#define SJD  400
#define VV   50000
#define NEGV (-1e10f)
#define JY   800   // joint tiles (51200 rows / 64); copy tiles follow

typedef unsigned short u16;
typedef __bf16 bf16x8 __attribute__((ext_vector_type(8)));
typedef float f32x4 __attribute__((ext_vector_type(4)));
typedef u16 u16x8 __attribute__((ext_vector_type(8)));

__device__ __forceinline__ u16 f2bf(float x) {
  unsigned u = __float_as_uint(x);
  unsigned r = (u + 0x7fffu + ((u >> 16) & 1u)) >> 16;
  return (u16)r;
}
__device__ __forceinline__ float bf2f(u16 h) {
  return __uint_as_float(((unsigned)h) << 16);
}
// hardware RTNE pack (r7/r16/r17-verified: identical absmax to manual f2bf)
__device__ __forceinline__ u16x8 cvt8h(float4 a, float4 b) {
  bf16x8 r;
  r[0] = (__bf16)a.x; r[1] = (__bf16)a.y; r[2] = (__bf16)a.z; r[3] = (__bf16)a.w;
  r[4] = (__bf16)b.x; r[5] = (__bf16)b.y; r[6] = (__bf16)b.z; r[7] = (__bf16)b.w;
  return *reinterpret_cast<u16x8*>(&r);
}

typedef const __attribute__((address_space(1))) void* gas_t;
typedef __attribute__((address_space(3))) void* las_t;
__device__ __forceinline__ void async_copy16(const u16* g, u16* l) {
  __builtin_amdgcn_global_load_lds((gas_t)g, (las_t)l, 16, 0, 0);
}

// ---------------- fused prep (r16/r17-verified): wt2 | cvt hid | hWa | embx ----------------
__global__ __launch_bounds__(256) void k_prep(
    const float* __restrict__ Wa, const float* __restrict__ Wc,
    u16* __restrict__ Wta, u16* __restrict__ Wtc,
    const float* __restrict__ hidden, u16* __restrict__ hid_bf,
    const float* __restrict__ attn_b, float* __restrict__ hWa,
    const int* __restrict__ inp, const float* __restrict__ table,
    u16* __restrict__ x_bf) {
  int blk = blockIdx.x, tid = threadIdx.x;
  if (blk < 1024) {
    __shared__ float t[32][33];
    int z = blk >> 9, rem = blk & 511;
    int bk = rem & 31, bn = rem >> 5;
    const float* W = z ? Wc : Wa;
    u16* Wt = z ? Wtc : Wta;
    int tx = tid & 31, ty = tid >> 5;
    #pragma unroll
    for (int r = 0; r < 4; ++r) {
      int k = bk * 32 + ty + r * 8;
      t[ty + r * 8][tx] = W[(size_t)(512 + k) * 512 + bn * 32 + tx];
    }
    __syncthreads();
    #pragma unroll
    for (int r = 0; r < 4; ++r) {
      int n = bn * 32 + ty + r * 8;
      Wt[(size_t)n * 1024 + bk * 32 + tx] = f2bf(t[tx][ty + r * 8]);
    }
  } else if (blk < 1056) {
    int i = (blk - 1024) * 256 + tid;
    const float4 f0 = *(const float4*)(hidden + (size_t)i * 8);
    const float4 f1 = *(const float4*)(hidden + (size_t)i * 8 + 4);
    *(u16x8*)(hid_bf + (size_t)i * 8) = cvt8h(f0, f1);
  } else if (blk < 1312) {
    int idx = blk - 1056;
    int b = idx >> 1;
    int d = (idx & 1) * 256 + tid;
    const float* hr = hidden + (size_t)b * DECD;
    float acc = attn_b[d];
    #pragma unroll 8
    for (int k = 0; k < DECD; ++k) acc += hr[k] * Wa[(size_t)k * DECD + d];
    hWa[(size_t)b * DECD + d] = acc;
  } else {
    int b = blk - 1312;
    x_bf[(size_t)b * 1280 + tid] = f2bf(table[(size_t)inp[b] * EMBD + tid]);
  }
}

// ---------------- combined joint+copy energy GEMM (r14-r17-verified) ----------------
__global__ __launch_bounds__(256) void gemm_energy_jc(
    const float* __restrict__ enc1, const float* __restrict__ enc2,
    const u16* __restrict__ BtA, const u16* __restrict__ BtC,
    const float* __restrict__ hW, const float* __restrict__ v,
    float* __restrict__ partJ, float* __restrict__ preC) {
  __shared__ u16 As[2][64 * 32];   // 2 x 4 KB
  __shared__ u16 Bs[256 * 32];     // 16 KB
  __shared__ float sbuf[64][2];
  int tid = threadIdx.x;
  int wid = tid >> 6, lane = tid & 63;
  int wr = wid >> 1, wc = wid & 1;
  int bn = blockIdx.x;
  int jy = blockIdx.y;
  int joint = (jy < JY);
  size_t m0 = joint ? (size_t)jy * 64 : (size_t)(jy - JY) * 64;
  int bhalf = (jy & 1) * 64;
  int n0 = bn * 256;

  int rA = tid >> 2, cslot = tid & 3;
  int lAoff = rA * 32 + ((cslot ^ ((rA >> 1) & 3)) * 8);
  const float* base;
  if (joint)
    base = (m0 < (size_t)S1D * BB) ? (enc1 + m0 * E2D)
                                   : (enc2 + (m0 - (size_t)S1D * BB) * E2D);
  else
    base = enc1 + m0 * E2D;
  const float* gA_f = base + (size_t)rA * E2D + cslot * 8;

  const u16* Bt = joint ? BtA : BtC;
  const u16* gB[4];
  #pragma unroll
  for (int i = 0; i < 4; ++i) {
    int rn = i * 64 + wid * 16 + (lane >> 2);
    int c = (lane & 3) ^ ((rn >> 1) & 3);
    gB[i] = Bt + (size_t)(n0 + rn) * E2D + c * 8;
  }

  int q = lane >> 4, cl = lane & 15;
  int aoff[2], boff[8];
  #pragma unroll
  for (int mi = 0; mi < 2; ++mi) {
    int row = wr * 32 + mi * 16 + cl;
    aoff[mi] = row * 64 + ((q ^ ((row >> 1) & 3)) * 16);
  }
  #pragma unroll
  for (int nj = 0; nj < 8; ++nj) {
    int rn = wc * 128 + nj * 16 + cl;
    boff[nj] = rn * 64 + ((q ^ ((rn >> 1) & 3)) * 16);
  }

  f32x4 acc[2][8];
  #pragma unroll
  for (int mi = 0; mi < 2; ++mi)
    #pragma unroll
    for (int nj = 0; nj < 8; ++nj) {
      f32x4 z = {0.f, 0.f, 0.f, 0.f};
      acc[mi][nj] = z;
    }

  float4 a0 = *(const float4*)(gA_f);
  float4 a1 = *(const float4*)(gA_f + 4);
  *(u16x8*)(&As[0][lAoff]) = cvt8h(a0, a1);
  a0 = *(const float4*)(gA_f + 32);
  a1 = *(const float4*)(gA_f + 36);

  for (int t = 0; t < 32; ++t) {
    int cur = t & 1, nxt = cur ^ 1;
    int k0 = t * 32, k1 = k0 + 32;
    #pragma unroll
    for (int i = 0; i < 4; ++i) async_copy16(gB[i] + k0, &Bs[2048 * i + wid * 512]);
    if (t < 31) {
      *(u16x8*)(&As[nxt][lAoff]) = cvt8h(a0, a1);
      if (t < 30) {
        a0 = *(const float4*)(gA_f + k1 + 32);
        a1 = *(const float4*)(gA_f + k1 + 36);
      }
    }
    __syncthreads();
    bf16x8 af[2];
    #pragma unroll
    for (int mi = 0; mi < 2; ++mi)
      af[mi] = *(const bf16x8*)((const char*)As[cur] + aoff[mi]);
    #pragma unroll
    for (int nj = 0; nj < 8; ++nj) {
      bf16x8 bg = *(const bf16x8*)((const char*)Bs + boff[nj]);
      acc[0][nj] = __builtin_amdgcn_mfma_f32_16x16x32_bf16(af[0], bg, acc[0][nj], 0, 0, 0);
      acc[1][nj] = __builtin_amdgcn_mfma_f32_16x16x32_bf16(af[1], bg, acc[1][nj], 0, 0, 0);
    }
    __syncthreads();
  }

  if (joint) {
    #pragma unroll
    for (int mi = 0; mi < 2; ++mi) {
      #pragma unroll
      for (int j = 0; j < 4; ++j) {
        int m = wr * 32 + mi * 16 + q * 4 + j;
        float s = 0.f;
        #pragma unroll
        for (int nj = 0; nj < 8; ++nj) {
          int d = n0 + wc * 128 + nj * 16 + cl;
          s += tanhf(acc[mi][nj][j] + hW[(size_t)(bhalf + m) * DECD + d]) * v[d];
        }
        s += __shfl_xor(s, 1, 64);
        s += __shfl_xor(s, 2, 64);
        s += __shfl_xor(s, 4, 64);
        s += __shfl_xor(s, 8, 64);
        if (cl == 0) sbuf[m][wc] = s;
      }
    }
    __syncthreads();
    if (tid < 64)
      partJ[(size_t)bn * 51200 + m0 + tid] = sbuf[tid][0] + sbuf[tid][1];
  } else {
    #pragma unroll
    for (int mi = 0; mi < 2; ++mi) {
      #pragma unroll
      for (int nj = 0; nj < 8; ++nj) {
        int d = n0 + wc * 128 + nj * 16 + cl;
        #pragma unroll
        for (int j = 0; j < 4; ++j) {
          int m = wr * 32 + mi * 16 + q * 4 + j;
          preC[(m0 + m) * (size_t)DECD + d] = acc[mi][nj][j];
        }
      }
    }
  }
}

// weighted partials with inline joint softmax (r16/r17-verified; unroll 8)
__global__ __launch_bounds__(256) void k_wpart_sm(const float* __restrict__ part,
    const float* __restrict__ enc1, const float* __restrict__ enc2,
    const int* __restrict__ m1, const int* __restrict__ m2,
    float* __restrict__ wp) {
  int b = blockIdx.x, tid = threadIdx.x;
  int e2 = blockIdx.y * 256 + tid;
  int scn = blockIdx.z;
  __shared__ float sm[4];
  __shared__ float ws[100];
  int s0 = tid, s2 = tid + 256;
  float a0, a1 = -INFINITY;
  {
    int msk = (s0 < S1D) ? m1[b * S1D + s0] : m2[b * S2D + (s0 - S1D)];
    int m = s0 * 128 + b;
    a0 = msk ? (part[m] + part[51200 + m]) : NEGV;
  }
  if (s2 < SJD) {
    int msk = (s2 < S1D) ? m1[b * S1D + s2] : m2[b * S2D + (s2 - S1D)];
    int m = s2 * 128 + b;
    a1 = msk ? (part[m] + part[51200 + m]) : NEGV;
  }
  float vmax = fmaxf(a0, a1);
  #pragma unroll
  for (int off = 32; off > 0; off >>= 1) vmax = fmaxf(vmax, __shfl_down(vmax, off, 64));
  int lane = tid & 63, wid = tid >> 6;
  if (lane == 0) sm[wid] = vmax;
  __syncthreads();
  vmax = fmaxf(fmaxf(sm[0], sm[1]), fmaxf(sm[2], sm[3]));
  __syncthreads();
  float lsum = expf(a0 - vmax);
  if (s2 < SJD) lsum += expf(a1 - vmax);
  #pragma unroll
  for (int off = 32; off > 0; off >>= 1) lsum += __shfl_down(lsum, off, 64);
  if (lane == 0) sm[wid] = lsum;
  __syncthreads();
  float inv = 1.0f / (sm[0] + sm[1] + sm[2] + sm[3]);
  if (tid < 100) {
    int s = scn * 100 + tid;
    int msk = (s < S1D) ? m1[b * S1D + s] : m2[b * S2D + (s - S1D)];
    int m = s * 128 + b;
    float av = msk ? (part[m] + part[51200 + m]) : NEGV;
    ws[tid] = expf(av - vmax) * inv;
  }
  __syncthreads();
  float acc0 = 0.f, acc1 = 0.f;
  #pragma unroll 8
  for (int i = 0; i < 100; ++i) {
    int s = scn * 100 + i;
    const float* ep = (s < S1D) ? (enc1 + ((size_t)s * BB + b) * E2D)
                                : (enc2 + ((size_t)(s - S1D) * BB + b) * E2D);
    float2 u = *(const float2*)(ep + e2 * 2);
    float w = ws[i];
    acc0 += w * u.x;
    acc1 += w * u.y;
  }
  float* dst = wp + ((size_t)scn * BB + b) * E2D + e2 * 2;
  dst[0] = acc0;
  dst[1] = acc1;
}

__global__ __launch_bounds__(256) void k_wsum_x(const float* __restrict__ wp,
    float* __restrict__ wgt, u16* __restrict__ x) {
  int i = blockIdx.x * 256 + threadIdx.x;
  const int NN = BB * E2D;
  float s = wp[i] + wp[NN + i] + wp[2 * NN + i] + wp[3 * NN + i];
  wgt[i] = s;
  int b = i >> 10, e = i & 1023;
  x[(size_t)b * 1280 + EMBD + e] = f2bf(s);
}

// ---------------- fc2 body as device function (r8/r15-r17-verified) ----------------
__device__ __forceinline__ void fc2_body(
    const u16* __restrict__ A, const float* __restrict__ Bf,
    const float* __restrict__ bias, float* __restrict__ C,
    int N, int K, int n0) {
  __shared__ u16 As[2][128 * 32];
  __shared__ u16 Bs[2][128 * 32];
  int tid = threadIdx.x;
  int wid = tid >> 6, lane = tid & 63;
  int wr = wid >> 2, wc = wid & 3;

  int rowa = wid * 16 + (lane >> 2);
  int ca = (lane & 3) ^ ((rowa >> 1) & 3);
  const u16* gA = A + (size_t)rowa * K + ca * 8;

  int rB = tid >> 2, cB = tid & 3;
  int gnB = n0 + rB; if (gnB >= N) gnB = N - 1;
  const float* gB = Bf + (size_t)gnB * K + cB * 8;
  int lBoff = rB * 32 + ((cB ^ ((rB >> 1) & 3)) * 8);

  int q = lane >> 4, cl = lane & 15;
  int aoff[4], boff[2];
  #pragma unroll
  for (int mi = 0; mi < 4; ++mi) {
    int row = wr * 64 + mi * 16 + cl;
    aoff[mi] = row * 64 + ((q ^ ((row >> 1) & 3)) * 16);
  }
  #pragma unroll
  for (int nj = 0; nj < 2; ++nj) {
    int rn = wc * 32 + nj * 16 + cl;
    boff[nj] = rn * 64 + ((q ^ ((rn >> 1) & 3)) * 16);
  }

  f32x4 acc[4][2];
  #pragma unroll
  for (int mi = 0; mi < 4; ++mi)
    #pragma unroll
    for (int nj = 0; nj < 2; ++nj) {
      f32x4 z = {0.f, 0.f, 0.f, 0.f};
      acc[mi][nj] = z;
    }

  for (int k0 = 0; k0 < K; k0 += 64) {
    float4 b00 = *(const float4*)(gB + k0);
    float4 b01 = *(const float4*)(gB + k0 + 4);
    float4 b10 = *(const float4*)(gB + k0 + 32);
    float4 b11 = *(const float4*)(gB + k0 + 36);
    *(u16x8*)(&Bs[0][lBoff]) = cvt8h(b00, b01);
    *(u16x8*)(&Bs[1][lBoff]) = cvt8h(b10, b11);
    async_copy16(gA + k0,      &As[0][wid * 512]);
    async_copy16(gA + k0 + 32, &As[1][wid * 512]);
    __syncthreads();
    #pragma unroll
    for (int h = 0; h < 2; ++h) {
      bf16x8 af[4], bg[2];
      #pragma unroll
      for (int mi = 0; mi < 4; ++mi) af[mi] = *(const bf16x8*)((const char*)As[h] + aoff[mi]);
      #pragma unroll
      for (int nj = 0; nj < 2; ++nj) bg[nj] = *(const bf16x8*)((const char*)Bs[h] + boff[nj]);
      #pragma unroll
      for (int mi = 0; mi < 4; ++mi)
        #pragma unroll
        for (int nj = 0; nj < 2; ++nj)
          acc[mi][nj] = __builtin_amdgcn_mfma_f32_16x16x32_bf16(af[mi], bg[nj], acc[mi][nj], 0, 0, 0);
    }
    __syncthreads();
  }

  #pragma unroll
  for (int mi = 0; mi < 4; ++mi) {
    #pragma unroll
    for (int nj = 0; nj < 2; ++nj) {
      int n = n0 + wc * 32 + nj * 16 + cl;
      if (n < N) {
        float bv = bias[n];
        #pragma unroll
        for (int j = 0; j < 4; ++j) {
          int m = wr * 64 + mi * 16 + q * 4 + j;
          C[(size_t)m * N + n] = acc[mi][nj][j] + bv;
        }
      }
    }
  }
}

// merged GRU GEMMs (r15-r17-verified)
__global__ __launch_bounds__(512) void gemm_gru(
    const u16* __restrict__ x_bf, const float* __restrict__ Wih,
    const float* __restrict__ bih, float* __restrict__ gx,
    const u16* __restrict__ h_bf, const float* __restrict__ Whh,
    const float* __restrict__ bhh, float* __restrict__ gh) {
  if (blockIdx.x < 12)
    fc2_body(x_bf, Wih, bih, gx, 1536, 1280, blockIdx.x * 128);
  else
    fc2_body(h_bf, Whh, bhh, gh, 1536, 512, (blockIdx.x - 12) * 128);
}

// ---------------- combined fc3 + pgen + copy-epilogue launch (small blocks FIRST) ----------------
// blocks 0..127   : p_gen per b
// blocks 128..255 : copy epilogue per b (hWc in-block + 200 energies -> raw scC)
// blocks 256..1037: fc3 (r15-r17-verified body, B 1-deep prefetch)
__global__ __launch_bounds__(512) void gemm_fc3c(
    const u16* __restrict__ A, const float* __restrict__ Bf,
    const float* __restrict__ bias, float* __restrict__ C, int N, int K,
    const float* __restrict__ wgt, const int* __restrict__ inp,
    const float* __restrict__ table, const float* __restrict__ gW,
    const float* __restrict__ gb, float* __restrict__ pg,
    const float* __restrict__ hnew, const float* __restrict__ copy_W,
    const float* __restrict__ copy_b, const float* __restrict__ copy_v,
    const float* __restrict__ preC, float* __restrict__ scC) {
  __shared__ u16 smem[12288];   // 24.6 KB pool, aliased per role
  int tid = threadIdx.x;
  if (blockIdx.x >= 256) {
    // ---- fc3 body ----
    u16* As0 = smem;            u16* As1 = smem + 4096;
    u16* Bs0 = smem + 8192;     u16* Bs1 = smem + 10240;
    u16* AsH[2] = {As0, As1};
    u16* BsH[2] = {Bs0, Bs1};
    int wid = tid >> 6, lane = tid & 63;
    int wr = wid >> 2, wc = wid & 3;
    int n0 = (blockIdx.x - 256) * 64;

    int rowa = wid * 16 + (lane >> 2);
    int ca = (lane & 3) ^ ((rowa >> 1) & 3);
    const u16* gA = A + (size_t)rowa * K + ca * 8;

    int rB = tid >> 3, cB = tid & 7;
    int gnB = n0 + rB; if (gnB >= N) gnB = N - 1;
    const float* gB = Bf + (size_t)gnB * K + cB * 8;
    int hB = cB >> 2, s4 = cB & 3;
    int lBoff = rB * 32 + ((s4 ^ ((rB >> 1) & 3)) * 8);

    int q = lane >> 4, cl = lane & 15;
    int aoff[4], boff;
    #pragma unroll
    for (int mi = 0; mi < 4; ++mi) {
      int row = wr * 64 + mi * 16 + cl;
      aoff[mi] = row * 64 + ((q ^ ((row >> 1) & 3)) * 16);
    }
    {
      int rn = wc * 16 + cl;
      boff = rn * 64 + ((q ^ ((rn >> 1) & 3)) * 16);
    }

    f32x4 acc[4];
    #pragma unroll
    for (int mi = 0; mi < 4; ++mi) {
      f32x4 z = {0.f, 0.f, 0.f, 0.f};
      acc[mi] = z;
    }

    float4 b0 = *(const float4*)(gB);
    float4 b1 = *(const float4*)(gB + 4);

    for (int k0 = 0; k0 < K; k0 += 64) {
      *(u16x8*)(&BsH[hB][lBoff]) = cvt8h(b0, b1);
      async_copy16(gA + k0,      &As0[wid * 512]);
      async_copy16(gA + k0 + 32, &As1[wid * 512]);
      __syncthreads();
      if (k0 + 64 < K) {
        b0 = *(const float4*)(gB + k0 + 64);
        b1 = *(const float4*)(gB + k0 + 68);
      }
      #pragma unroll
      for (int h = 0; h < 2; ++h) {
        bf16x8 af[4];
        #pragma unroll
        for (int mi = 0; mi < 4; ++mi) af[mi] = *(const bf16x8*)((const char*)AsH[h] + aoff[mi]);
        bf16x8 bg = *(const bf16x8*)((const char*)BsH[h] + boff);
        #pragma unroll
        for (int mi = 0; mi < 4; ++mi)
          acc[mi] = __builtin_amdgcn_mfma_f32_16x16x32_bf16(af[mi], bg, acc[mi], 0, 0, 0);
      }
      __syncthreads();
    }

    int n = n0 + wc * 16 + cl;
    if (n < N) {
      float bv = bias[n];
      #pragma unroll
      for (int mi = 0; mi < 4; ++mi)
        #pragma unroll
        for (int j = 0; j < 4; ++j) {
          int m = wr * 64 + mi * 16 + q * 4 + j;
          C[(size_t)m * N + n] = acc[mi][j] + bv;
        }
    }
  } else if (blockIdx.x < 128) {
    // ---- p_gen per b (r16/r17-verified math) ----
    int b = blockIdx.x;
    float* sm = (float*)smem;
    float s = 0.f;
    for (int k = tid; k < E2D + EMBD; k += 512)
      s += gW[k] * ((k < E2D) ? wgt[(size_t)b * E2D + k]
                              : table[(size_t)inp[b] * EMBD + k - E2D]);
    #pragma unroll
    for (int off = 32; off > 0; off >>= 1) s += __shfl_down(s, off, 64);
    int lane = tid & 63, wid = tid >> 6;
    if (lane == 0) sm[wid] = s;
    __syncthreads();
    if (tid == 0) {
      float t = sm[0] + sm[1] + sm[2] + sm[3] + sm[4] + sm[5] + sm[6] + sm[7] + gb[0];
      pg[b] = 1.f / (1.f + expf(-t));
    }
  } else {
    // ---- copy epilogue per b (r17-verified) ----
    int b = blockIdx.x - 128;
    float* hn  = (float*)smem;          // 512 floats
    float* hwc = (float*)smem + 512;    // 512 floats
    hn[tid] = hnew[(size_t)b * DECD + tid];
    __syncthreads();
    {
      float acc = copy_b[tid];
      #pragma unroll 8
      for (int k = 0; k < DECD; ++k) acc += hn[k] * copy_W[(size_t)k * DECD + tid];
      hwc[tid] = acc;
    }
    __syncthreads();
    int wid = tid >> 6, lane = tid & 63;
    float4 h0 = *(const float4*)(hwc + lane * 8);
    float4 h1 = *(const float4*)(hwc + lane * 8 + 4);
    float4 v0 = *(const float4*)(copy_v + lane * 8);
    float4 v1 = *(const float4*)(copy_v + lane * 8 + 4);
    for (int s = wid; s < S1D; s += 8) {
      const float* pr = preC + ((size_t)s * 128 + b) * DECD + lane * 8;
      float4 p0 = *(const float4*)(pr);
      float4 p1 = *(const float4*)(pr + 4);
      float e = tanhf(p0.x + h0.x) * v0.x + tanhf(p0.y + h0.y) * v0.y
              + tanhf(p0.z + h0.z) * v0.z + tanhf(p0.w + h0.w) * v0.w
              + tanhf(p1.x + h1.x) * v1.x + tanhf(p1.y + h1.y) * v1.y
              + tanhf(p1.z + h1.z) * v1.z + tanhf(p1.w + h1.w) * v1.w;
      #pragma unroll
      for (int off = 32; off > 0; off >>= 1) e += __shfl_xor(e, off, 64);
      if (lane == 0) scC[(size_t)b * S1D + s] = e;
    }
  }
}

// GRU pointwise + fused concat (r15-r17-verified)
__global__ __launch_bounds__(256) void k_gru_concat(const float* __restrict__ gx,
    const float* __restrict__ gh, const float* __restrict__ hidden,
    const float* __restrict__ wgt, float* __restrict__ hnew,
    u16* __restrict__ st) {
  int b = blockIdx.x, tid = threadIdx.x;
  #pragma unroll
  for (int qq = 0; qq < 2; ++qq) {
    int d = tid + qq * 256;
    size_t o = (size_t)b * 1536;
    float xr = gx[o + d],        hr = gh[o + d];
    float xz = gx[o + 512 + d],  hz = gh[o + 512 + d];
    float xn = gx[o + 1024 + d], hn = gh[o + 1024 + d];
    float r = 1.f / (1.f + expf(-(xr + hr)));
    float z = 1.f / (1.f + expf(-(xz + hz)));
    float n = tanhf(xn + r * hn);
    float hv = (1.f - z) * n + z * hidden[(size_t)b * DECD + d];
    hnew[(size_t)b * DECD + d] = hv;
    st[(size_t)b * 1536 + d] = f2bf(hv);
  }
  #pragma unroll
  for (int qq = 0; qq < 4; ++qq) {
    int e = tid + qq * 256;
    st[(size_t)b * 1536 + DECD + e] = f2bf(wgt[(size_t)b * E2D + e]);
  }
}

// vocab softmax (single-pass online max+sum) + p_gen scale + copy-softmax + scatter
__global__ __launch_bounds__(256) void k_vocab_sc2(float* __restrict__ dist,
    const float* __restrict__ pg, const float* __restrict__ scC,
    const int* __restrict__ m1, const int* __restrict__ tr,
    const int* __restrict__ src1) {
  int b = blockIdx.x, tid = threadIdx.x;
  float* row = dist + (size_t)b * VV;
  __shared__ float smM[4], smS[4];
  int lane = tid & 63, wid = tid >> 6;
  // online (m, s) pass
  float m = -INFINITY, s = 0.f;
  for (int i = tid; i < VV; i += 256) {
    float x = row[i];
    float mn = fmaxf(m, x);
    s = s * expf(m - mn) + expf(x - mn);
    m = mn;
  }
  #pragma unroll
  for (int off = 32; off > 0; off >>= 1) {
    float mo = __shfl_down(m, off, 64);
    float so = __shfl_down(s, off, 64);
    float mn = fmaxf(m, mo);
    s = s * expf(m - mn) + so * expf(mo - mn);
    m = mn;
  }
  if (lane == 0) { smM[wid] = m; smS[wid] = s; }
  __syncthreads();
  if (tid == 0) {
    float mt = smM[0], st = smS[0];
    #pragma unroll
    for (int i = 1; i < 4; ++i) {
      float mn = fmaxf(mt, smM[i]);
      st = st * expf(mt - mn) + smS[i] * expf(smM[i] - mn);
      mt = mn;
    }
    smM[0] = mt; smS[0] = st;
  }
  __syncthreads();
  m = smM[0];
  s = smS[0];
  float pgb = pg[b];
  float scale = pgb / s;
  for (int i = tid; i < VV; i += 256) row[i] = expf(row[i] - m) * scale;
  __syncthreads();
  // copy masked softmax over raw scC (r16/r17-verified math)
  float c0 = -INFINITY;
  if (tid < S1D) {
    int msk = m1[b * S1D + tid] * tr[b * S1D + tid];
    c0 = msk ? scC[(size_t)b * S1D + tid] : NEGV;
  }
  float cmax = c0;
  #pragma unroll
  for (int off = 32; off > 0; off >>= 1) cmax = fmaxf(cmax, __shfl_down(cmax, off, 64));
  if (lane == 0) smM[wid] = cmax;
  __syncthreads();
  cmax = fmaxf(fmaxf(smM[0], smM[1]), fmaxf(smM[2], smM[3]));
  __syncthreads();
  float csum = (tid < S1D) ? expf(c0 - cmax) : 0.f;
  #pragma unroll
  for (int off = 32; off > 0; off >>= 1) csum += __shfl_down(csum, off, 64);
  if (lane == 0) smS[wid] = csum;
  __syncthreads();
  float cinv = 1.0f / (smS[0] + smS[1] + smS[2] + smS[3]);
  if (tid < S1D) {
    float val = (1.f - pgb) * expf(c0 - cmax) * cinv;
    int tok = src1[(size_t)tid * BB + b];
    atomicAdd(&row[tok], val);
  }
}

extern "C" void kernel_launch(void* const* d_in, const int* in_sizes, int n_in,
                              void* d_out, int out_size, void* d_ws, size_t ws_size,
                              hipStream_t stream) {
  (void)in_sizes; (void)n_in; (void)out_size; (void)ws_size;
  const int*   input  = (const int*)d_in[0];
  const float* hidden = (const float*)d_in[1];
  const int*   src1   = (const int*)d_in[2];
  const float* enc1   = (const float*)d_in[3];
  const int*   mask1  = (const int*)d_in[4];
  const int*   triple = (const int*)d_in[5];
  const float* enc2   = (const float*)d_in[6];
  const int*   mask2  = (const int*)d_in[7];
  const float* embedding = (const float*)d_in[8];
  const float* attn_W = (const float*)d_in[9];
  const float* attn_b = (const float*)d_in[10];
  const float* attn_v = (const float*)d_in[11];
  const float* copy_W = (const float*)d_in[12];
  const float* copy_b = (const float*)d_in[13];
  const float* copy_v = (const float*)d_in[14];
  const float* gru_Wih = (const float*)d_in[15];
  const float* gru_Whh = (const float*)d_in[16];
  const float* gru_bih = (const float*)d_in[17];
  const float* gru_bhh = (const float*)d_in[18];
  const float* fc_W   = (const float*)d_in[19];
  const float* fc_b   = (const float*)d_in[20];
  const float* gate_W = (const float*)d_in[21];
  const float* gate_b = (const float*)d_in[22];

  char* w = (char*)d_ws;
  u16* Wt_a = (u16*)w;                w += (size_t)512 * 1024 * 2;
  u16* Wt_c = (u16*)w;                w += (size_t)512 * 1024 * 2;
  float* partJ = (float*)w;           w += (size_t)2 * 51200 * 4;
  float* preC = (float*)w;            w += (size_t)25600 * 512 * 4;
  float* hWa  = (float*)w;            w += (size_t)BB * DECD * 4;
  float* scC  = (float*)w;            w += (size_t)BB * S1D * 4;
  float* wgt  = (float*)w;            w += (size_t)BB * E2D * 4;
  float* wpart = (float*)w;           w += (size_t)4 * BB * E2D * 4;
  u16*   x_bf = (u16*)w;              w += (size_t)BB * 1280 * 2;
  u16*   hid_bf = (u16*)w;            w += (size_t)BB * DECD * 2;
  float* gx   = (float*)w;            w += (size_t)BB * 1536 * 4;
  float* gh   = (float*)w;            w += (size_t)BB * 1536 * 4;
  u16*   st_bf = (u16*)w;             w += (size_t)BB * 1536 * 2;
  float* pg   = (float*)w;            w += 512;

  float* out  = (float*)d_out;
  float* hnew = out + (size_t)BB * VV;

  // fused prep
  k_prep<<<1440, 256, 0, stream>>>(attn_W, copy_W, Wt_a, Wt_c,
                                   hidden, hid_bf, attn_b, hWa,
                                   input, embedding, x_bf);

  // combined joint-attn + copy-preactivation energy GEMM
  gemm_energy_jc<<<dim3(2, JY + 400), 256, 0, stream>>>(
      enc1, enc2, Wt_a, Wt_c, hWa, attn_v, partJ, preC);

  // weighted context with inline joint softmax
  k_wpart_sm<<<dim3(BB, 2, 4), 256, 0, stream>>>(partJ, enc1, enc2, mask1, mask2, wpart);
  k_wsum_x<<<512, 256, 0, stream>>>(wpart, wgt, x_bf);

  // GRU
  gemm_gru<<<24, 512, 0, stream>>>(x_bf, gru_Wih, gru_bih, gx,
                                   hid_bf, gru_Whh, gru_bhh, gh);
  k_gru_concat<<<BB, 256, 0, stream>>>(gx, gh, hidden, wgt, hnew, st_bf);

  // vocab logits + p_gen + copy-epilogue (co-resident; small blocks dispatch first)
  gemm_fc3c<<<256 + 782, 512, 0, stream>>>(
      st_bf, fc_W, fc_b, out, VV, 1536,
      wgt, input, embedding, gate_W, gate_b, pg,
      hnew, copy_W, copy_b, copy_v, preC, scC);

  // final distribution (vocab softmax + copy softmax + scatter)
  k_vocab_sc2<<<BB, 256, 0, stream>>>(out, pg, scC, mask1, triple, src1);
}

// Round 19
// 506.732 us; speedup vs baseline: 1.5800x; 1.0368x over previous
//
#include <hip/hip_runtime.h>
#include <math.h>

#define BB   128
#define DECD 512
#define E2D  1024
#define EMBD 256
#define S1D  200
#define S2D  200
#define SJD  400
#define VV   50000
#define NEGV (-1e10f)
#define JY   800   // joint tiles (51200 rows / 64); copy tiles follow

typedef unsigned short u16;
typedef __bf16 bf16x8 __attribute__((ext_vector_type(8)));
typedef float f32x4 __attribute__((ext_vector_type(4)));
typedef u16 u16x8 __attribute__((ext_vector_type(8)));

__device__ __forceinline__ u16 f2bf(float x) {
  unsigned u = __float_as_uint(x);
  unsigned r = (u + 0x7fffu + ((u >> 16) & 1u)) >> 16;
  return (u16)r;
}
__device__ __forceinline__ float bf2f(u16 h) {
  return __uint_as_float(((unsigned)h) << 16);
}
// hardware RTNE pack (r7/r16-r18-verified)
__device__ __forceinline__ u16x8 cvt8h(float4 a, float4 b) {
  bf16x8 r;
  r[0] = (__bf16)a.x; r[1] = (__bf16)a.y; r[2] = (__bf16)a.z; r[3] = (__bf16)a.w;
  r[4] = (__bf16)b.x; r[5] = (__bf16)b.y; r[6] = (__bf16)b.z; r[7] = (__bf16)b.w;
  return *reinterpret_cast<u16x8*>(&r);
}

typedef const __attribute__((address_space(1))) void* gas_t;
typedef __attribute__((address_space(3))) void* las_t;
__device__ __forceinline__ void async_copy16(const u16* g, u16* l) {
  __builtin_amdgcn_global_load_lds((gas_t)g, (las_t)l, 16, 0, 0);
}

// ---------------- fused prep (r16-r18-verified): wt2 | cvt hid | hWa | embx ----------------
__global__ __launch_bounds__(256) void k_prep(
    const float* __restrict__ Wa, const float* __restrict__ Wc,
    u16* __restrict__ Wta, u16* __restrict__ Wtc,
    const float* __restrict__ hidden, u16* __restrict__ hid_bf,
    const float* __restrict__ attn_b, float* __restrict__ hWa,
    const int* __restrict__ inp, const float* __restrict__ table,
    u16* __restrict__ x_bf) {
  int blk = blockIdx.x, tid = threadIdx.x;
  if (blk < 1024) {
    __shared__ float t[32][33];
    int z = blk >> 9, rem = blk & 511;
    int bk = rem & 31, bn = rem >> 5;
    const float* W = z ? Wc : Wa;
    u16* Wt = z ? Wtc : Wta;
    int tx = tid & 31, ty = tid >> 5;
    #pragma unroll
    for (int r = 0; r < 4; ++r) {
      int k = bk * 32 + ty + r * 8;
      t[ty + r * 8][tx] = W[(size_t)(512 + k) * 512 + bn * 32 + tx];
    }
    __syncthreads();
    #pragma unroll
    for (int r = 0; r < 4; ++r) {
      int n = bn * 32 + ty + r * 8;
      Wt[(size_t)n * 1024 + bk * 32 + tx] = f2bf(t[tx][ty + r * 8]);
    }
  } else if (blk < 1056) {
    int i = (blk - 1024) * 256 + tid;
    const float4 f0 = *(const float4*)(hidden + (size_t)i * 8);
    const float4 f1 = *(const float4*)(hidden + (size_t)i * 8 + 4);
    *(u16x8*)(hid_bf + (size_t)i * 8) = cvt8h(f0, f1);
  } else if (blk < 1312) {
    int idx = blk - 1056;
    int b = idx >> 1;
    int d = (idx & 1) * 256 + tid;
    const float* hr = hidden + (size_t)b * DECD;
    float acc = attn_b[d];
    #pragma unroll 8
    for (int k = 0; k < DECD; ++k) acc += hr[k] * Wa[(size_t)k * DECD + d];
    hWa[(size_t)b * DECD + d] = acc;
  } else {
    int b = blk - 1312;
    x_bf[(size_t)b * 1280 + tid] = f2bf(table[(size_t)inp[b] * EMBD + tid]);
  }
}

// ---------------- combined joint+copy energy GEMM (r14-r18-verified; preC now bf16) ----------------
__global__ __launch_bounds__(256) void gemm_energy_jc(
    const float* __restrict__ enc1, const float* __restrict__ enc2,
    const u16* __restrict__ BtA, const u16* __restrict__ BtC,
    const float* __restrict__ hW, const float* __restrict__ v,
    float* __restrict__ partJ, u16* __restrict__ preC) {
  __shared__ u16 As[2][64 * 32];   // 2 x 4 KB
  __shared__ u16 Bs[256 * 32];     // 16 KB
  __shared__ float sbuf[64][2];
  int tid = threadIdx.x;
  int wid = tid >> 6, lane = tid & 63;
  int wr = wid >> 1, wc = wid & 1;
  int bn = blockIdx.x;
  int jy = blockIdx.y;
  int joint = (jy < JY);
  size_t m0 = joint ? (size_t)jy * 64 : (size_t)(jy - JY) * 64;
  int bhalf = (jy & 1) * 64;
  int n0 = bn * 256;

  int rA = tid >> 2, cslot = tid & 3;
  int lAoff = rA * 32 + ((cslot ^ ((rA >> 1) & 3)) * 8);
  const float* base;
  if (joint)
    base = (m0 < (size_t)S1D * BB) ? (enc1 + m0 * E2D)
                                   : (enc2 + (m0 - (size_t)S1D * BB) * E2D);
  else
    base = enc1 + m0 * E2D;
  const float* gA_f = base + (size_t)rA * E2D + cslot * 8;

  const u16* Bt = joint ? BtA : BtC;
  const u16* gB[4];
  #pragma unroll
  for (int i = 0; i < 4; ++i) {
    int rn = i * 64 + wid * 16 + (lane >> 2);
    int c = (lane & 3) ^ ((rn >> 1) & 3);
    gB[i] = Bt + (size_t)(n0 + rn) * E2D + c * 8;
  }

  int q = lane >> 4, cl = lane & 15;
  int aoff[2], boff[8];
  #pragma unroll
  for (int mi = 0; mi < 2; ++mi) {
    int row = wr * 32 + mi * 16 + cl;
    aoff[mi] = row * 64 + ((q ^ ((row >> 1) & 3)) * 16);
  }
  #pragma unroll
  for (int nj = 0; nj < 8; ++nj) {
    int rn = wc * 128 + nj * 16 + cl;
    boff[nj] = rn * 64 + ((q ^ ((rn >> 1) & 3)) * 16);
  }

  f32x4 acc[2][8];
  #pragma unroll
  for (int mi = 0; mi < 2; ++mi)
    #pragma unroll
    for (int nj = 0; nj < 8; ++nj) {
      f32x4 z = {0.f, 0.f, 0.f, 0.f};
      acc[mi][nj] = z;
    }

  float4 a0 = *(const float4*)(gA_f);
  float4 a1 = *(const float4*)(gA_f + 4);
  *(u16x8*)(&As[0][lAoff]) = cvt8h(a0, a1);
  a0 = *(const float4*)(gA_f + 32);
  a1 = *(const float4*)(gA_f + 36);

  for (int t = 0; t < 32; ++t) {
    int cur = t & 1, nxt = cur ^ 1;
    int k0 = t * 32, k1 = k0 + 32;
    #pragma unroll
    for (int i = 0; i < 4; ++i) async_copy16(gB[i] + k0, &Bs[2048 * i + wid * 512]);
    if (t < 31) {
      *(u16x8*)(&As[nxt][lAoff]) = cvt8h(a0, a1);
      if (t < 30) {
        a0 = *(const float4*)(gA_f + k1 + 32);
        a1 = *(const float4*)(gA_f + k1 + 36);
      }
    }
    __syncthreads();
    bf16x8 af[2];
    #pragma unroll
    for (int mi = 0; mi < 2; ++mi)
      af[mi] = *(const bf16x8*)((const char*)As[cur] + aoff[mi]);
    #pragma unroll
    for (int nj = 0; nj < 8; ++nj) {
      bf16x8 bg = *(const bf16x8*)((const char*)Bs + boff[nj]);
      acc[0][nj] = __builtin_amdgcn_mfma_f32_16x16x32_bf16(af[0], bg, acc[0][nj], 0, 0, 0);
      acc[1][nj] = __builtin_amdgcn_mfma_f32_16x16x32_bf16(af[1], bg, acc[1][nj], 0, 0, 0);
    }
    __syncthreads();
  }

  if (joint) {
    #pragma unroll
    for (int mi = 0; mi < 2; ++mi) {
      #pragma unroll
      for (int j = 0; j < 4; ++j) {
        int m = wr * 32 + mi * 16 + q * 4 + j;
        float s = 0.f;
        #pragma unroll
        for (int nj = 0; nj < 8; ++nj) {
          int d = n0 + wc * 128 + nj * 16 + cl;
          s += tanhf(acc[mi][nj][j] + hW[(size_t)(bhalf + m) * DECD + d]) * v[d];
        }
        s += __shfl_xor(s, 1, 64);
        s += __shfl_xor(s, 2, 64);
        s += __shfl_xor(s, 4, 64);
        s += __shfl_xor(s, 8, 64);
        if (cl == 0) sbuf[m][wc] = s;
      }
    }
    __syncthreads();
    if (tid < 64)
      partJ[(size_t)bn * 51200 + m0 + tid] = sbuf[tid][0] + sbuf[tid][1];
  } else {
    #pragma unroll
    for (int mi = 0; mi < 2; ++mi) {
      #pragma unroll
      for (int nj = 0; nj < 8; ++nj) {
        int d = n0 + wc * 128 + nj * 16 + cl;
        #pragma unroll
        for (int j = 0; j < 4; ++j) {
          int m = wr * 32 + mi * 16 + q * 4 + j;
          preC[(m0 + m) * (size_t)DECD + d] = f2bf(acc[mi][nj][j]);
        }
      }
    }
  }
}

// weighted partials with inline joint softmax (r16-r18-verified; unroll 8)
__global__ __launch_bounds__(256) void k_wpart_sm(const float* __restrict__ part,
    const float* __restrict__ enc1, const float* __restrict__ enc2,
    const int* __restrict__ m1, const int* __restrict__ m2,
    float* __restrict__ wp) {
  int b = blockIdx.x, tid = threadIdx.x;
  int e2 = blockIdx.y * 256 + tid;
  int scn = blockIdx.z;
  __shared__ float sm[4];
  __shared__ float ws[100];
  int s0 = tid, s2 = tid + 256;
  float a0, a1 = -INFINITY;
  {
    int msk = (s0 < S1D) ? m1[b * S1D + s0] : m2[b * S2D + (s0 - S1D)];
    int m = s0 * 128 + b;
    a0 = msk ? (part[m] + part[51200 + m]) : NEGV;
  }
  if (s2 < SJD) {
    int msk = (s2 < S1D) ? m1[b * S1D + s2] : m2[b * S2D + (s2 - S1D)];
    int m = s2 * 128 + b;
    a1 = msk ? (part[m] + part[51200 + m]) : NEGV;
  }
  float vmax = fmaxf(a0, a1);
  #pragma unroll
  for (int off = 32; off > 0; off >>= 1) vmax = fmaxf(vmax, __shfl_down(vmax, off, 64));
  int lane = tid & 63, wid = tid >> 6;
  if (lane == 0) sm[wid] = vmax;
  __syncthreads();
  vmax = fmaxf(fmaxf(sm[0], sm[1]), fmaxf(sm[2], sm[3]));
  __syncthreads();
  float lsum = expf(a0 - vmax);
  if (s2 < SJD) lsum += expf(a1 - vmax);
  #pragma unroll
  for (int off = 32; off > 0; off >>= 1) lsum += __shfl_down(lsum, off, 64);
  if (lane == 0) sm[wid] = lsum;
  __syncthreads();
  float inv = 1.0f / (sm[0] + sm[1] + sm[2] + sm[3]);
  if (tid < 100) {
    int s = scn * 100 + tid;
    int msk = (s < S1D) ? m1[b * S1D + s] : m2[b * S2D + (s - S1D)];
    int m = s * 128 + b;
    float av = msk ? (part[m] + part[51200 + m]) : NEGV;
    ws[tid] = expf(av - vmax) * inv;
  }
  __syncthreads();
  float acc0 = 0.f, acc1 = 0.f;
  #pragma unroll 8
  for (int i = 0; i < 100; ++i) {
    int s = scn * 100 + i;
    const float* ep = (s < S1D) ? (enc1 + ((size_t)s * BB + b) * E2D)
                                : (enc2 + ((size_t)(s - S1D) * BB + b) * E2D);
    float2 u = *(const float2*)(ep + e2 * 2);
    float w = ws[i];
    acc0 += w * u.x;
    acc1 += w * u.y;
  }
  float* dst = wp + ((size_t)scn * BB + b) * E2D + e2 * 2;
  dst[0] = acc0;
  dst[1] = acc1;
}

__global__ __launch_bounds__(256) void k_wsum_x(const float* __restrict__ wp,
    float* __restrict__ wgt, u16* __restrict__ x) {
  int i = blockIdx.x * 256 + threadIdx.x;
  const int NN = BB * E2D;
  float s = wp[i] + wp[NN + i] + wp[2 * NN + i] + wp[3 * NN + i];
  wgt[i] = s;
  int b = i >> 10, e = i & 1023;
  x[(size_t)b * 1280 + EMBD + e] = f2bf(s);
}

// ---------------- fc3-style body (BN=64, 512 thr) as device function ----------------
__device__ __forceinline__ void fc3_body(
    const u16* __restrict__ A, const float* __restrict__ Bf,
    const float* __restrict__ bias, float* __restrict__ C,
    int N, int K, int n0, u16* smem) {
  u16* As0 = smem;            u16* As1 = smem + 4096;
  u16* Bs0 = smem + 8192;     u16* Bs1 = smem + 10240;
  u16* AsH[2] = {As0, As1};
  u16* BsH[2] = {Bs0, Bs1};
  int tid = threadIdx.x;
  int wid = tid >> 6, lane = tid & 63;
  int wr = wid >> 2, wc = wid & 3;

  int rowa = wid * 16 + (lane >> 2);
  int ca = (lane & 3) ^ ((rowa >> 1) & 3);
  const u16* gA = A + (size_t)rowa * K + ca * 8;

  int rB = tid >> 3, cB = tid & 7;
  int gnB = n0 + rB; if (gnB >= N) gnB = N - 1;
  const float* gB = Bf + (size_t)gnB * K + cB * 8;
  int hB = cB >> 2, s4 = cB & 3;
  int lBoff = rB * 32 + ((s4 ^ ((rB >> 1) & 3)) * 8);

  int q = lane >> 4, cl = lane & 15;
  int aoff[4], boff;
  #pragma unroll
  for (int mi = 0; mi < 4; ++mi) {
    int row = wr * 64 + mi * 16 + cl;
    aoff[mi] = row * 64 + ((q ^ ((row >> 1) & 3)) * 16);
  }
  {
    int rn = wc * 16 + cl;
    boff = rn * 64 + ((q ^ ((rn >> 1) & 3)) * 16);
  }

  f32x4 acc[4];
  #pragma unroll
  for (int mi = 0; mi < 4; ++mi) {
    f32x4 z = {0.f, 0.f, 0.f, 0.f};
    acc[mi] = z;
  }

  float4 b0 = *(const float4*)(gB);
  float4 b1 = *(const float4*)(gB + 4);

  for (int k0 = 0; k0 < K; k0 += 64) {
    *(u16x8*)(&BsH[hB][lBoff]) = cvt8h(b0, b1);
    async_copy16(gA + k0,      &As0[wid * 512]);
    async_copy16(gA + k0 + 32, &As1[wid * 512]);
    __syncthreads();
    if (k0 + 64 < K) {
      b0 = *(const float4*)(gB + k0 + 64);
      b1 = *(const float4*)(gB + k0 + 68);
    }
    #pragma unroll
    for (int h = 0; h < 2; ++h) {
      bf16x8 af[4];
      #pragma unroll
      for (int mi = 0; mi < 4; ++mi) af[mi] = *(const bf16x8*)((const char*)AsH[h] + aoff[mi]);
      bf16x8 bg = *(const bf16x8*)((const char*)BsH[h] + boff);
      #pragma unroll
      for (int mi = 0; mi < 4; ++mi)
        acc[mi] = __builtin_amdgcn_mfma_f32_16x16x32_bf16(af[mi], bg, acc[mi], 0, 0, 0);
    }
    __syncthreads();
  }

  int n = n0 + wc * 16 + cl;
  if (n < N) {
    float bv = bias[n];
    #pragma unroll
    for (int mi = 0; mi < 4; ++mi)
      #pragma unroll
      for (int j = 0; j < 4; ++j) {
        int m = wr * 64 + mi * 16 + q * 4 + j;
        C[(size_t)m * N + n] = acc[mi][j] + bv;
      }
  }
}

// merged GRU GEMMs, BN=64 x 48 blocks (fc3 body, runtime K)
__global__ __launch_bounds__(512) void gemm_gru2(
    const u16* __restrict__ x_bf, const float* __restrict__ Wih,
    const float* __restrict__ bih, float* __restrict__ gx,
    const u16* __restrict__ h_bf, const float* __restrict__ Whh,
    const float* __restrict__ bhh, float* __restrict__ gh) {
  __shared__ u16 smem[12288];
  if (blockIdx.x < 24)
    fc3_body(x_bf, Wih, bih, gx, 1536, 1280, blockIdx.x * 64, smem);
  else
    fc3_body(h_bf, Whh, bhh, gh, 1536, 512, (blockIdx.x - 24) * 64, smem);
}

// ---------------- combined fc3 + pgen + copy-epilogue (small blocks first; preC bf16) ----------------
__global__ __launch_bounds__(512) void gemm_fc3c(
    const u16* __restrict__ A, const float* __restrict__ Bf,
    const float* __restrict__ bias, float* __restrict__ C, int N, int K,
    const float* __restrict__ wgt, const int* __restrict__ inp,
    const float* __restrict__ table, const float* __restrict__ gW,
    const float* __restrict__ gb, float* __restrict__ pg,
    const float* __restrict__ hnew, const float* __restrict__ copy_W,
    const float* __restrict__ copy_b, const float* __restrict__ copy_v,
    const u16* __restrict__ preC, float* __restrict__ scC) {
  __shared__ u16 smem[12288];   // 24.6 KB pool, aliased per role
  int tid = threadIdx.x;
  if (blockIdx.x >= 256) {
    fc3_body(A, Bf, bias, C, N, K, (blockIdx.x - 256) * 64, smem);
  } else if (blockIdx.x < 128) {
    // ---- p_gen per b (r16-r18-verified math) ----
    int b = blockIdx.x;
    float* sm = (float*)smem;
    float s = 0.f;
    for (int k = tid; k < E2D + EMBD; k += 512)
      s += gW[k] * ((k < E2D) ? wgt[(size_t)b * E2D + k]
                              : table[(size_t)inp[b] * EMBD + k - E2D]);
    #pragma unroll
    for (int off = 32; off > 0; off >>= 1) s += __shfl_down(s, off, 64);
    int lane = tid & 63, wid = tid >> 6;
    if (lane == 0) sm[wid] = s;
    __syncthreads();
    if (tid == 0) {
      float t = sm[0] + sm[1] + sm[2] + sm[3] + sm[4] + sm[5] + sm[6] + sm[7] + gb[0];
      pg[b] = 1.f / (1.f + expf(-t));
    }
  } else {
    // ---- copy epilogue per b (r17/r18-verified; bf16 preC reads) ----
    int b = blockIdx.x - 128;
    float* hn  = (float*)smem;          // 512 floats
    float* hwc = (float*)smem + 512;    // 512 floats
    hn[tid] = hnew[(size_t)b * DECD + tid];
    __syncthreads();
    {
      float acc = copy_b[tid];
      #pragma unroll 8
      for (int k = 0; k < DECD; ++k) acc += hn[k] * copy_W[(size_t)k * DECD + tid];
      hwc[tid] = acc;
    }
    __syncthreads();
    int wid = tid >> 6, lane = tid & 63;
    float4 h0 = *(const float4*)(hwc + lane * 8);
    float4 h1 = *(const float4*)(hwc + lane * 8 + 4);
    float4 v0 = *(const float4*)(copy_v + lane * 8);
    float4 v1 = *(const float4*)(copy_v + lane * 8 + 4);
    for (int s = wid; s < S1D; s += 8) {
      const u16* pr = preC + ((size_t)s * 128 + b) * DECD + lane * 8;
      u16x8 pv = *(const u16x8*)(pr);
      float e = tanhf(bf2f(pv[0]) + h0.x) * v0.x + tanhf(bf2f(pv[1]) + h0.y) * v0.y
              + tanhf(bf2f(pv[2]) + h0.z) * v0.z + tanhf(bf2f(pv[3]) + h0.w) * v0.w
              + tanhf(bf2f(pv[4]) + h1.x) * v1.x + tanhf(bf2f(pv[5]) + h1.y) * v1.y
              + tanhf(bf2f(pv[6]) + h1.z) * v1.z + tanhf(bf2f(pv[7]) + h1.w) * v1.w;
      #pragma unroll
      for (int off = 32; off > 0; off >>= 1) e += __shfl_xor(e, off, 64);
      if (lane == 0) scC[(size_t)b * S1D + s] = e;
    }
  }
}

// GRU pointwise + fused concat (r15-r18-verified)
__global__ __launch_bounds__(256) void k_gru_concat(const float* __restrict__ gx,
    const float* __restrict__ gh, const float* __restrict__ hidden,
    const float* __restrict__ wgt, float* __restrict__ hnew,
    u16* __restrict__ st) {
  int b = blockIdx.x, tid = threadIdx.x;
  #pragma unroll
  for (int qq = 0; qq < 2; ++qq) {
    int d = tid + qq * 256;
    size_t o = (size_t)b * 1536;
    float xr = gx[o + d],        hr = gh[o + d];
    float xz = gx[o + 512 + d],  hz = gh[o + 512 + d];
    float xn = gx[o + 1024 + d], hn = gh[o + 1024 + d];
    float r = 1.f / (1.f + expf(-(xr + hr)));
    float z = 1.f / (1.f + expf(-(xz + hz)));
    float n = tanhf(xn + r * hn);
    float hv = (1.f - z) * n + z * hidden[(size_t)b * DECD + d];
    hnew[(size_t)b * DECD + d] = hv;
    st[(size_t)b * 1536 + d] = f2bf(hv);
  }
  #pragma unroll
  for (int qq = 0; qq < 4; ++qq) {
    int e = tid + qq * 256;
    st[(size_t)b * 1536 + DECD + e] = f2bf(wgt[(size_t)b * E2D + e]);
  }
}

// vocab softmax (single-pass online) + p_gen scale + copy-softmax + scatter (r18-verified)
__global__ __launch_bounds__(256) void k_vocab_sc2(float* __restrict__ dist,
    const float* __restrict__ pg, const float* __restrict__ scC,
    const int* __restrict__ m1, const int* __restrict__ tr,
    const int* __restrict__ src1) {
  int b = blockIdx.x, tid = threadIdx.x;
  float* row = dist + (size_t)b * VV;
  __shared__ float smM[4], smS[4];
  int lane = tid & 63, wid = tid >> 6;
  float m = -INFINITY, s = 0.f;
  for (int i = tid; i < VV; i += 256) {
    float x = row[i];
    float mn = fmaxf(m, x);
    s = s * expf(m - mn) + expf(x - mn);
    m = mn;
  }
  #pragma unroll
  for (int off = 32; off > 0; off >>= 1) {
    float mo = __shfl_down(m, off, 64);
    float so = __shfl_down(s, off, 64);
    float mn = fmaxf(m, mo);
    s = s * expf(m - mn) + so * expf(mo - mn);
    m = mn;
  }
  if (lane == 0) { smM[wid] = m; smS[wid] = s; }
  __syncthreads();
  if (tid == 0) {
    float mt = smM[0], st = smS[0];
    #pragma unroll
    for (int i = 1; i < 4; ++i) {
      float mn = fmaxf(mt, smM[i]);
      st = st * expf(mt - mn) + smS[i] * expf(smM[i] - mn);
      mt = mn;
    }
    smM[0] = mt; smS[0] = st;
  }
  __syncthreads();
  m = smM[0];
  s = smS[0];
  float pgb = pg[b];
  float scale = pgb / s;
  for (int i = tid; i < VV; i += 256) row[i] = expf(row[i] - m) * scale;
  __syncthreads();
  float c0 = -INFINITY;
  if (tid < S1D) {
    int msk = m1[b * S1D + tid] * tr[b * S1D + tid];
    c0 = msk ? scC[(size_t)b * S1D + tid] : NEGV;
  }
  float cmax = c0;
  #pragma unroll
  for (int off = 32; off > 0; off >>= 1) cmax = fmaxf(cmax, __shfl_down(cmax, off, 64));
  if (lane == 0) smM[wid] = cmax;
  __syncthreads();
  cmax = fmaxf(fmaxf(smM[0], smM[1]), fmaxf(smM[2], smM[3]));
  __syncthreads();
  float csum = (tid < S1D) ? expf(c0 - cmax) : 0.f;
  #pragma unroll
  for (int off = 32; off > 0; off >>= 1) csum += __shfl_down(csum, off, 64);
  if (lane == 0) smS[wid] = csum;
  __syncthreads();
  float cinv = 1.0f / (smS[0] + smS[1] + smS[2] + smS[3]);
  if (tid < S1D) {
    float val = (1.f - pgb) * expf(c0 - cmax) * cinv;
    int tok = src1[(size_t)tid * BB + b];
    atomicAdd(&row[tok], val);
  }
}

extern "C" void kernel_launch(void* const* d_in, const int* in_sizes, int n_in,
                              void* d_out, int out_size, void* d_ws, size_t ws_size,
                              hipStream_t stream) {
  (void)in_sizes; (void)n_in; (void)out_size; (void)ws_size;
  const int*   input  = (const int*)d_in[0];
  const float* hidden = (const float*)d_in[1];
  const int*   src1   = (const int*)d_in[2];
  const float* enc1   = (const float*)d_in[3];
  const int*   mask1  = (const int*)d_in[4];
  const int*   triple = (const int*)d_in[5];
  const float* enc2   = (const float*)d_in[6];
  const int*   mask2  = (const int*)d_in[7];
  const float* embedding = (const float*)d_in[8];
  const float* attn_W = (const float*)d_in[9];
  const float* attn_b = (const float*)d_in[10];
  const float* attn_v = (const float*)d_in[11];
  const float* copy_W = (const float*)d_in[12];
  const float* copy_b = (const float*)d_in[13];
  const float* copy_v = (const float*)d_in[14];
  const float* gru_Wih = (const float*)d_in[15];
  const float* gru_Whh = (const float*)d_in[16];
  const float* gru_bih = (const float*)d_in[17];
  const float* gru_bhh = (const float*)d_in[18];
  const float* fc_W   = (const float*)d_in[19];
  const float* fc_b   = (const float*)d_in[20];
  const float* gate_W = (const float*)d_in[21];
  const float* gate_b = (const float*)d_in[22];

  char* w = (char*)d_ws;
  u16* Wt_a = (u16*)w;                w += (size_t)512 * 1024 * 2;
  u16* Wt_c = (u16*)w;                w += (size_t)512 * 1024 * 2;
  float* partJ = (float*)w;           w += (size_t)2 * 51200 * 4;
  u16*   preC = (u16*)w;              w += (size_t)25600 * 512 * 2;
  float* hWa  = (float*)w;            w += (size_t)BB * DECD * 4;
  float* scC  = (float*)w;            w += (size_t)BB * S1D * 4;
  float* wgt  = (float*)w;            w += (size_t)BB * E2D * 4;
  float* wpart = (float*)w;           w += (size_t)4 * BB * E2D * 4;
  u16*   x_bf = (u16*)w;              w += (size_t)BB * 1280 * 2;
  u16*   hid_bf = (u16*)w;            w += (size_t)BB * DECD * 2;
  float* gx   = (float*)w;            w += (size_t)BB * 1536 * 4;
  float* gh   = (float*)w;            w += (size_t)BB * 1536 * 4;
  u16*   st_bf = (u16*)w;             w += (size_t)BB * 1536 * 2;
  float* pg   = (float*)w;            w += 512;

  float* out  = (float*)d_out;
  float* hnew = out + (size_t)BB * VV;

  // fused prep
  k_prep<<<1440, 256, 0, stream>>>(attn_W, copy_W, Wt_a, Wt_c,
                                   hidden, hid_bf, attn_b, hWa,
                                   input, embedding, x_bf);

  // combined joint-attn + copy-preactivation energy GEMM (preC bf16)
  gemm_energy_jc<<<dim3(2, JY + 400), 256, 0, stream>>>(
      enc1, enc2, Wt_a, Wt_c, hWa, attn_v, partJ, preC);

  // weighted context with inline joint softmax
  k_wpart_sm<<<dim3(BB, 2, 4), 256, 0, stream>>>(partJ, enc1, enc2, mask1, mask2, wpart);
  k_wsum_x<<<512, 256, 0, stream>>>(wpart, wgt, x_bf);

  // GRU (48 BN=64 blocks)
  gemm_gru2<<<48, 512, 0, stream>>>(x_bf, gru_Wih, gru_bih, gx,
                                    hid_bf, gru_Whh, gru_bhh, gh);
  k_gru_concat<<<BB, 256, 0, stream>>>(gx, gh, hidden, wgt, hnew, st_bf);

  // vocab logits + p_gen + copy-epilogue (co-resident; small blocks first)
  gemm_fc3c<<<256 + 782, 512, 0, stream>>>(
      st_bf, fc_W, fc_b, out, VV, 1536,
      wgt, input, embedding, gate_W, gate_b, pg,
      hnew, copy_W, copy_b, copy_v, preC, scC);

  // final distribution (vocab softmax + copy softmax + scatter)
  k_vocab_sc2<<<BB, 256, 0, stream>>>(out, pg, scC, mask1, triple, src1);
}

// Round 20
// 504.998 us; speedup vs baseline: 1.5855x; 1.0034x over previous
//
#include <hip/hip_runtime.h>
#include <math.h>

#define BB   128
#define DECD 512
#define E2D  1024
#define EMBD 256
#define S1D  200
#define S2D  200
#define SJD  400
#define VV   50000
#define NEGV (-1e10f)
#define JY   800   // joint tiles (51200 rows / 64); copy tiles follow

typedef unsigned short u16;
typedef __bf16 bf16x8 __attribute__((ext_vector_type(8)));
typedef float f32x4 __attribute__((ext_vector_type(4)));
typedef u16 u16x8 __attribute__((ext_vector_type(8)));

__device__ __forceinline__ u16 f2bf(float x) {
  unsigned u = __float_as_uint(x);
  unsigned r = (u + 0x7fffu + ((u >> 16) & 1u)) >> 16;
  return (u16)r;
}
__device__ __forceinline__ float bf2f(u16 h) {
  return __uint_as_float(((unsigned)h) << 16);
}
// hardware RTNE pack (r7/r16-r19-verified)
__device__ __forceinline__ u16x8 cvt8h(float4 a, float4 b) {
  bf16x8 r;
  r[0] = (__bf16)a.x; r[1] = (__bf16)a.y; r[2] = (__bf16)a.z; r[3] = (__bf16)a.w;
  r[4] = (__bf16)b.x; r[5] = (__bf16)b.y; r[6] = (__bf16)b.z; r[7] = (__bf16)b.w;
  return *reinterpret_cast<u16x8*>(&r);
}

typedef const __attribute__((address_space(1))) void* gas_t;
typedef __attribute__((address_space(3))) void* las_t;
__device__ __forceinline__ void async_copy16(const u16* g, u16* l) {
  __builtin_amdgcn_global_load_lds((gas_t)g, (las_t)l, 16, 0, 0);
}

// ---------------- fused prep (r16-r19-verified): wt2 | cvt hid | hWa | embx ----------------
__global__ __launch_bounds__(256) void k_prep(
    const float* __restrict__ Wa, const float* __restrict__ Wc,
    u16* __restrict__ Wta, u16* __restrict__ Wtc,
    const float* __restrict__ hidden, u16* __restrict__ hid_bf,
    const float* __restrict__ attn_b, float* __restrict__ hWa,
    const int* __restrict__ inp, const float* __restrict__ table,
    u16* __restrict__ x_bf) {
  int blk = blockIdx.x, tid = threadIdx.x;
  if (blk < 1024) {
    __shared__ float t[32][33];
    int z = blk >> 9, rem = blk & 511;
    int bk = rem & 31, bn = rem >> 5;
    const float* W = z ? Wc : Wa;
    u16* Wt = z ? Wtc : Wta;
    int tx = tid & 31, ty = tid >> 5;
    #pragma unroll
    for (int r = 0; r < 4; ++r) {
      int k = bk * 32 + ty + r * 8;
      t[ty + r * 8][tx] = W[(size_t)(512 + k) * 512 + bn * 32 + tx];
    }
    __syncthreads();
    #pragma unroll
    for (int r = 0; r < 4; ++r) {
      int n = bn * 32 + ty + r * 8;
      Wt[(size_t)n * 1024 + bk * 32 + tx] = f2bf(t[tx][ty + r * 8]);
    }
  } else if (blk < 1056) {
    int i = (blk - 1024) * 256 + tid;
    const float4 f0 = *(const float4*)(hidden + (size_t)i * 8);
    const float4 f1 = *(const float4*)(hidden + (size_t)i * 8 + 4);
    *(u16x8*)(hid_bf + (size_t)i * 8) = cvt8h(f0, f1);
  } else if (blk < 1312) {
    int idx = blk - 1056;
    int b = idx >> 1;
    int d = (idx & 1) * 256 + tid;
    const float* hr = hidden + (size_t)b * DECD;
    float acc = attn_b[d];
    #pragma unroll 8
    for (int k = 0; k < DECD; ++k) acc += hr[k] * Wa[(size_t)k * DECD + d];
    hWa[(size_t)b * DECD + d] = acc;
  } else {
    int b = blk - 1312;
    x_bf[(size_t)b * 1280 + tid] = f2bf(table[(size_t)inp[b] * EMBD + tid]);
  }
}

// ---------------- combined joint+copy energy GEMM — counted-vmcnt single-barrier pipeline ----------------
// B double-buffered (2x16KB); per step: {vmcnt(4)+lgkmcnt(0); raw s_barrier; issue B(t+1)+A(t+1);
// compute from cur}. B(t+1)'s HBM latency hides under step t's MFMA (T3/T4-lite).
__global__ __launch_bounds__(256) void gemm_energy_jc(
    const float* __restrict__ enc1, const float* __restrict__ enc2,
    const u16* __restrict__ BtA, const u16* __restrict__ BtC,
    const float* __restrict__ hW, const float* __restrict__ v,
    float* __restrict__ partJ, u16* __restrict__ preC) {
  __shared__ u16 As[2][64 * 32];    // 2 x 4 KB
  __shared__ u16 Bs[2][256 * 32];   // 2 x 16 KB
  __shared__ float sbuf[64][2];
  int tid = threadIdx.x;
  int wid = tid >> 6, lane = tid & 63;
  int wr = wid >> 1, wc = wid & 1;
  int bn = blockIdx.x;
  int jy = blockIdx.y;
  int joint = (jy < JY);
  size_t m0 = joint ? (size_t)jy * 64 : (size_t)(jy - JY) * 64;
  int bhalf = (jy & 1) * 64;
  int n0 = bn * 256;

  int rA = tid >> 2, cslot = tid & 3;
  int lAoff = rA * 32 + ((cslot ^ ((rA >> 1) & 3)) * 8);
  const float* base;
  if (joint)
    base = (m0 < (size_t)S1D * BB) ? (enc1 + m0 * E2D)
                                   : (enc2 + (m0 - (size_t)S1D * BB) * E2D);
  else
    base = enc1 + m0 * E2D;
  const float* gA_f = base + (size_t)rA * E2D + cslot * 8;

  const u16* Bt = joint ? BtA : BtC;
  const u16* gB[4];
  #pragma unroll
  for (int i = 0; i < 4; ++i) {
    int rn = i * 64 + wid * 16 + (lane >> 2);
    int c = (lane & 3) ^ ((rn >> 1) & 3);
    gB[i] = Bt + (size_t)(n0 + rn) * E2D + c * 8;
  }

  int q = lane >> 4, cl = lane & 15;
  int aoff[2], boff[8];
  #pragma unroll
  for (int mi = 0; mi < 2; ++mi) {
    int row = wr * 32 + mi * 16 + cl;
    aoff[mi] = row * 64 + ((q ^ ((row >> 1) & 3)) * 16);
  }
  #pragma unroll
  for (int nj = 0; nj < 8; ++nj) {
    int rn = wc * 128 + nj * 16 + cl;
    boff[nj] = rn * 64 + ((q ^ ((rn >> 1) & 3)) * 16);
  }

  f32x4 acc[2][8];
  #pragma unroll
  for (int mi = 0; mi < 2; ++mi)
    #pragma unroll
    for (int nj = 0; nj < 8; ++nj) {
      f32x4 z = {0.f, 0.f, 0.f, 0.f};
      acc[mi][nj] = z;
    }

  // ---- prologue: A(0) -> As[0]; issue B(0); load A(1) regs ----
  float4 a0 = *(const float4*)(gA_f);
  float4 a1 = *(const float4*)(gA_f + 4);
  *(u16x8*)(&As[0][lAoff]) = cvt8h(a0, a1);
  #pragma unroll
  for (int i = 0; i < 4; ++i) async_copy16(gB[i], &Bs[0][2048 * i + wid * 512]);
  a0 = *(const float4*)(gA_f + 32);
  a1 = *(const float4*)(gA_f + 36);

  // ---- main loop: ONE raw barrier per step, counted vmcnt ----
  for (int t = 0; t < 32; ++t) {
    int cur = t & 1, nxt = cur ^ 1;
    if (t < 31) {
      // wait: 4 oldest (B(t)) retired; A-reg loads may stay in flight.
      asm volatile("s_waitcnt vmcnt(4) lgkmcnt(0)\n\ts_barrier" ::: "memory");
      // issue next-step staging AFTER the barrier (prev readers of these buffers are done)
      int k1 = (t + 1) * 32;
      #pragma unroll
      for (int i = 0; i < 4; ++i) async_copy16(gB[i] + k1, &Bs[nxt][2048 * i + wid * 512]);
      *(u16x8*)(&As[nxt][lAoff]) = cvt8h(a0, a1);
      if (t < 30) {
        a0 = *(const float4*)(gA_f + k1 + 32);
        a1 = *(const float4*)(gA_f + k1 + 36);
      }
    } else {
      // last step: nothing younger in flight — drain fully.
      asm volatile("s_waitcnt vmcnt(0) lgkmcnt(0)\n\ts_barrier" ::: "memory");
    }
    bf16x8 af[2];
    #pragma unroll
    for (int mi = 0; mi < 2; ++mi)
      af[mi] = *(const bf16x8*)((const char*)As[cur] + aoff[mi]);
    #pragma unroll
    for (int nj = 0; nj < 8; ++nj) {
      bf16x8 bg = *(const bf16x8*)((const char*)Bs[cur] + boff[nj]);
      acc[0][nj] = __builtin_amdgcn_mfma_f32_16x16x32_bf16(af[0], bg, acc[0][nj], 0, 0, 0);
      acc[1][nj] = __builtin_amdgcn_mfma_f32_16x16x32_bf16(af[1], bg, acc[1][nj], 0, 0, 0);
    }
  }
  __syncthreads();   // full sync before epilogue LDS reuse

  if (joint) {
    #pragma unroll
    for (int mi = 0; mi < 2; ++mi) {
      #pragma unroll
      for (int j = 0; j < 4; ++j) {
        int m = wr * 32 + mi * 16 + q * 4 + j;
        float s = 0.f;
        #pragma unroll
        for (int nj = 0; nj < 8; ++nj) {
          int d = n0 + wc * 128 + nj * 16 + cl;
          s += tanhf(acc[mi][nj][j] + hW[(size_t)(bhalf + m) * DECD + d]) * v[d];
        }
        s += __shfl_xor(s, 1, 64);
        s += __shfl_xor(s, 2, 64);
        s += __shfl_xor(s, 4, 64);
        s += __shfl_xor(s, 8, 64);
        if (cl == 0) sbuf[m][wc] = s;
      }
    }
    __syncthreads();
    if (tid < 64)
      partJ[(size_t)bn * 51200 + m0 + tid] = sbuf[tid][0] + sbuf[tid][1];
  } else {
    #pragma unroll
    for (int mi = 0; mi < 2; ++mi) {
      #pragma unroll
      for (int nj = 0; nj < 8; ++nj) {
        int d = n0 + wc * 128 + nj * 16 + cl;
        #pragma unroll
        for (int j = 0; j < 4; ++j) {
          int m = wr * 32 + mi * 16 + q * 4 + j;
          preC[(m0 + m) * (size_t)DECD + d] = f2bf(acc[mi][nj][j]);
        }
      }
    }
  }
}

// weighted partials with inline joint softmax (r16-r19-verified; unroll 8)
__global__ __launch_bounds__(256) void k_wpart_sm(const float* __restrict__ part,
    const float* __restrict__ enc1, const float* __restrict__ enc2,
    const int* __restrict__ m1, const int* __restrict__ m2,
    float* __restrict__ wp) {
  int b = blockIdx.x, tid = threadIdx.x;
  int e2 = blockIdx.y * 256 + tid;
  int scn = blockIdx.z;
  __shared__ float sm[4];
  __shared__ float ws[100];
  int s0 = tid, s2 = tid + 256;
  float a0, a1 = -INFINITY;
  {
    int msk = (s0 < S1D) ? m1[b * S1D + s0] : m2[b * S2D + (s0 - S1D)];
    int m = s0 * 128 + b;
    a0 = msk ? (part[m] + part[51200 + m]) : NEGV;
  }
  if (s2 < SJD) {
    int msk = (s2 < S1D) ? m1[b * S1D + s2] : m2[b * S2D + (s2 - S1D)];
    int m = s2 * 128 + b;
    a1 = msk ? (part[m] + part[51200 + m]) : NEGV;
  }
  float vmax = fmaxf(a0, a1);
  #pragma unroll
  for (int off = 32; off > 0; off >>= 1) vmax = fmaxf(vmax, __shfl_down(vmax, off, 64));
  int lane = tid & 63, wid = tid >> 6;
  if (lane == 0) sm[wid] = vmax;
  __syncthreads();
  vmax = fmaxf(fmaxf(sm[0], sm[1]), fmaxf(sm[2], sm[3]));
  __syncthreads();
  float lsum = expf(a0 - vmax);
  if (s2 < SJD) lsum += expf(a1 - vmax);
  #pragma unroll
  for (int off = 32; off > 0; off >>= 1) lsum += __shfl_down(lsum, off, 64);
  if (lane == 0) sm[wid] = lsum;
  __syncthreads();
  float inv = 1.0f / (sm[0] + sm[1] + sm[2] + sm[3]);
  if (tid < 100) {
    int s = scn * 100 + tid;
    int msk = (s < S1D) ? m1[b * S1D + s] : m2[b * S2D + (s - S1D)];
    int m = s * 128 + b;
    float av = msk ? (part[m] + part[51200 + m]) : NEGV;
    ws[tid] = expf(av - vmax) * inv;
  }
  __syncthreads();
  float acc0 = 0.f, acc1 = 0.f;
  #pragma unroll 8
  for (int i = 0; i < 100; ++i) {
    int s = scn * 100 + i;
    const float* ep = (s < S1D) ? (enc1 + ((size_t)s * BB + b) * E2D)
                                : (enc2 + ((size_t)(s - S1D) * BB + b) * E2D);
    float2 u = *(const float2*)(ep + e2 * 2);
    float w = ws[i];
    acc0 += w * u.x;
    acc1 += w * u.y;
  }
  float* dst = wp + ((size_t)scn * BB + b) * E2D + e2 * 2;
  dst[0] = acc0;
  dst[1] = acc1;
}

__global__ __launch_bounds__(256) void k_wsum_x(const float* __restrict__ wp,
    float* __restrict__ wgt, u16* __restrict__ x) {
  int i = blockIdx.x * 256 + threadIdx.x;
  const int NN = BB * E2D;
  float s = wp[i] + wp[NN + i] + wp[2 * NN + i] + wp[3 * NN + i];
  wgt[i] = s;
  int b = i >> 10, e = i & 1023;
  x[(size_t)b * 1280 + EMBD + e] = f2bf(s);
}

// ---------------- fc3-style body (BN=64, 512 thr) as device function (r18/r19-verified) ----------------
__device__ __forceinline__ void fc3_body(
    const u16* __restrict__ A, const float* __restrict__ Bf,
    const float* __restrict__ bias, float* __restrict__ C,
    int N, int K, int n0, u16* smem) {
  u16* As0 = smem;            u16* As1 = smem + 4096;
  u16* Bs0 = smem + 8192;     u16* Bs1 = smem + 10240;
  u16* AsH[2] = {As0, As1};
  u16* BsH[2] = {Bs0, Bs1};
  int tid = threadIdx.x;
  int wid = tid >> 6, lane = tid & 63;
  int wr = wid >> 2, wc = wid & 3;

  int rowa = wid * 16 + (lane >> 2);
  int ca = (lane & 3) ^ ((rowa >> 1) & 3);
  const u16* gA = A + (size_t)rowa * K + ca * 8;

  int rB = tid >> 3, cB = tid & 7;
  int gnB = n0 + rB; if (gnB >= N) gnB = N - 1;
  const float* gB = Bf + (size_t)gnB * K + cB * 8;
  int hB = cB >> 2, s4 = cB & 3;
  int lBoff = rB * 32 + ((s4 ^ ((rB >> 1) & 3)) * 8);

  int q = lane >> 4, cl = lane & 15;
  int aoff[4], boff;
  #pragma unroll
  for (int mi = 0; mi < 4; ++mi) {
    int row = wr * 64 + mi * 16 + cl;
    aoff[mi] = row * 64 + ((q ^ ((row >> 1) & 3)) * 16);
  }
  {
    int rn = wc * 16 + cl;
    boff = rn * 64 + ((q ^ ((rn >> 1) & 3)) * 16);
  }

  f32x4 acc[4];
  #pragma unroll
  for (int mi = 0; mi < 4; ++mi) {
    f32x4 z = {0.f, 0.f, 0.f, 0.f};
    acc[mi] = z;
  }

  float4 b0 = *(const float4*)(gB);
  float4 b1 = *(const float4*)(gB + 4);

  for (int k0 = 0; k0 < K; k0 += 64) {
    *(u16x8*)(&BsH[hB][lBoff]) = cvt8h(b0, b1);
    async_copy16(gA + k0,      &As0[wid * 512]);
    async_copy16(gA + k0 + 32, &As1[wid * 512]);
    __syncthreads();
    if (k0 + 64 < K) {
      b0 = *(const float4*)(gB + k0 + 64);
      b1 = *(const float4*)(gB + k0 + 68);
    }
    #pragma unroll
    for (int h = 0; h < 2; ++h) {
      bf16x8 af[4];
      #pragma unroll
      for (int mi = 0; mi < 4; ++mi) af[mi] = *(const bf16x8*)((const char*)AsH[h] + aoff[mi]);
      bf16x8 bg = *(const bf16x8*)((const char*)BsH[h] + boff);
      #pragma unroll
      for (int mi = 0; mi < 4; ++mi)
        acc[mi] = __builtin_amdgcn_mfma_f32_16x16x32_bf16(af[mi], bg, acc[mi], 0, 0, 0);
    }
    __syncthreads();
  }

  int n = n0 + wc * 16 + cl;
  if (n < N) {
    float bv = bias[n];
    #pragma unroll
    for (int mi = 0; mi < 4; ++mi)
      #pragma unroll
      for (int j = 0; j < 4; ++j) {
        int m = wr * 64 + mi * 16 + q * 4 + j;
        C[(size_t)m * N + n] = acc[mi][j] + bv;
      }
  }
}

// merged GRU GEMMs, BN=64 x 48 blocks (r19-verified)
__global__ __launch_bounds__(512) void gemm_gru2(
    const u16* __restrict__ x_bf, const float* __restrict__ Wih,
    const float* __restrict__ bih, float* __restrict__ gx,
    const u16* __restrict__ h_bf, const float* __restrict__ Whh,
    const float* __restrict__ bhh, float* __restrict__ gh) {
  __shared__ u16 smem[12288];
  if (blockIdx.x < 24)
    fc3_body(x_bf, Wih, bih, gx, 1536, 1280, blockIdx.x * 64, smem);
  else
    fc3_body(h_bf, Whh, bhh, gh, 1536, 512, (blockIdx.x - 24) * 64, smem);
}

// ---------------- combined fc3 + pgen + copy-epilogue (r18/r19-verified; preC bf16) ----------------
__global__ __launch_bounds__(512) void gemm_fc3c(
    const u16* __restrict__ A, const float* __restrict__ Bf,
    const float* __restrict__ bias, float* __restrict__ C, int N, int K,
    const float* __restrict__ wgt, const int* __restrict__ inp,
    const float* __restrict__ table, const float* __restrict__ gW,
    const float* __restrict__ gb, float* __restrict__ pg,
    const float* __restrict__ hnew, const float* __restrict__ copy_W,
    const float* __restrict__ copy_b, const float* __restrict__ copy_v,
    const u16* __restrict__ preC, float* __restrict__ scC) {
  __shared__ u16 smem[12288];   // 24.6 KB pool, aliased per role
  int tid = threadIdx.x;
  if (blockIdx.x >= 256) {
    fc3_body(A, Bf, bias, C, N, K, (blockIdx.x - 256) * 64, smem);
  } else if (blockIdx.x < 128) {
    // ---- p_gen per b (r16-r19-verified math) ----
    int b = blockIdx.x;
    float* sm = (float*)smem;
    float s = 0.f;
    for (int k = tid; k < E2D + EMBD; k += 512)
      s += gW[k] * ((k < E2D) ? wgt[(size_t)b * E2D + k]
                              : table[(size_t)inp[b] * EMBD + k - E2D]);
    #pragma unroll
    for (int off = 32; off > 0; off >>= 1) s += __shfl_down(s, off, 64);
    int lane = tid & 63, wid = tid >> 6;
    if (lane == 0) sm[wid] = s;
    __syncthreads();
    if (tid == 0) {
      float t = sm[0] + sm[1] + sm[2] + sm[3] + sm[4] + sm[5] + sm[6] + sm[7] + gb[0];
      pg[b] = 1.f / (1.f + expf(-t));
    }
  } else {
    // ---- copy epilogue per b (r17-r19-verified; bf16 preC reads) ----
    int b = blockIdx.x - 128;
    float* hn  = (float*)smem;          // 512 floats
    float* hwc = (float*)smem + 512;    // 512 floats
    hn[tid] = hnew[(size_t)b * DECD + tid];
    __syncthreads();
    {
      float acc = copy_b[tid];
      #pragma unroll 8
      for (int k = 0; k < DECD; ++k) acc += hn[k] * copy_W[(size_t)k * DECD + tid];
      hwc[tid] = acc;
    }
    __syncthreads();
    int wid = tid >> 6, lane = tid & 63;
    float4 h0 = *(const float4*)(hwc + lane * 8);
    float4 h1 = *(const float4*)(hwc + lane * 8 + 4);
    float4 v0 = *(const float4*)(copy_v + lane * 8);
    float4 v1 = *(const float4*)(copy_v + lane * 8 + 4);
    for (int s = wid; s < S1D; s += 8) {
      const u16* pr = preC + ((size_t)s * 128 + b) * DECD + lane * 8;
      u16x8 pv = *(const u16x8*)(pr);
      float e = tanhf(bf2f(pv[0]) + h0.x) * v0.x + tanhf(bf2f(pv[1]) + h0.y) * v0.y
              + tanhf(bf2f(pv[2]) + h0.z) * v0.z + tanhf(bf2f(pv[3]) + h0.w) * v0.w
              + tanhf(bf2f(pv[4]) + h1.x) * v1.x + tanhf(bf2f(pv[5]) + h1.y) * v1.y
              + tanhf(bf2f(pv[6]) + h1.z) * v1.z + tanhf(bf2f(pv[7]) + h1.w) * v1.w;
      #pragma unroll
      for (int off = 32; off > 0; off >>= 1) e += __shfl_xor(e, off, 64);
      if (lane == 0) scC[(size_t)b * S1D + s] = e;
    }
  }
}

// GRU pointwise + fused concat (r15-r19-verified)
__global__ __launch_bounds__(256) void k_gru_concat(const float* __restrict__ gx,
    const float* __restrict__ gh, const float* __restrict__ hidden,
    const float* __restrict__ wgt, float* __restrict__ hnew,
    u16* __restrict__ st) {
  int b = blockIdx.x, tid = threadIdx.x;
  #pragma unroll
  for (int qq = 0; qq < 2; ++qq) {
    int d = tid + qq * 256;
    size_t o = (size_t)b * 1536;
    float xr = gx[o + d],        hr = gh[o + d];
    float xz = gx[o + 512 + d],  hz = gh[o + 512 + d];
    float xn = gx[o + 1024 + d], hn = gh[o + 1024 + d];
    float r = 1.f / (1.f + expf(-(xr + hr)));
    float z = 1.f / (1.f + expf(-(xz + hz)));
    float n = tanhf(xn + r * hn);
    float hv = (1.f - z) * n + z * hidden[(size_t)b * DECD + d];
    hnew[(size_t)b * DECD + d] = hv;
    st[(size_t)b * 1536 + d] = f2bf(hv);
  }
  #pragma unroll
  for (int qq = 0; qq < 4; ++qq) {
    int e = tid + qq * 256;
    st[(size_t)b * 1536 + DECD + e] = f2bf(wgt[(size_t)b * E2D + e]);
  }
}

// vocab softmax (single-pass online) + p_gen scale + copy-softmax + scatter (r18/r19-verified)
__global__ __launch_bounds__(256) void k_vocab_sc2(float* __restrict__ dist,
    const float* __restrict__ pg, const float* __restrict__ scC,
    const int* __restrict__ m1, const int* __restrict__ tr,
    const int* __restrict__ src1) {
  int b = blockIdx.x, tid = threadIdx.x;
  float* row = dist + (size_t)b * VV;
  __shared__ float smM[4], smS[4];
  int lane = tid & 63, wid = tid >> 6;
  float m = -INFINITY, s = 0.f;
  for (int i = tid; i < VV; i += 256) {
    float x = row[i];
    float mn = fmaxf(m, x);
    s = s * expf(m - mn) + expf(x - mn);
    m = mn;
  }
  #pragma unroll
  for (int off = 32; off > 0; off >>= 1) {
    float mo = __shfl_down(m, off, 64);
    float so = __shfl_down(s, off, 64);
    float mn = fmaxf(m, mo);
    s = s * expf(m - mn) + so * expf(mo - mn);
    m = mn;
  }
  if (lane == 0) { smM[wid] = m; smS[wid] = s; }
  __syncthreads();
  if (tid == 0) {
    float mt = smM[0], st = smS[0];
    #pragma unroll
    for (int i = 1; i < 4; ++i) {
      float mn = fmaxf(mt, smM[i]);
      st = st * expf(mt - mn) + smS[i] * expf(smM[i] - mn);
      mt = mn;
    }
    smM[0] = mt; smS[0] = st;
  }
  __syncthreads();
  m = smM[0];
  s = smS[0];
  float pgb = pg[b];
  float scale = pgb / s;
  for (int i = tid; i < VV; i += 256) row[i] = expf(row[i] - m) * scale;
  __syncthreads();
  float c0 = -INFINITY;
  if (tid < S1D) {
    int msk = m1[b * S1D + tid] * tr[b * S1D + tid];
    c0 = msk ? scC[(size_t)b * S1D + tid] : NEGV;
  }
  float cmax = c0;
  #pragma unroll
  for (int off = 32; off > 0; off >>= 1) cmax = fmaxf(cmax, __shfl_down(cmax, off, 64));
  if (lane == 0) smM[wid] = cmax;
  __syncthreads();
  cmax = fmaxf(fmaxf(smM[0], smM[1]), fmaxf(smM[2], smM[3]));
  __syncthreads();
  float csum = (tid < S1D) ? expf(c0 - cmax) : 0.f;
  #pragma unroll
  for (int off = 32; off > 0; off >>= 1) csum += __shfl_down(csum, off, 64);
  if (lane == 0) smS[wid] = csum;
  __syncthreads();
  float cinv = 1.0f / (smS[0] + smS[1] + smS[2] + smS[3]);
  if (tid < S1D) {
    float val = (1.f - pgb) * expf(c0 - cmax) * cinv;
    int tok = src1[(size_t)tid * BB + b];
    atomicAdd(&row[tok], val);
  }
}

extern "C" void kernel_launch(void* const* d_in, const int* in_sizes, int n_in,
                              void* d_out, int out_size, void* d_ws, size_t ws_size,
                              hipStream_t stream) {
  (void)in_sizes; (void)n_in; (void)out_size; (void)ws_size;
  const int*   input  = (const int*)d_in[0];
  const float* hidden = (const float*)d_in[1];
  const int*   src1   = (const int*)d_in[2];
  const float* enc1   = (const float*)d_in[3];
  const int*   mask1  = (const int*)d_in[4];
  const int*   triple = (const int*)d_in[5];
  const float* enc2   = (const float*)d_in[6];
  const int*   mask2  = (const int*)d_in[7];
  const float* embedding = (const float*)d_in[8];
  const float* attn_W = (const float*)d_in[9];
  const float* attn_b = (const float*)d_in[10];
  const float* attn_v = (const float*)d_in[11];
  const float* copy_W = (const float*)d_in[12];
  const float* copy_b = (const float*)d_in[13];
  const float* copy_v = (const float*)d_in[14];
  const float* gru_Wih = (const float*)d_in[15];
  const float* gru_Whh = (const float*)d_in[16];
  const float* gru_bih = (const float*)d_in[17];
  const float* gru_bhh = (const float*)d_in[18];
  const float* fc_W   = (const float*)d_in[19];
  const float* fc_b   = (const float*)d_in[20];
  const float* gate_W = (const float*)d_in[21];
  const float* gate_b = (const float*)d_in[22];

  char* w = (char*)d_ws;
  u16* Wt_a = (u16*)w;                w += (size_t)512 * 1024 * 2;
  u16* Wt_c = (u16*)w;                w += (size_t)512 * 1024 * 2;
  float* partJ = (float*)w;           w += (size_t)2 * 51200 * 4;
  u16*   preC = (u16*)w;              w += (size_t)25600 * 512 * 2;
  float* hWa  = (float*)w;            w += (size_t)BB * DECD * 4;
  float* scC  = (float*)w;            w += (size_t)BB * S1D * 4;
  float* wgt  = (float*)w;            w += (size_t)BB * E2D * 4;
  float* wpart = (float*)w;           w += (size_t)4 * BB * E2D * 4;
  u16*   x_bf = (u16*)w;              w += (size_t)BB * 1280 * 2;
  u16*   hid_bf = (u16*)w;            w += (size_t)BB * DECD * 2;
  float* gx   = (float*)w;            w += (size_t)BB * 1536 * 4;
  float* gh   = (float*)w;            w += (size_t)BB * 1536 * 4;
  u16*   st_bf = (u16*)w;             w += (size_t)BB * 1536 * 2;
  float* pg   = (float*)w;            w += 512;

  float* out  = (float*)d_out;
  float* hnew = out + (size_t)BB * VV;

  // fused prep
  k_prep<<<1440, 256, 0, stream>>>(attn_W, copy_W, Wt_a, Wt_c,
                                   hidden, hid_bf, attn_b, hWa,
                                   input, embedding, x_bf);

  // combined joint-attn + copy-preactivation energy GEMM (counted-vmcnt pipeline)
  gemm_energy_jc<<<dim3(2, JY + 400), 256, 0, stream>>>(
      enc1, enc2, Wt_a, Wt_c, hWa, attn_v, partJ, preC);

  // weighted context with inline joint softmax
  k_wpart_sm<<<dim3(BB, 2, 4), 256, 0, stream>>>(partJ, enc1, enc2, mask1, mask2, wpart);
  k_wsum_x<<<512, 256, 0, stream>>>(wpart, wgt, x_bf);

  // GRU (48 BN=64 blocks)
  gemm_gru2<<<48, 512, 0, stream>>>(x_bf, gru_Wih, gru_bih, gx,
                                    hid_bf, gru_Whh, gru_bhh, gh);
  k_gru_concat<<<BB, 256, 0, stream>>>(gx, gh, hidden, wgt, hnew, st_bf);

  // vocab logits + p_gen + copy-epilogue (co-resident; small blocks first)
  gemm_fc3c<<<256 + 782, 512, 0, stream>>>(
      st_bf, fc_W, fc_b, out, VV, 1536,
      wgt, input, embedding, gate_W, gate_b, pg,
      hnew, copy_W, copy_b, copy_v, preC, scC);

  // final distribution (vocab softmax + copy softmax + scatter)
  k_vocab_sc2<<<BB, 256, 0, stream>>>(out, pg, scC, mask1, triple, src1);
}